// Round 1
// baseline (1974.194 us; speedup 1.0000x reference)
//
#include <hip/hip_runtime.h>
#include <hip/hip_bf16.h>

// Problem constants
constexpr int Bb  = 16;
constexpr int Ll  = 100;
constexpr int DIN = 6144;
constexpr int Hh  = 1024;
constexpr int DI  = 2048;
constexpr int Nst = 16;
constexpr int DTR = 64;
constexpr int Kc  = 4;
constexpr int NC  = 16;
constexpr int M   = Bb * Ll;   // 1600 tokens

// ---------------------------------------------------------------------------
// Generic fp32 tiled GEMM: C[M,N] = A[M,K] @ B[K,N] (+bias) (+activation)
// 64x64 tile, BK=16, 256 threads, 4x4 accum per thread.
// ACT: 0 = none, 1 = softplus
// ---------------------------------------------------------------------------
template<int ACT, bool BIAS>
__global__ __launch_bounds__(256) void gemm_f32(
    const float* __restrict__ A, const float* __restrict__ Bm,
    const float* __restrict__ bias, float* __restrict__ C,
    int Md, int Nd, int Kd, int lda, int ldb, int ldc)
{
    __shared__ float As[16][68];   // [k][m], padded: 68*4=272B rows -> 16B-aligned float4, 2-way-max bank on write
    __shared__ float Bs[16][64];   // [k][n]

    const int t  = threadIdx.x;
    const int tx = t & 15;
    const int ty = t >> 4;
    const int m0 = blockIdx.x * 64;
    const int n0 = blockIdx.y * 64;

    float acc[4][4] = {};

    for (int k0 = 0; k0 < Kd; k0 += 16) {
        // Load A tile (64 rows x 16 k), transposed into As[k][m]
        #pragma unroll
        for (int i = 0; i < 4; i++) {
            int r  = ty + i * 16;
            int gm = m0 + r;
            int gk = k0 + tx;
            As[tx][r] = (gm < Md && gk < Kd) ? A[(size_t)gm * lda + gk] : 0.f;
        }
        // Load B tile (16 k x 64 n)
        const int bc = t & 63;
        const int br = t >> 6;
        #pragma unroll
        for (int i = 0; i < 4; i++) {
            int r  = br + i * 4;
            int gk = k0 + r;
            int gn = n0 + bc;
            Bs[r][bc] = (gk < Kd && gn < Nd) ? Bm[(size_t)gk * ldb + gn] : 0.f;
        }
        __syncthreads();

        #pragma unroll
        for (int kk = 0; kk < 16; kk++) {
            float4 a4 = *(const float4*)&As[kk][ty * 4];
            float4 b4 = *(const float4*)&Bs[kk][tx * 4];
            float av[4] = {a4.x, a4.y, a4.z, a4.w};
            float bv[4] = {b4.x, b4.y, b4.z, b4.w};
            #pragma unroll
            for (int i = 0; i < 4; i++)
                #pragma unroll
                for (int j = 0; j < 4; j++)
                    acc[i][j] = fmaf(av[i], bv[j], acc[i][j]);
        }
        __syncthreads();
    }

    // Epilogue
    #pragma unroll
    for (int i = 0; i < 4; i++) {
        int gm = m0 + ty * 4 + i;
        if (gm >= Md) continue;
        #pragma unroll
        for (int j = 0; j < 4; j++) {
            int gn = n0 + tx * 4 + j;
            if (gn >= Nd) continue;
            float v = acc[i][j];
            if (BIAS) v += bias[gn];
            if (ACT == 1) v = fmaxf(v, 0.f) + log1pf(expf(-fabsf(v)));  // stable softplus
            C[(size_t)gm * ldc + gn] = v;
        }
    }
}

// ---------------------------------------------------------------------------
// Causal depthwise conv (K=4) + bias + SiLU.
// xm is the first DI columns of xz (row stride 2*DI).
// ---------------------------------------------------------------------------
__global__ __launch_bounds__(256) void conv_silu_kernel(
    const float* __restrict__ xz, const float* __restrict__ conv_w,
    const float* __restrict__ conv_b, float* __restrict__ xc)
{
    int idx = blockIdx.x * 256 + threadIdx.x;      // over B*L*DI
    if (idx >= Bb * Ll * DI) return;
    int d  = idx & (DI - 1);
    int bl = idx >> 11;                             // DI = 2048 = 2^11
    int l  = bl % Ll;

    float acc = conv_b[d];
    #pragma unroll
    for (int k = 0; k < Kc; k++) {
        int ls = l + k - (Kc - 1);
        if (ls >= 0)
            acc = fmaf(conv_w[d * Kc + k], xz[(size_t)(bl + ls - l) * (2 * DI) + d], acc);
    }
    float s = acc / (1.f + expf(-acc));             // silu
    xc[idx] = s;
}

// ---------------------------------------------------------------------------
// Selective scan: one thread per (b, d); 16 states in registers.
// Fuses y = (sum_n h*C) + D*xc, then y *= silu(z).
// ---------------------------------------------------------------------------
__global__ __launch_bounds__(256) void scan_kernel(
    const float* __restrict__ delta, const float* __restrict__ xc,
    const float* __restrict__ xz,    const float* __restrict__ proj,
    const float* __restrict__ A_log, const float* __restrict__ Dv,
    float* __restrict__ y)
{
    int d = blockIdx.x * 256 + threadIdx.x;   // 0..DI-1
    int b = blockIdx.y;

    float Ar[Nst];
    #pragma unroll
    for (int n = 0; n < Nst; n++) Ar[n] = -expf(A_log[(size_t)d * Nst + n]);
    const float Dd = Dv[d];

    float h[Nst];
    #pragma unroll
    for (int n = 0; n < Nst; n++) h[n] = 0.f;

    for (int l = 0; l < Ll; l++) {
        size_t bl = (size_t)b * Ll + l;
        float dl  = delta[bl * DI + d];
        float xcv = xc[bl * DI + d];
        float zv  = xz[bl * (2 * DI) + DI + d];
        float dx  = dl * xcv;
        const float* p = proj + bl * (DTR + 2 * Nst);

        float yacc = 0.f;
        #pragma unroll
        for (int n = 0; n < Nst; n++) {
            float dA = expf(dl * Ar[n]);
            h[n] = fmaf(dA, h[n], dx * p[DTR + n]);
            yacc = fmaf(h[n], p[DTR + Nst + n], yacc);
        }
        float yv = yacc + Dd * xcv;
        yv *= zv / (1.f + expf(-zv));   // * silu(z)
        y[bl * DI + d] = yv;
    }
}

// ---------------------------------------------------------------------------
// Final tiny GEMM: logits[M,16] = out[M,1024] @ W_out[1024,16] + b_out
// One block per row.
// ---------------------------------------------------------------------------
__global__ __launch_bounds__(256) void gemm_n16(
    const float* __restrict__ A, const float* __restrict__ W,
    const float* __restrict__ bias, float* __restrict__ C, int Kd)
{
    int m  = blockIdx.x;
    int t  = threadIdx.x;
    int c  = t & 15;
    int kg = t >> 4;   // 16 k-groups
    const float* a = A + (size_t)m * Kd;

    float acc = 0.f;
    for (int k = kg; k < Kd; k += 16)
        acc = fmaf(a[k], W[k * NC + c], acc);

    __shared__ float red[256];
    red[t] = acc;
    __syncthreads();
    #pragma unroll
    for (int s = 128; s >= 16; s >>= 1) {
        if (t < s) red[t] += red[t + s];
        __syncthreads();
    }
    if (t < 16) C[(size_t)m * NC + t] = red[t] + bias[t];
}

// ---------------------------------------------------------------------------
extern "C" void kernel_launch(void* const* d_in, const int* in_sizes, int n_in,
                              void* d_out, int out_size, void* d_ws, size_t ws_size,
                              hipStream_t stream) {
    const float* x         = (const float*)d_in[0];
    const float* W_in      = (const float*)d_in[1];
    const float* b_in      = (const float*)d_in[2];
    const float* in_proj_w = (const float*)d_in[3];
    const float* conv_w    = (const float*)d_in[4];
    const float* conv_b    = (const float*)d_in[5];
    const float* x_proj_w  = (const float*)d_in[6];
    const float* dt_proj_w = (const float*)d_in[7];
    const float* dt_proj_b = (const float*)d_in[8];
    const float* A_log     = (const float*)d_in[9];
    const float* Dv        = (const float*)d_in[10];
    const float* out_proj  = (const float*)d_in[11];
    const float* W_out     = (const float*)d_in[12];
    const float* b_out     = (const float*)d_in[13];
    float* logits = (float*)d_out;

    // Workspace layout (floats)
    float* ws = (float*)d_ws;
    size_t off = 0;
    float* hbuf  = ws + off; off += (size_t)M * Hh;        // 1600*1024
    float* xz    = ws + off; off += (size_t)M * 2 * DI;    // 1600*4096
    float* xc    = ws + off; off += (size_t)M * DI;        // 1600*2048
    float* proj  = ws + off; off += (size_t)M * (DTR + 2 * Nst); // 1600*96
    float* delta = ws + off; off += (size_t)M * DI;        // 1600*2048
    float* ybuf  = ws + off; off += (size_t)M * DI;        // 1600*2048
    float* outb  = hbuf;                                   // reuse h (free after GEMM2)

    dim3 blk(256);

    // 1) h = x @ W_in + b_in          [1600,6144]@[6144,1024]
    gemm_f32<0, true><<<dim3(M / 64, Hh / 64), blk, 0, stream>>>(
        x, W_in, b_in, hbuf, M, Hh, DIN, DIN, Hh, Hh);

    // 2) xz = h @ in_proj_w           [1600,1024]@[1024,4096]
    gemm_f32<0, false><<<dim3(M / 64, (2 * DI) / 64), blk, 0, stream>>>(
        hbuf, in_proj_w, nullptr, xz, M, 2 * DI, Hh, Hh, 2 * DI, 2 * DI);

    // 3) xc = silu(causal_conv(xm) + conv_b)
    conv_silu_kernel<<<dim3((Bb * Ll * DI) / 256), blk, 0, stream>>>(
        xz, conv_w, conv_b, xc);

    // 4) proj = xc @ x_proj_w         [1600,2048]@[2048,96]
    gemm_f32<0, false><<<dim3(M / 64, 2), blk, 0, stream>>>(
        xc, x_proj_w, nullptr, proj, M, DTR + 2 * Nst, DI, DI, DTR + 2 * Nst, DTR + 2 * Nst);

    // 5) delta = softplus(proj[:,:64] @ dt_proj_w + dt_proj_b)   [1600,64]@[64,2048]
    gemm_f32<1, true><<<dim3(M / 64, DI / 64), blk, 0, stream>>>(
        proj, dt_proj_w, dt_proj_b, delta, M, DI, DTR, DTR + 2 * Nst, DI, DI);

    // 6) selective scan (fused D*xc and silu(z) gating) -> y
    scan_kernel<<<dim3(DI / 256, Bb), blk, 0, stream>>>(
        delta, xc, xz, proj, A_log, Dv, ybuf);

    // 7) out = y @ out_proj_w         [1600,2048]@[2048,1024]
    gemm_f32<0, false><<<dim3(M / 64, Hh / 64), blk, 0, stream>>>(
        ybuf, out_proj, nullptr, outb, M, Hh, DI, DI, Hh, Hh);

    // 8) logits = out @ W_out + b_out [1600,1024]@[1024,16]
    gemm_n16<<<dim3(M), blk, 0, stream>>>(outb, W_out, b_out, logits, Hh);
}

// Round 2
// 722.205 us; speedup vs baseline: 2.7336x; 2.7336x over previous
//
#include <hip/hip_runtime.h>
#include <hip/hip_bf16.h>
#include <stdint.h>

// Problem constants
constexpr int Bb  = 16;
constexpr int Ll  = 100;
constexpr int DIN = 6144;
constexpr int Hh  = 1024;
constexpr int DI  = 2048;
constexpr int Nst = 16;
constexpr int DTR = 64;
constexpr int Kc  = 4;
constexpr int NC  = 16;
constexpr int M   = Bb * Ll;   // 1600 tokens

typedef __attribute__((ext_vector_type(8))) short short8;
typedef __attribute__((ext_vector_type(4))) float floatx4;

__device__ __forceinline__ float bf2f(unsigned short u) {
    union { uint32_t b; float f; } x; x.b = ((uint32_t)u) << 16; return x.f;
}
__device__ __forceinline__ unsigned short f2bf(float f) {
    union { float f; uint32_t b; } x; x.f = f;
    uint32_t r = x.b + 0x7FFF + ((x.b >> 16) & 1);   // RNE
    return (unsigned short)(r >> 16);
}

// ---------------------------------------------------------------------------
// bf16 MFMA GEMM: C[M,N] = A[M,K] @ Bt[N,K]^T (+bias), bf16 in/out, fp32 acc.
// BM=128, BN=64, BK=32. 256 threads = 4 waves (2x2), wave tile 64x32 (4x2 frags).
// LDS layout: cell(g, r) = 16B of 8 k-elems; offset = (g*ROWS + r)*16B.
//  -> linear for global_load_lds, conflict-free ds_read_b128 (lanes stride 16B).
// ---------------------------------------------------------------------------
template<bool BIAS>
__global__ __launch_bounds__(256) void gemm_mfma_bf16(
    const unsigned short* __restrict__ A,   // [Md x Kd]
    const unsigned short* __restrict__ Bt,  // [Nd x Kd]  (B transposed)
    const float* __restrict__ bias,
    unsigned short* __restrict__ C,         // [Md x Nd]
    int Md, int Nd, int Kd)
{
    __shared__ short As[4 * 128 * 8];   // 8 KB
    __shared__ short Bs[4 * 64 * 8];    // 4 KB

    const int tid  = threadIdx.x;
    const int lane = tid & 63;
    const int wid  = tid >> 6;
    const int wr   = wid >> 1;      // wave row (0..1) -> 64 rows each
    const int wc   = wid & 1;       // wave col (0..1) -> 32 cols each
    const int l15  = lane & 15;
    const int kg   = lane >> 4;     // k-block 0..3
    const int m0   = blockIdx.x * 128;
    const int n0   = blockIdx.y * 64;

    floatx4 acc[4][2];
    #pragma unroll
    for (int m = 0; m < 4; m++)
        #pragma unroll
        for (int n = 0; n < 2; n++)
            acc[m][n] = (floatx4){0.f, 0.f, 0.f, 0.f};

    for (int k0 = 0; k0 < Kd; k0 += 32) {
        // Stage A tile: 512 cells x 16B
        #pragma unroll
        for (int j = 0; j < 2; j++) {
            int c = j * 256 + tid;
            int g = c >> 7, r = c & 127;
            int grow = m0 + r; grow = grow < Md ? grow : Md - 1;
            const __attribute__((address_space(1))) short* src =
                (const __attribute__((address_space(1))) short*)(A + (size_t)grow * Kd + k0 + g * 8);
            __builtin_amdgcn_global_load_lds(
                (const __attribute__((address_space(1))) void*)src,
                (__attribute__((address_space(3))) void*)&As[c * 8], 16, 0, 0);
        }
        // Stage B tile: 256 cells x 16B
        {
            int c = tid;
            int g = c >> 6, r = c & 63;
            const __attribute__((address_space(1))) short* src =
                (const __attribute__((address_space(1))) short*)(Bt + (size_t)(n0 + r) * Kd + k0 + g * 8);
            __builtin_amdgcn_global_load_lds(
                (const __attribute__((address_space(1))) void*)src,
                (__attribute__((address_space(3))) void*)&Bs[c * 8], 16, 0, 0);
        }
        __syncthreads();

        short8 a[4], b[2];
        #pragma unroll
        for (int m = 0; m < 4; m++)
            a[m] = *(const short8*)&As[(kg * 128 + wr * 64 + m * 16 + l15) * 8];
        #pragma unroll
        for (int n = 0; n < 2; n++)
            b[n] = *(const short8*)&Bs[(kg * 64 + wc * 32 + n * 16 + l15) * 8];

        #pragma unroll
        for (int m = 0; m < 4; m++)
            #pragma unroll
            for (int n = 0; n < 2; n++)
                acc[m][n] = __builtin_amdgcn_mfma_f32_16x16x32_bf16(a[m], b[n], acc[m][n], 0, 0, 0);

        __syncthreads();
    }

    // Epilogue: D layout col=lane&15, row=(lane>>4)*4+q
    #pragma unroll
    for (int m = 0; m < 4; m++) {
        #pragma unroll
        for (int n = 0; n < 2; n++) {
            int col = n0 + wc * 32 + n * 16 + l15;
            float bv = BIAS ? bias[col] : 0.f;
            #pragma unroll
            for (int q = 0; q < 4; q++) {
                int row = m0 + wr * 64 + m * 16 + kg * 4 + q;
                if (row < Md)
                    C[(size_t)row * Nd + col] = f2bf(acc[m][n][q] + bv);
            }
        }
    }
}

// ---------------------------------------------------------------------------
// fp32 tiled GEMM (kept for small GEMMs): C = A@B (+bias)(+softplus)
// ---------------------------------------------------------------------------
template<int ACT, bool BIAS>
__global__ __launch_bounds__(256) void gemm_f32(
    const float* __restrict__ A, const float* __restrict__ Bm,
    const float* __restrict__ bias, float* __restrict__ C,
    int Md, int Nd, int Kd, int lda, int ldb, int ldc)
{
    __shared__ float As[16][68];
    __shared__ float Bs[16][64];

    const int t  = threadIdx.x;
    const int tx = t & 15;
    const int ty = t >> 4;
    const int m0 = blockIdx.x * 64;
    const int n0 = blockIdx.y * 64;

    float acc[4][4] = {};

    for (int k0 = 0; k0 < Kd; k0 += 16) {
        #pragma unroll
        for (int i = 0; i < 4; i++) {
            int r  = ty + i * 16;
            int gm = m0 + r;
            int gk = k0 + tx;
            As[tx][r] = (gm < Md && gk < Kd) ? A[(size_t)gm * lda + gk] : 0.f;
        }
        const int bc = t & 63;
        const int br = t >> 6;
        #pragma unroll
        for (int i = 0; i < 4; i++) {
            int r  = br + i * 4;
            int gk = k0 + r;
            int gn = n0 + bc;
            Bs[r][bc] = (gk < Kd && gn < Nd) ? Bm[(size_t)gk * ldb + gn] : 0.f;
        }
        __syncthreads();

        #pragma unroll
        for (int kk = 0; kk < 16; kk++) {
            float4 a4 = *(const float4*)&As[kk][ty * 4];
            float4 b4 = *(const float4*)&Bs[kk][tx * 4];
            float av[4] = {a4.x, a4.y, a4.z, a4.w};
            float bv[4] = {b4.x, b4.y, b4.z, b4.w};
            #pragma unroll
            for (int i = 0; i < 4; i++)
                #pragma unroll
                for (int j = 0; j < 4; j++)
                    acc[i][j] = fmaf(av[i], bv[j], acc[i][j]);
        }
        __syncthreads();
    }

    #pragma unroll
    for (int i = 0; i < 4; i++) {
        int gm = m0 + ty * 4 + i;
        if (gm >= Md) continue;
        #pragma unroll
        for (int j = 0; j < 4; j++) {
            int gn = n0 + tx * 4 + j;
            if (gn >= Nd) continue;
            float v = acc[i][j];
            if (BIAS) v += bias[gn];
            if (ACT == 1) v = fmaxf(v, 0.f) + log1pf(expf(-fabsf(v)));
            C[(size_t)gm * ldc + gn] = v;
        }
    }
}

// ---------------------------------------------------------------------------
// fp32 -> bf16 flat convert (n % 1024 == 0)
// ---------------------------------------------------------------------------
__global__ __launch_bounds__(256) void f32_to_bf16_kernel(
    const float* __restrict__ in, unsigned short* __restrict__ out, int n4)
{
    int i = (blockIdx.x * 256 + threadIdx.x) * 4;
    float4 v = *(const float4*)&in[i];
    out[i + 0] = f2bf(v.x);
    out[i + 1] = f2bf(v.y);
    out[i + 2] = f2bf(v.z);
    out[i + 3] = f2bf(v.w);
}

// ---------------------------------------------------------------------------
// Transpose fp32 [K][N] -> bf16 [N][K]  (K,N multiples of 32)
// ---------------------------------------------------------------------------
__global__ __launch_bounds__(256) void transpose_f32_bf16(
    const float* __restrict__ in, unsigned short* __restrict__ out, int K, int N)
{
    __shared__ float t[32][33];
    int k0 = blockIdx.x * 32, n0 = blockIdx.y * 32;
    int tx = threadIdx.x & 31, ty = threadIdx.x >> 5;   // ty 0..7
    #pragma unroll
    for (int i = 0; i < 4; i++)
        t[ty + i * 8][tx] = in[(size_t)(k0 + ty + i * 8) * N + n0 + tx];
    __syncthreads();
    #pragma unroll
    for (int i = 0; i < 4; i++)
        out[(size_t)(n0 + ty + i * 8) * K + k0 + tx] = f2bf(t[tx][ty + i * 8]);
}

// ---------------------------------------------------------------------------
// Causal depthwise conv (K=4) + bias + SiLU; xz is bf16 with row stride 2*DI.
// ---------------------------------------------------------------------------
__global__ __launch_bounds__(256) void conv_silu_kernel(
    const unsigned short* __restrict__ xz, const float* __restrict__ conv_w,
    const float* __restrict__ conv_b, float* __restrict__ xc)
{
    int idx = blockIdx.x * 256 + threadIdx.x;
    if (idx >= Bb * Ll * DI) return;
    int d  = idx & (DI - 1);
    int bl = idx >> 11;
    int l  = bl % Ll;

    float acc = conv_b[d];
    #pragma unroll
    for (int k = 0; k < Kc; k++) {
        int ls = l + k - (Kc - 1);
        if (ls >= 0)
            acc = fmaf(conv_w[d * Kc + k], bf2f(xz[(size_t)(bl + ls - l) * (2 * DI) + d]), acc);
    }
    xc[idx] = acc / (1.f + expf(-acc));
}

// ---------------------------------------------------------------------------
// Selective scan: one thread per (b,d); fused D*xc + silu(z) gate; bf16 out.
// ---------------------------------------------------------------------------
__global__ __launch_bounds__(256) void scan_kernel(
    const float* __restrict__ delta, const float* __restrict__ xc,
    const unsigned short* __restrict__ xz, const float* __restrict__ proj,
    const float* __restrict__ A_log, const float* __restrict__ Dv,
    unsigned short* __restrict__ y)
{
    int d = blockIdx.x * 256 + threadIdx.x;
    int b = blockIdx.y;

    float Ar[Nst];
    #pragma unroll
    for (int n = 0; n < Nst; n++) Ar[n] = -expf(A_log[(size_t)d * Nst + n]);
    const float Dd = Dv[d];

    float h[Nst];
    #pragma unroll
    for (int n = 0; n < Nst; n++) h[n] = 0.f;

    for (int l = 0; l < Ll; l++) {
        size_t bl = (size_t)b * Ll + l;
        float dl  = delta[bl * DI + d];
        float xcv = xc[bl * DI + d];
        float zv  = bf2f(xz[bl * (2 * DI) + DI + d]);
        float dx  = dl * xcv;
        const float* p = proj + bl * (DTR + 2 * Nst);

        float yacc = 0.f;
        #pragma unroll
        for (int n = 0; n < Nst; n++) {
            float dA = expf(dl * Ar[n]);
            h[n] = fmaf(dA, h[n], dx * p[DTR + n]);
            yacc = fmaf(h[n], p[DTR + Nst + n], yacc);
        }
        float yv = yacc + Dd * xcv;
        yv *= zv / (1.f + expf(-zv));
        y[bl * DI + d] = f2bf(yv);
    }
}

// ---------------------------------------------------------------------------
// logits[M,16] = out_bf[M,1024] @ W_out[1024,16] + b_out
// ---------------------------------------------------------------------------
__global__ __launch_bounds__(256) void gemm_n16(
    const unsigned short* __restrict__ A, const float* __restrict__ W,
    const float* __restrict__ bias, float* __restrict__ C, int Kd)
{
    int m  = blockIdx.x;
    int t  = threadIdx.x;
    int c  = t & 15;
    int kg = t >> 4;
    const unsigned short* a = A + (size_t)m * Kd;

    float acc = 0.f;
    for (int k = kg; k < Kd; k += 16)
        acc = fmaf(bf2f(a[k]), W[k * NC + c], acc);

    __shared__ float red[256];
    red[t] = acc;
    __syncthreads();
    #pragma unroll
    for (int s = 128; s >= 16; s >>= 1) {
        if (t < s) red[t] += red[t + s];
        __syncthreads();
    }
    if (t < 16) C[(size_t)m * NC + t] = red[t] + bias[t];
}

// ---------------------------------------------------------------------------
extern "C" void kernel_launch(void* const* d_in, const int* in_sizes, int n_in,
                              void* d_out, int out_size, void* d_ws, size_t ws_size,
                              hipStream_t stream) {
    const float* x         = (const float*)d_in[0];
    const float* W_in      = (const float*)d_in[1];
    const float* b_in      = (const float*)d_in[2];
    const float* in_proj_w = (const float*)d_in[3];
    const float* conv_w    = (const float*)d_in[4];
    const float* conv_b    = (const float*)d_in[5];
    const float* x_proj_w  = (const float*)d_in[6];
    const float* dt_proj_w = (const float*)d_in[7];
    const float* dt_proj_b = (const float*)d_in[8];
    const float* A_log     = (const float*)d_in[9];
    const float* Dv        = (const float*)d_in[10];
    const float* out_proj  = (const float*)d_in[11];
    const float* W_out     = (const float*)d_in[12];
    const float* b_out     = (const float*)d_in[13];
    float* logits = (float*)d_out;

    // Workspace layout (bytes, 256-aligned)
    char* base = (char*)d_ws;
    size_t off = 0;
    auto alloc = [&](size_t bytes) {
        char* p = base + off;
        off += (bytes + 255) & ~(size_t)255;
        return p;
    };
    unsigned short* x_bf   = (unsigned short*)alloc((size_t)M * DIN * 2);
    unsigned short* Wt_in  = (unsigned short*)alloc((size_t)Hh * DIN * 2);
    unsigned short* Wt_ip  = (unsigned short*)alloc((size_t)(2 * DI) * Hh * 2);
    unsigned short* Wt_op  = (unsigned short*)alloc((size_t)Hh * DI * 2);
    unsigned short* h_bf   = (unsigned short*)alloc((size_t)M * Hh * 2);
    unsigned short* xz_bf  = (unsigned short*)alloc((size_t)M * 2 * DI * 2);
    float*          xc     = (float*)alloc((size_t)M * DI * 4);
    float*          proj   = (float*)alloc((size_t)M * 96 * 4);
    float*          delta  = (float*)alloc((size_t)M * DI * 4);
    unsigned short* y_bf   = (unsigned short*)alloc((size_t)M * DI * 2);
    unsigned short* out_bf = (unsigned short*)alloc((size_t)M * Hh * 2);

    dim3 blk(256);

    // 0) conversions / weight transposes
    f32_to_bf16_kernel<<<dim3((M * DIN) / 1024), blk, 0, stream>>>(x, x_bf, M * DIN);
    transpose_f32_bf16<<<dim3(DIN / 32, Hh / 32), blk, 0, stream>>>(W_in, Wt_in, DIN, Hh);
    transpose_f32_bf16<<<dim3(Hh / 32, (2 * DI) / 32), blk, 0, stream>>>(in_proj_w, Wt_ip, Hh, 2 * DI);
    transpose_f32_bf16<<<dim3(DI / 32, Hh / 32), blk, 0, stream>>>(out_proj, Wt_op, DI, Hh);

    // 1) h = x @ W_in + b_in
    gemm_mfma_bf16<true><<<dim3(13, Hh / 64), blk, 0, stream>>>(
        x_bf, Wt_in, b_in, h_bf, M, Hh, DIN);

    // 2) xz = h @ in_proj_w
    gemm_mfma_bf16<false><<<dim3(13, (2 * DI) / 64), blk, 0, stream>>>(
        h_bf, Wt_ip, nullptr, xz_bf, M, 2 * DI, Hh);

    // 3) xc = silu(conv(xm) + conv_b)
    conv_silu_kernel<<<dim3((Bb * Ll * DI) / 256), blk, 0, stream>>>(
        xz_bf, conv_w, conv_b, xc);

    // 4) proj = xc @ x_proj_w   [1600,2048]@[2048,96]
    gemm_f32<0, false><<<dim3(25, 2), blk, 0, stream>>>(
        xc, x_proj_w, nullptr, proj, M, DTR + 2 * Nst, DI, DI, DTR + 2 * Nst, DTR + 2 * Nst);

    // 5) delta = softplus(proj[:,:64] @ dt_proj_w + dt_proj_b)
    gemm_f32<1, true><<<dim3(25, DI / 64), blk, 0, stream>>>(
        proj, dt_proj_w, dt_proj_b, delta, M, DI, DTR, DTR + 2 * Nst, DI, DI);

    // 6) selective scan
    scan_kernel<<<dim3(DI / 256, Bb), blk, 0, stream>>>(
        delta, xc, xz_bf, proj, A_log, Dv, y_bf);

    // 7) out = y @ out_proj_w
    gemm_mfma_bf16<false><<<dim3(13, Hh / 64), blk, 0, stream>>>(
        y_bf, Wt_op, nullptr, out_bf, M, Hh, DI);

    // 8) logits = out @ W_out + b_out
    gemm_n16<<<dim3(M), blk, 0, stream>>>(out_bf, W_out, b_out, logits, Hh);
}

// Round 3
// 473.337 us; speedup vs baseline: 4.1708x; 1.5258x over previous
//
#include <hip/hip_runtime.h>
#include <hip/hip_bf16.h>
#include <stdint.h>

// Problem constants
constexpr int Bb  = 16;
constexpr int Ll  = 100;
constexpr int DIN = 6144;
constexpr int Hh  = 1024;
constexpr int DI  = 2048;
constexpr int Nst = 16;
constexpr int DTR = 64;
constexpr int Kc  = 4;
constexpr int NC  = 16;
constexpr int M   = Bb * Ll;   // 1600 tokens

typedef __attribute__((ext_vector_type(8))) short short8;
typedef __attribute__((ext_vector_type(4))) float floatx4;

__device__ __forceinline__ float bf2f(unsigned short u) {
    union { uint32_t b; float f; } x; x.b = ((uint32_t)u) << 16; return x.f;
}
__device__ __forceinline__ unsigned short f2bf(float f) {
    union { float f; uint32_t b; } x; x.f = f;
    uint32_t r = x.b + 0x7FFF + ((x.b >> 16) & 1);   // RNE
    return (unsigned short)(r >> 16);
}

// ---------------------------------------------------------------------------
// bf16 MFMA GEMM: C[M,N] = A[M,K] @ Bt[N,K]^T (+bias) (+softplus), fp32 acc.
// BM=128, BN=64, BK=32. 256 threads = 4 waves (2x2), wave tile 64x32 (4x2 frags).
// A row stride = lda (elements). Outputs: fp32 C32 and/or bf16 C16.
// LDS: cell(g,r) = 16B of 8 k-elems at (g*ROWS+r)*16B -> linear for
// global_load_lds, conflict-free ds_read_b128.
// ---------------------------------------------------------------------------
template<bool BIAS, int ACT, bool W32, bool W16>
__global__ __launch_bounds__(256) void gemm_mfma(
    const unsigned short* __restrict__ A,   // [Md x lda]
    int lda,
    const unsigned short* __restrict__ Bt,  // [Nd x Kd]
    const float* __restrict__ bias,         // [Nd]
    float* __restrict__ C32,
    unsigned short* __restrict__ C16,
    int Md, int Nd, int Kd)
{
    __shared__ short As[4 * 128 * 8];   // 8 KB
    __shared__ short Bs[4 * 64 * 8];    // 4 KB

    const int tid  = threadIdx.x;
    const int lane = tid & 63;
    const int wid  = tid >> 6;
    const int wr   = wid >> 1;
    const int wc   = wid & 1;
    const int l15  = lane & 15;
    const int kg   = lane >> 4;
    const int m0   = blockIdx.x * 128;
    const int n0   = blockIdx.y * 64;

    floatx4 acc[4][2];
    #pragma unroll
    for (int m = 0; m < 4; m++)
        #pragma unroll
        for (int n = 0; n < 2; n++)
            acc[m][n] = (floatx4){0.f, 0.f, 0.f, 0.f};

    for (int k0 = 0; k0 < Kd; k0 += 32) {
        // Stage A tile: 512 cells x 16B
        #pragma unroll
        for (int j = 0; j < 2; j++) {
            int c = j * 256 + tid;
            int g = c >> 7, r = c & 127;
            int grow = m0 + r; grow = grow < Md ? grow : Md - 1;
            const __attribute__((address_space(1))) short* src =
                (const __attribute__((address_space(1))) short*)(A + (size_t)grow * lda + k0 + g * 8);
            __builtin_amdgcn_global_load_lds(
                (const __attribute__((address_space(1))) void*)src,
                (__attribute__((address_space(3))) void*)&As[c * 8], 16, 0, 0);
        }
        // Stage B tile: 256 cells x 16B (clamp row for Nd not multiple of 64)
        {
            int c = tid;
            int g = c >> 6, r = c & 63;
            int brow = n0 + r; brow = brow < Nd ? brow : Nd - 1;
            const __attribute__((address_space(1))) short* src =
                (const __attribute__((address_space(1))) short*)(Bt + (size_t)brow * Kd + k0 + g * 8);
            __builtin_amdgcn_global_load_lds(
                (const __attribute__((address_space(1))) void*)src,
                (__attribute__((address_space(3))) void*)&Bs[c * 8], 16, 0, 0);
        }
        __syncthreads();

        short8 a[4], b[2];
        #pragma unroll
        for (int m = 0; m < 4; m++)
            a[m] = *(const short8*)&As[(kg * 128 + wr * 64 + m * 16 + l15) * 8];
        #pragma unroll
        for (int n = 0; n < 2; n++)
            b[n] = *(const short8*)&Bs[(kg * 64 + wc * 32 + n * 16 + l15) * 8];

        #pragma unroll
        for (int m = 0; m < 4; m++)
            #pragma unroll
            for (int n = 0; n < 2; n++)
                acc[m][n] = __builtin_amdgcn_mfma_f32_16x16x32_bf16(a[m], b[n], acc[m][n], 0, 0, 0);

        __syncthreads();
    }

    // Epilogue: D layout col=lane&15, row=(lane>>4)*4+q
    #pragma unroll
    for (int n = 0; n < 2; n++) {
        int col = n0 + wc * 32 + n * 16 + l15;
        if (col >= Nd) continue;
        float bv = BIAS ? bias[col] : 0.f;
        #pragma unroll
        for (int m = 0; m < 4; m++) {
            #pragma unroll
            for (int q = 0; q < 4; q++) {
                int row = m0 + wr * 64 + m * 16 + kg * 4 + q;
                if (row >= Md) continue;
                float v = acc[m][n][q] + bv;
                if (ACT == 1) v = fmaxf(v, 0.f) + log1pf(expf(-fabsf(v)));  // softplus
                if (W32) C32[(size_t)row * Nd + col] = v;
                if (W16) C16[(size_t)row * Nd + col] = f2bf(v);
            }
        }
    }
}

// ---------------------------------------------------------------------------
// fp32 -> bf16 flat convert (n % 1024 == 0)
// ---------------------------------------------------------------------------
__global__ __launch_bounds__(256) void f32_to_bf16_kernel(
    const float* __restrict__ in, unsigned short* __restrict__ out, int n4)
{
    int i = (blockIdx.x * 256 + threadIdx.x) * 4;
    float4 v = *(const float4*)&in[i];
    out[i + 0] = f2bf(v.x);
    out[i + 1] = f2bf(v.y);
    out[i + 2] = f2bf(v.z);
    out[i + 3] = f2bf(v.w);
}

// ---------------------------------------------------------------------------
// Transpose fp32 [K][N] -> bf16 [N][K]  (K,N multiples of 32)
// ---------------------------------------------------------------------------
__global__ __launch_bounds__(256) void transpose_f32_bf16(
    const float* __restrict__ in, unsigned short* __restrict__ out, int K, int N)
{
    __shared__ float t[32][33];
    int k0 = blockIdx.x * 32, n0 = blockIdx.y * 32;
    int tx = threadIdx.x & 31, ty = threadIdx.x >> 5;   // ty 0..7
    #pragma unroll
    for (int i = 0; i < 4; i++)
        t[ty + i * 8][tx] = in[(size_t)(k0 + ty + i * 8) * N + n0 + tx];
    __syncthreads();
    #pragma unroll
    for (int i = 0; i < 4; i++)
        out[(size_t)(n0 + ty + i * 8) * K + k0 + tx] = f2bf(t[tx][ty + i * 8]);
}

// ---------------------------------------------------------------------------
// Causal depthwise conv (K=4) + bias + SiLU; xz is bf16 with row stride 2*DI.
// Writes xc as fp32 (for scan) and bf16 (for proj GEMM).
// ---------------------------------------------------------------------------
__global__ __launch_bounds__(256) void conv_silu_kernel(
    const unsigned short* __restrict__ xz, const float* __restrict__ conv_w,
    const float* __restrict__ conv_b, float* __restrict__ xc,
    unsigned short* __restrict__ xc_bf)
{
    int idx = blockIdx.x * 256 + threadIdx.x;
    if (idx >= Bb * Ll * DI) return;
    int d  = idx & (DI - 1);
    int bl = idx >> 11;
    int l  = bl % Ll;

    float acc = conv_b[d];
    #pragma unroll
    for (int k = 0; k < Kc; k++) {
        int ls = l + k - (Kc - 1);
        if (ls >= 0)
            acc = fmaf(conv_w[d * Kc + k], bf2f(xz[(size_t)(bl + ls - l) * (2 * DI) + d]), acc);
    }
    float s = acc / (1.f + expf(-acc));
    xc[idx] = s;
    xc_bf[idx] = f2bf(s);
}

// ---------------------------------------------------------------------------
// Selective scan: one thread per (b,d); fused D*xc + silu(z) gate; bf16 out.
// delta, xc, proj are fp32; z read from bf16 xz.
// ---------------------------------------------------------------------------
__global__ __launch_bounds__(256) void scan_kernel(
    const float* __restrict__ delta, const float* __restrict__ xc,
    const unsigned short* __restrict__ xz, const float* __restrict__ proj,
    const float* __restrict__ A_log, const float* __restrict__ Dv,
    unsigned short* __restrict__ y)
{
    int d = blockIdx.x * 256 + threadIdx.x;
    int b = blockIdx.y;

    float Ar[Nst];
    #pragma unroll
    for (int n = 0; n < Nst; n++) Ar[n] = -expf(A_log[(size_t)d * Nst + n]);
    const float Dd = Dv[d];

    float h[Nst];
    #pragma unroll
    for (int n = 0; n < Nst; n++) h[n] = 0.f;

    for (int l = 0; l < Ll; l++) {
        size_t bl = (size_t)b * Ll + l;
        float dl  = delta[bl * DI + d];
        float xcv = xc[bl * DI + d];
        float zv  = bf2f(xz[bl * (2 * DI) + DI + d]);
        float dx  = dl * xcv;
        const float* p = proj + bl * (DTR + 2 * Nst);

        float yacc = 0.f;
        #pragma unroll
        for (int n = 0; n < Nst; n++) {
            float dA = expf(dl * Ar[n]);
            h[n] = fmaf(dA, h[n], dx * p[DTR + n]);
            yacc = fmaf(h[n], p[DTR + Nst + n], yacc);
        }
        float yv = yacc + Dd * xcv;
        yv *= zv / (1.f + expf(-zv));
        y[bl * DI + d] = f2bf(yv);
    }
}

// ---------------------------------------------------------------------------
// logits[M,16] = out_bf[M,1024] @ W_out[1024,16] + b_out
// ---------------------------------------------------------------------------
__global__ __launch_bounds__(256) void gemm_n16(
    const unsigned short* __restrict__ A, const float* __restrict__ W,
    const float* __restrict__ bias, float* __restrict__ C, int Kd)
{
    int m  = blockIdx.x;
    int t  = threadIdx.x;
    int c  = t & 15;
    int kg = t >> 4;
    const unsigned short* a = A + (size_t)m * Kd;

    float acc = 0.f;
    for (int k = kg; k < Kd; k += 16)
        acc = fmaf(bf2f(a[k]), W[k * NC + c], acc);

    __shared__ float red[256];
    red[t] = acc;
    __syncthreads();
    #pragma unroll
    for (int s = 128; s >= 16; s >>= 1) {
        if (t < s) red[t] += red[t + s];
        __syncthreads();
    }
    if (t < 16) C[(size_t)m * NC + t] = red[t] + bias[t];
}

// ---------------------------------------------------------------------------
extern "C" void kernel_launch(void* const* d_in, const int* in_sizes, int n_in,
                              void* d_out, int out_size, void* d_ws, size_t ws_size,
                              hipStream_t stream) {
    const float* x         = (const float*)d_in[0];
    const float* W_in      = (const float*)d_in[1];
    const float* b_in      = (const float*)d_in[2];
    const float* in_proj_w = (const float*)d_in[3];
    const float* conv_w    = (const float*)d_in[4];
    const float* conv_b    = (const float*)d_in[5];
    const float* x_proj_w  = (const float*)d_in[6];
    const float* dt_proj_w = (const float*)d_in[7];
    const float* dt_proj_b = (const float*)d_in[8];
    const float* A_log     = (const float*)d_in[9];
    const float* Dv        = (const float*)d_in[10];
    const float* out_proj  = (const float*)d_in[11];
    const float* W_out     = (const float*)d_in[12];
    const float* b_out     = (const float*)d_in[13];
    float* logits = (float*)d_out;

    // Workspace layout (bytes, 256-aligned)
    char* base = (char*)d_ws;
    size_t off = 0;
    auto alloc = [&](size_t bytes) {
        char* p = base + off;
        off += (bytes + 255) & ~(size_t)255;
        return p;
    };
    unsigned short* x_bf    = (unsigned short*)alloc((size_t)M * DIN * 2);
    unsigned short* Wt_in   = (unsigned short*)alloc((size_t)Hh * DIN * 2);
    unsigned short* Wt_ip   = (unsigned short*)alloc((size_t)(2 * DI) * Hh * 2);
    unsigned short* Wt_op   = (unsigned short*)alloc((size_t)Hh * DI * 2);
    unsigned short* xpw_t   = (unsigned short*)alloc((size_t)96 * DI * 2);
    unsigned short* dtw_t   = (unsigned short*)alloc((size_t)DI * DTR * 2);
    unsigned short* h_bf    = (unsigned short*)alloc((size_t)M * Hh * 2);
    unsigned short* xz_bf   = (unsigned short*)alloc((size_t)M * 2 * DI * 2);
    float*          xc      = (float*)alloc((size_t)M * DI * 4);
    unsigned short* xc_bf   = (unsigned short*)alloc((size_t)M * DI * 2);
    float*          proj_f  = (float*)alloc((size_t)M * 96 * 4);
    unsigned short* proj_bf = (unsigned short*)alloc((size_t)M * 96 * 2);
    float*          delta   = (float*)alloc((size_t)M * DI * 4);
    unsigned short* y_bf    = (unsigned short*)alloc((size_t)M * DI * 2);
    unsigned short* out_bf  = (unsigned short*)alloc((size_t)M * Hh * 2);

    dim3 blk(256);

    // 0) conversions / weight transposes
    f32_to_bf16_kernel<<<dim3((M * DIN) / 1024), blk, 0, stream>>>(x, x_bf, M * DIN);
    transpose_f32_bf16<<<dim3(DIN / 32, Hh / 32), blk, 0, stream>>>(W_in, Wt_in, DIN, Hh);
    transpose_f32_bf16<<<dim3(Hh / 32, (2 * DI) / 32), blk, 0, stream>>>(in_proj_w, Wt_ip, Hh, 2 * DI);
    transpose_f32_bf16<<<dim3(DI / 32, Hh / 32), blk, 0, stream>>>(out_proj, Wt_op, DI, Hh);
    transpose_f32_bf16<<<dim3(DI / 32, 96 / 32), blk, 0, stream>>>(x_proj_w, xpw_t, DI, 96);
    transpose_f32_bf16<<<dim3(DTR / 32, DI / 32), blk, 0, stream>>>(dt_proj_w, dtw_t, DTR, DI);

    // 1) h = x @ W_in + b_in           [1600,6144]@[6144,1024]
    gemm_mfma<true, 0, false, true><<<dim3(13, Hh / 64), blk, 0, stream>>>(
        x_bf, DIN, Wt_in, b_in, nullptr, h_bf, M, Hh, DIN);

    // 2) xz = h @ in_proj_w            [1600,1024]@[1024,4096]
    gemm_mfma<false, 0, false, true><<<dim3(13, (2 * DI) / 64), blk, 0, stream>>>(
        h_bf, Hh, Wt_ip, nullptr, nullptr, xz_bf, M, 2 * DI, Hh);

    // 3) xc = silu(conv(xm) + conv_b)  -> fp32 + bf16
    conv_silu_kernel<<<dim3((Bb * Ll * DI) / 256), blk, 0, stream>>>(
        xz_bf, conv_w, conv_b, xc, xc_bf);

    // 4) proj = xc @ x_proj_w          [1600,2048]@[2048,96] -> fp32 + bf16
    gemm_mfma<false, 0, true, true><<<dim3(13, 2), blk, 0, stream>>>(
        xc_bf, DI, xpw_t, nullptr, proj_f, proj_bf, M, 96, DI);

    // 5) delta = softplus(proj[:,:64] @ dt_proj_w + dt_proj_b)  [1600,64]@[64,2048]
    gemm_mfma<true, 1, true, false><<<dim3(13, DI / 64), blk, 0, stream>>>(
        proj_bf, 96, dtw_t, dt_proj_b, delta, nullptr, M, DI, DTR);

    // 6) selective scan
    scan_kernel<<<dim3(DI / 256, Bb), blk, 0, stream>>>(
        delta, xc, xz_bf, proj_f, A_log, Dv, y_bf);

    // 7) out = y @ out_proj_w          [1600,2048]@[2048,1024]
    gemm_mfma<false, 0, false, true><<<dim3(13, Hh / 64), blk, 0, stream>>>(
        y_bf, DI, Wt_op, nullptr, nullptr, out_bf, M, Hh, DI);

    // 8) logits = out @ W_out + b_out  [1600,1024]@[1024,16]
    gemm_n16<<<dim3(M), blk, 0, stream>>>(out_bf, W_out, b_out, logits, Hh);
}

// Round 4
// 379.649 us; speedup vs baseline: 5.2001x; 1.2468x over previous
//
#include <hip/hip_runtime.h>
#include <hip/hip_bf16.h>
#include <stdint.h>

// Problem constants
constexpr int Bb  = 16;
constexpr int Ll  = 100;
constexpr int DIN = 6144;
constexpr int Hh  = 1024;
constexpr int DI  = 2048;
constexpr int Nst = 16;
constexpr int DTR = 64;
constexpr int Kc  = 4;
constexpr int NC  = 16;
constexpr int M   = Bb * Ll;   // 1600 tokens

typedef __attribute__((ext_vector_type(8))) short short8;
typedef __attribute__((ext_vector_type(4))) float floatx4;

__device__ __forceinline__ float bf2f(unsigned short u) {
    union { uint32_t b; float f; } x; x.b = ((uint32_t)u) << 16; return x.f;
}
__device__ __forceinline__ unsigned short f2bf(float f) {
    union { float f; uint32_t b; } x; x.f = f;
    uint32_t r = x.b + 0x7FFF + ((x.b >> 16) & 1);   // RNE
    return (unsigned short)(r >> 16);
}

// ---------------------------------------------------------------------------
// bf16 MFMA GEMM: C[M,N] = A[M,K] @ Bt[N,K]^T, fp32 acc.
// BM=128, BN=64, BK=64, double-buffered LDS (2-phase pipeline).
// 256 threads = 4 waves (2x2), wave tile 64x32: a[2][4], b[2][2], 16 MFMA/step.
// SPLIT: grid.z slices K; each z writes fp32 partial to Cpart[z][Md][Nd];
//        reduce_split sums + applies bias/act. Deterministic (no atomics).
// LDS: cell(g,r) = 16B of 8 k-elems at (g*ROWS+r)*16B -> linear for
// global_load_lds, measured 0 bank conflicts on ds_read_b128.
// ---------------------------------------------------------------------------
template<bool SPLIT, bool BIAS, int ACT, bool W32, bool W16>
__global__ __launch_bounds__(256) void gemm_mfma(
    const unsigned short* __restrict__ A, int lda,    // [Md x lda]
    const unsigned short* __restrict__ Bt, int ldb,   // [Nd x ldb]
    const float* __restrict__ bias,                   // [Nd]
    float* __restrict__ C32,
    unsigned short* __restrict__ C16,
    float* __restrict__ Cpart,
    int Md, int Nd, int Kslab)                        // Kslab = K per z-slice
{
    __shared__ short As[2][8 * 128 * 8];   // 16 KB per buf
    __shared__ short Bs[2][8 * 64 * 8];    // 8 KB per buf

    const int tid  = threadIdx.x;
    const int lane = tid & 63;
    const int wid  = tid >> 6;
    const int wr   = wid >> 1;
    const int wc   = wid & 1;
    const int l15  = lane & 15;
    const int kg   = lane >> 4;
    const int m0   = blockIdx.x * 128;
    const int n0   = blockIdx.y * 64;
    const int kbeg = SPLIT ? blockIdx.z * Kslab : 0;

    floatx4 acc[4][2];
    #pragma unroll
    for (int m = 0; m < 4; m++)
        #pragma unroll
        for (int n = 0; n < 2; n++)
            acc[m][n] = (floatx4){0.f, 0.f, 0.f, 0.f};

    auto stage = [&](int buf, int k0) {
        // A: 1024 cells x 16B (128 rows x 8 k-groups)
        #pragma unroll
        for (int j = 0; j < 4; j++) {
            int c = j * 256 + tid;
            int g = c >> 7, r = c & 127;
            int grow = m0 + r; grow = grow < Md ? grow : Md - 1;
            const __attribute__((address_space(1))) short* src =
                (const __attribute__((address_space(1))) short*)(A + (size_t)grow * lda + k0 + g * 8);
            __builtin_amdgcn_global_load_lds(
                (const __attribute__((address_space(1))) void*)src,
                (__attribute__((address_space(3))) void*)&As[buf][c * 8], 16, 0, 0);
        }
        // B: 512 cells x 16B (64 rows x 8 k-groups)
        #pragma unroll
        for (int j = 0; j < 2; j++) {
            int c = j * 256 + tid;
            int g = c >> 6, r = c & 63;
            int brow = n0 + r; brow = brow < Nd ? brow : Nd - 1;
            const __attribute__((address_space(1))) short* src =
                (const __attribute__((address_space(1))) short*)(Bt + (size_t)brow * ldb + k0 + g * 8);
            __builtin_amdgcn_global_load_lds(
                (const __attribute__((address_space(1))) void*)src,
                (__attribute__((address_space(3))) void*)&Bs[buf][c * 8], 16, 0, 0);
        }
    };

    stage(0, kbeg);
    __syncthreads();

    const int nt = Kslab >> 6;
    for (int t = 0; t < nt; t++) {
        const int cur = t & 1;
        if (t + 1 < nt) stage(cur ^ 1, kbeg + (t + 1) * 64);   // prefetch next

        short8 a[2][4], b[2][2];
        #pragma unroll
        for (int kk = 0; kk < 2; kk++) {
            #pragma unroll
            for (int m = 0; m < 4; m++)
                a[kk][m] = *(const short8*)&As[cur][((kk * 4 + kg) * 128 + wr * 64 + m * 16 + l15) * 8];
            #pragma unroll
            for (int n = 0; n < 2; n++)
                b[kk][n] = *(const short8*)&Bs[cur][((kk * 4 + kg) * 64 + wc * 32 + n * 16 + l15) * 8];
        }
        #pragma unroll
        for (int kk = 0; kk < 2; kk++)
            #pragma unroll
            for (int m = 0; m < 4; m++)
                #pragma unroll
                for (int n = 0; n < 2; n++)
                    acc[m][n] = __builtin_amdgcn_mfma_f32_16x16x32_bf16(a[kk][m], b[kk][n], acc[m][n], 0, 0, 0);

        __syncthreads();   // drains prefetch (vmcnt0) + protects cur for overwrite
    }

    // Epilogue: D layout col=lane&15, row=(lane>>4)*4+q
    if (SPLIT) {
        float* P = Cpart + (size_t)blockIdx.z * Md * Nd;
        #pragma unroll
        for (int n = 0; n < 2; n++) {
            int col = n0 + wc * 32 + n * 16 + l15;
            if (col >= Nd) continue;
            #pragma unroll
            for (int m = 0; m < 4; m++)
                #pragma unroll
                for (int q = 0; q < 4; q++) {
                    int row = m0 + wr * 64 + m * 16 + kg * 4 + q;
                    if (row < Md) P[(size_t)row * Nd + col] = acc[m][n][q];
                }
        }
    } else {
        #pragma unroll
        for (int n = 0; n < 2; n++) {
            int col = n0 + wc * 32 + n * 16 + l15;
            if (col >= Nd) continue;
            float bv = BIAS ? bias[col] : 0.f;
            #pragma unroll
            for (int m = 0; m < 4; m++)
                #pragma unroll
                for (int q = 0; q < 4; q++) {
                    int row = m0 + wr * 64 + m * 16 + kg * 4 + q;
                    if (row >= Md) continue;
                    float v = acc[m][n][q] + bv;
                    if (ACT == 1) v = fmaxf(v, 0.f) + log1pf(expf(-fabsf(v)));  // softplus
                    if (W32) C32[(size_t)row * Nd + col] = v;
                    if (W16) C16[(size_t)row * Nd + col] = f2bf(v);
                }
        }
    }
}

// ---------------------------------------------------------------------------
// Sum S split-K partials + bias/act, write fp32 and/or bf16. total % 1024 == 0.
// nmask = Nd-1 (Nd power of 2) for bias addressing.
// ---------------------------------------------------------------------------
template<int S, bool BIAS, int ACT, bool W32, bool W16>
__global__ __launch_bounds__(256) void reduce_split(
    const float* __restrict__ P, const float* __restrict__ bias,
    float* __restrict__ C32, unsigned short* __restrict__ C16,
    int total, int nmask)
{
    int i = (blockIdx.x * 256 + threadIdx.x) * 4;
    float4 v = *(const float4*)&P[i];
    #pragma unroll
    for (int s = 1; s < S; s++) {
        float4 p = *(const float4*)&P[(size_t)s * total + i];
        v.x += p.x; v.y += p.y; v.z += p.z; v.w += p.w;
    }
    float r[4] = {v.x, v.y, v.z, v.w};
    #pragma unroll
    for (int j = 0; j < 4; j++) {
        float t = r[j];
        if (BIAS) t += bias[(i + j) & nmask];
        if (ACT == 1) t = fmaxf(t, 0.f) + log1pf(expf(-fabsf(t)));
        if (W32) C32[i + j] = t;
        if (W16) C16[i + j] = f2bf(t);
    }
}

// ---------------------------------------------------------------------------
// fp32 -> bf16 flat convert (n % 1024 == 0)
// ---------------------------------------------------------------------------
__global__ __launch_bounds__(256) void f32_to_bf16_kernel(
    const float* __restrict__ in, unsigned short* __restrict__ out, int n4)
{
    int i = (blockIdx.x * 256 + threadIdx.x) * 4;
    float4 v = *(const float4*)&in[i];
    out[i + 0] = f2bf(v.x);
    out[i + 1] = f2bf(v.y);
    out[i + 2] = f2bf(v.z);
    out[i + 3] = f2bf(v.w);
}

// ---------------------------------------------------------------------------
// Transpose fp32 [K][N] -> bf16 [N][K]  (K,N multiples of 32)
// ---------------------------------------------------------------------------
__global__ __launch_bounds__(256) void transpose_f32_bf16(
    const float* __restrict__ in, unsigned short* __restrict__ out, int K, int N)
{
    __shared__ float t[32][33];
    int k0 = blockIdx.x * 32, n0 = blockIdx.y * 32;
    int tx = threadIdx.x & 31, ty = threadIdx.x >> 5;   // ty 0..7
    #pragma unroll
    for (int i = 0; i < 4; i++)
        t[ty + i * 8][tx] = in[(size_t)(k0 + ty + i * 8) * N + n0 + tx];
    __syncthreads();
    #pragma unroll
    for (int i = 0; i < 4; i++)
        out[(size_t)(n0 + ty + i * 8) * K + k0 + tx] = f2bf(t[tx][ty + i * 8]);
}

// ---------------------------------------------------------------------------
// Causal depthwise conv (K=4) + bias + SiLU; xz is bf16 with row stride 2*DI.
// Writes xc as fp32 (for scan) and bf16 (for proj GEMM).
// ---------------------------------------------------------------------------
__global__ __launch_bounds__(256) void conv_silu_kernel(
    const unsigned short* __restrict__ xz, const float* __restrict__ conv_w,
    const float* __restrict__ conv_b, float* __restrict__ xc,
    unsigned short* __restrict__ xc_bf)
{
    int idx = blockIdx.x * 256 + threadIdx.x;
    if (idx >= Bb * Ll * DI) return;
    int d  = idx & (DI - 1);
    int bl = idx >> 11;
    int l  = bl % Ll;

    float acc = conv_b[d];
    #pragma unroll
    for (int k = 0; k < Kc; k++) {
        int ls = l + k - (Kc - 1);
        if (ls >= 0)
            acc = fmaf(conv_w[d * Kc + k], bf2f(xz[(size_t)(bl + ls - l) * (2 * DI) + d]), acc);
    }
    float s = acc / (1.f + expf(-acc));
    xc[idx] = s;
    xc_bf[idx] = f2bf(s);
}

// ---------------------------------------------------------------------------
// Selective scan: one thread per (b,d); fused D*xc + silu(z) gate; bf16 out.
// ---------------------------------------------------------------------------
__global__ __launch_bounds__(256) void scan_kernel(
    const float* __restrict__ delta, const float* __restrict__ xc,
    const unsigned short* __restrict__ xz, const float* __restrict__ proj,
    const float* __restrict__ A_log, const float* __restrict__ Dv,
    unsigned short* __restrict__ y)
{
    int d = blockIdx.x * 256 + threadIdx.x;
    int b = blockIdx.y;

    float Ar[Nst];
    #pragma unroll
    for (int n = 0; n < Nst; n++) Ar[n] = -expf(A_log[(size_t)d * Nst + n]);
    const float Dd = Dv[d];

    float h[Nst];
    #pragma unroll
    for (int n = 0; n < Nst; n++) h[n] = 0.f;

    for (int l = 0; l < Ll; l++) {
        size_t bl = (size_t)b * Ll + l;
        float dl  = delta[bl * DI + d];
        float xcv = xc[bl * DI + d];
        float zv  = bf2f(xz[bl * (2 * DI) + DI + d]);
        float dx  = dl * xcv;
        const float* p = proj + bl * (DTR + 2 * Nst);

        float yacc = 0.f;
        #pragma unroll
        for (int n = 0; n < Nst; n++) {
            float dA = expf(dl * Ar[n]);
            h[n] = fmaf(dA, h[n], dx * p[DTR + n]);
            yacc = fmaf(h[n], p[DTR + Nst + n], yacc);
        }
        float yv = yacc + Dd * xcv;
        yv *= zv / (1.f + expf(-zv));
        y[bl * DI + d] = f2bf(yv);
    }
}

// ---------------------------------------------------------------------------
// logits[M,16] = out_bf[M,1024] @ W_out[1024,16] + b_out
// ---------------------------------------------------------------------------
__global__ __launch_bounds__(256) void gemm_n16(
    const unsigned short* __restrict__ A, const float* __restrict__ W,
    const float* __restrict__ bias, float* __restrict__ C, int Kd)
{
    int m  = blockIdx.x;
    int t  = threadIdx.x;
    int c  = t & 15;
    int kg = t >> 4;
    const unsigned short* a = A + (size_t)m * Kd;

    float acc = 0.f;
    for (int k = kg; k < Kd; k += 16)
        acc = fmaf(bf2f(a[k]), W[k * NC + c], acc);

    __shared__ float red[256];
    red[t] = acc;
    __syncthreads();
    #pragma unroll
    for (int s = 128; s >= 16; s >>= 1) {
        if (t < s) red[t] += red[t + s];
        __syncthreads();
    }
    if (t < 16) C[(size_t)m * NC + t] = red[t] + bias[t];
}

// ---------------------------------------------------------------------------
extern "C" void kernel_launch(void* const* d_in, const int* in_sizes, int n_in,
                              void* d_out, int out_size, void* d_ws, size_t ws_size,
                              hipStream_t stream) {
    const float* x         = (const float*)d_in[0];
    const float* W_in      = (const float*)d_in[1];
    const float* b_in      = (const float*)d_in[2];
    const float* in_proj_w = (const float*)d_in[3];
    const float* conv_w    = (const float*)d_in[4];
    const float* conv_b    = (const float*)d_in[5];
    const float* x_proj_w  = (const float*)d_in[6];
    const float* dt_proj_w = (const float*)d_in[7];
    const float* dt_proj_b = (const float*)d_in[8];
    const float* A_log     = (const float*)d_in[9];
    const float* Dv        = (const float*)d_in[10];
    const float* out_proj  = (const float*)d_in[11];
    const float* W_out     = (const float*)d_in[12];
    const float* b_out     = (const float*)d_in[13];
    float* logits = (float*)d_out;

    // Workspace layout (bytes, 256-aligned). xc and delta are ADJACENT:
    // their combined 26.2MB region is reused for split-K partials
    // (P1: GEMM1, consumed before xc written; P2 in delta: proj partials,
    //  consumed before delta written; P3: GEMM7, xc/delta dead by then).
    char* base = (char*)d_ws;
    size_t off = 0;
    auto alloc = [&](size_t bytes) {
        char* p = base + off;
        off += (bytes + 255) & ~(size_t)255;
        return p;
    };
    unsigned short* x_bf    = (unsigned short*)alloc((size_t)M * DIN * 2);
    unsigned short* Wt_in   = (unsigned short*)alloc((size_t)Hh * DIN * 2);
    unsigned short* Wt_ip   = (unsigned short*)alloc((size_t)(2 * DI) * Hh * 2);
    unsigned short* Wt_op   = (unsigned short*)alloc((size_t)Hh * DI * 2);
    unsigned short* xpw_t   = (unsigned short*)alloc((size_t)96 * DI * 2);
    unsigned short* dtw_t   = (unsigned short*)alloc((size_t)DI * DTR * 2);
    unsigned short* h_bf    = (unsigned short*)alloc((size_t)M * Hh * 2);
    unsigned short* xz_bf   = (unsigned short*)alloc((size_t)M * 2 * DI * 2);
    float*          xc      = (float*)alloc((size_t)M * DI * 4);       // | 26.2MB partial
    float*          delta   = (float*)alloc((size_t)M * DI * 4);       // | region (P1/P3)
    unsigned short* xc_bf   = (unsigned short*)alloc((size_t)M * DI * 2);
    float*          proj_f  = (float*)alloc((size_t)M * 96 * 4);
    unsigned short* proj_bf = (unsigned short*)alloc((size_t)M * 96 * 2);
    unsigned short* y_bf    = (unsigned short*)alloc((size_t)M * DI * 2);
    unsigned short* out_bf  = (unsigned short*)alloc((size_t)M * Hh * 2);

    float* P14 = xc;      // 4-way partials for GEMM1 / GEMM7 (4*1600*1024*4 = 26.2MB)
    float* P8  = delta;   // 8-way partials for proj (8*1600*96*4 = 4.9MB)

    dim3 blk(256);

    // 0) conversions / weight transposes
    f32_to_bf16_kernel<<<dim3((M * DIN) / 1024), blk, 0, stream>>>(x, x_bf, M * DIN);
    transpose_f32_bf16<<<dim3(DIN / 32, Hh / 32), blk, 0, stream>>>(W_in, Wt_in, DIN, Hh);
    transpose_f32_bf16<<<dim3(Hh / 32, (2 * DI) / 32), blk, 0, stream>>>(in_proj_w, Wt_ip, Hh, 2 * DI);
    transpose_f32_bf16<<<dim3(DI / 32, Hh / 32), blk, 0, stream>>>(out_proj, Wt_op, DI, Hh);
    transpose_f32_bf16<<<dim3(DI / 32, 96 / 32), blk, 0, stream>>>(x_proj_w, xpw_t, DI, 96);
    transpose_f32_bf16<<<dim3(DTR / 32, DI / 32), blk, 0, stream>>>(dt_proj_w, dtw_t, DTR, DI);

    // 1) h = x @ W_in + b_in   [1600,6144]@[6144,1024], split-K 4 -> 832 blocks
    gemm_mfma<true, false, 0, false, false><<<dim3(13, Hh / 64, 4), blk, 0, stream>>>(
        x_bf, DIN, Wt_in, DIN, nullptr, nullptr, nullptr, P14, M, Hh, DIN / 4);
    reduce_split<4, true, 0, false, true><<<dim3((M * Hh) / 1024), blk, 0, stream>>>(
        P14, b_in, nullptr, h_bf, M * Hh, Hh - 1);

    // 2) xz = h @ in_proj_w    [1600,1024]@[1024,4096], 832 blocks, no split
    gemm_mfma<false, false, 0, false, true><<<dim3(13, (2 * DI) / 64, 1), blk, 0, stream>>>(
        h_bf, Hh, Wt_ip, Hh, nullptr, nullptr, xz_bf, nullptr, M, 2 * DI, Hh);

    // 3) xc = silu(conv(xm) + conv_b)  -> fp32 + bf16
    conv_silu_kernel<<<dim3((Bb * Ll * DI) / 256), blk, 0, stream>>>(
        xz_bf, conv_w, conv_b, xc, xc_bf);

    // 4) proj = xc @ x_proj_w  [1600,2048]@[2048,96], split-K 8 -> 208 blocks
    gemm_mfma<true, false, 0, false, false><<<dim3(13, 2, 8), blk, 0, stream>>>(
        xc_bf, DI, xpw_t, DI, nullptr, nullptr, nullptr, P8, M, 96, DI / 8);
    reduce_split<8, false, 0, true, true><<<dim3((M * 96) / 1024), blk, 0, stream>>>(
        P8, nullptr, proj_f, proj_bf, M * 96, 0);

    // 5) delta = softplus(proj[:,:64] @ dt_proj_w + dt_proj_b)  [1600,64]@[64,2048]
    gemm_mfma<false, true, 1, true, false><<<dim3(13, DI / 64, 1), blk, 0, stream>>>(
        proj_bf, 96, dtw_t, DTR, dt_proj_b, delta, nullptr, nullptr, M, DI, DTR);

    // 6) selective scan
    scan_kernel<<<dim3(DI / 256, Bb), blk, 0, stream>>>(
        delta, xc, xz_bf, proj_f, A_log, Dv, y_bf);

    // 7) out = y @ out_proj_w  [1600,2048]@[2048,1024], split-K 4 -> 832 blocks
    gemm_mfma<true, false, 0, false, false><<<dim3(13, Hh / 64, 4), blk, 0, stream>>>(
        y_bf, DI, Wt_op, DI, nullptr, nullptr, nullptr, P14, M, Hh, DI / 4);
    reduce_split<4, false, 0, false, true><<<dim3((M * Hh) / 1024), blk, 0, stream>>>(
        P14, nullptr, nullptr, out_bf, M * Hh, 0);

    // 8) logits = out @ W_out + b_out  [1600,1024]@[1024,16]
    gemm_n16<<<dim3(M), blk, 0, stream>>>(out_bf, W_out, b_out, logits, Hh);
}

// Round 5
// 361.891 us; speedup vs baseline: 5.4552x; 1.0491x over previous
//
#include <hip/hip_runtime.h>
#include <hip/hip_bf16.h>
#include <stdint.h>

// Problem constants
constexpr int Bb  = 16;
constexpr int Ll  = 100;
constexpr int DIN = 6144;
constexpr int Hh  = 1024;
constexpr int DI  = 2048;
constexpr int Nst = 16;
constexpr int DTR = 64;
constexpr int Kc  = 4;
constexpr int NC  = 16;
constexpr int M   = Bb * Ll;   // 1600 tokens

typedef __attribute__((ext_vector_type(8))) short short8;
typedef __attribute__((ext_vector_type(4))) float floatx4;

__device__ __forceinline__ float bf2f(unsigned short u) {
    union { uint32_t b; float f; } x; x.b = ((uint32_t)u) << 16; return x.f;
}
__device__ __forceinline__ unsigned short f2bf(float f) {
    union { float f; uint32_t b; } x; x.f = f;
    uint32_t r = x.b + 0x7FFF + ((x.b >> 16) & 1);   // RNE
    return (unsigned short)(r >> 16);
}

// ---------------------------------------------------------------------------
// bf16 MFMA GEMM: C[M,N] = A[M,K] @ Bt[N,K]^T, fp32 acc.
// BM=128, BN=64, BK=64, double-buffered LDS (2-phase pipeline).
// 256 threads = 4 waves (2x2), wave tile 64x32: 16 MFMA/step.
// XCD-aware chunked swizzle (requires gridtotal % 8 == 0; falls back if not):
// hardware round-robins linear block id over 8 XCDs -> give each XCD a
// contiguous chunk of (x-fastest) tile space for A/B panel L2 locality.
// SPLIT: z slices K; partials (fp32 or bf16) to Cpart[z][Md][Nd]; reduce_split*
// sums + bias/act. Deterministic (no atomics).
// ---------------------------------------------------------------------------
template<bool SPLIT, bool PARTBF, bool BIAS, int ACT, bool W32, bool W16>
__global__ __launch_bounds__(256) void gemm_mfma(
    const unsigned short* __restrict__ A, int lda,    // [Md x lda]
    const unsigned short* __restrict__ Bt, int ldb,   // [Nd x ldb]
    const float* __restrict__ bias,                   // [Nd]
    float* __restrict__ C32,
    unsigned short* __restrict__ C16,
    void* __restrict__ Cpart,
    int Md, int Nd, int Kslab)                        // Kslab = K per z-slice
{
    __shared__ short As[2][8 * 128 * 8];   // 16 KB per buf
    __shared__ short Bs[2][8 * 64 * 8];    // 8 KB per buf

    // XCD-aware block remap (bijective chunked transform)
    const int nx = gridDim.x, ny = gridDim.y, nz = gridDim.z;
    const int nb = nx * ny * nz;
    int id = blockIdx.x + nx * (blockIdx.y + ny * blockIdx.z);
    int bx, by, bz;
    if ((nb & 7) == 0) {
        int swz = (id & 7) * (nb >> 3) + (id >> 3);
        bx = swz % nx;
        int rem = swz / nx;
        by = rem % ny;
        bz = rem / ny;
    } else {
        bx = blockIdx.x; by = blockIdx.y; bz = blockIdx.z;
    }

    const int tid  = threadIdx.x;
    const int lane = tid & 63;
    const int wid  = tid >> 6;
    const int wr   = wid >> 1;
    const int wc   = wid & 1;
    const int l15  = lane & 15;
    const int kg   = lane >> 4;
    const int m0   = bx * 128;
    const int n0   = by * 64;
    const int kbeg = SPLIT ? bz * Kslab : 0;

    floatx4 acc[4][2];
    #pragma unroll
    for (int m = 0; m < 4; m++)
        #pragma unroll
        for (int n = 0; n < 2; n++)
            acc[m][n] = (floatx4){0.f, 0.f, 0.f, 0.f};

    auto stage = [&](int buf, int k0) {
        #pragma unroll
        for (int j = 0; j < 4; j++) {
            int c = j * 256 + tid;
            int g = c >> 7, r = c & 127;
            int grow = m0 + r; grow = grow < Md ? grow : Md - 1;
            const __attribute__((address_space(1))) short* src =
                (const __attribute__((address_space(1))) short*)(A + (size_t)grow * lda + k0 + g * 8);
            __builtin_amdgcn_global_load_lds(
                (const __attribute__((address_space(1))) void*)src,
                (__attribute__((address_space(3))) void*)&As[buf][c * 8], 16, 0, 0);
        }
        #pragma unroll
        for (int j = 0; j < 2; j++) {
            int c = j * 256 + tid;
            int g = c >> 6, r = c & 63;
            int brow = n0 + r; brow = brow < Nd ? brow : Nd - 1;
            const __attribute__((address_space(1))) short* src =
                (const __attribute__((address_space(1))) short*)(Bt + (size_t)brow * ldb + k0 + g * 8);
            __builtin_amdgcn_global_load_lds(
                (const __attribute__((address_space(1))) void*)src,
                (__attribute__((address_space(3))) void*)&Bs[buf][c * 8], 16, 0, 0);
        }
    };

    stage(0, kbeg);
    __syncthreads();

    const int nt = Kslab >> 6;
    for (int t = 0; t < nt; t++) {
        const int cur = t & 1;
        if (t + 1 < nt) stage(cur ^ 1, kbeg + (t + 1) * 64);   // prefetch next

        short8 a[2][4], b[2][2];
        #pragma unroll
        for (int kk = 0; kk < 2; kk++) {
            #pragma unroll
            for (int m = 0; m < 4; m++)
                a[kk][m] = *(const short8*)&As[cur][((kk * 4 + kg) * 128 + wr * 64 + m * 16 + l15) * 8];
            #pragma unroll
            for (int n = 0; n < 2; n++)
                b[kk][n] = *(const short8*)&Bs[cur][((kk * 4 + kg) * 64 + wc * 32 + n * 16 + l15) * 8];
        }
        #pragma unroll
        for (int kk = 0; kk < 2; kk++)
            #pragma unroll
            for (int m = 0; m < 4; m++)
                #pragma unroll
                for (int n = 0; n < 2; n++)
                    acc[m][n] = __builtin_amdgcn_mfma_f32_16x16x32_bf16(a[kk][m], b[kk][n], acc[m][n], 0, 0, 0);

        __syncthreads();
    }

    // Epilogue: D layout col=lane&15, row=(lane>>4)*4+q
    if (SPLIT) {
        #pragma unroll
        for (int n = 0; n < 2; n++) {
            int col = n0 + wc * 32 + n * 16 + l15;
            if (col >= Nd) continue;
            #pragma unroll
            for (int m = 0; m < 4; m++)
                #pragma unroll
                for (int q = 0; q < 4; q++) {
                    int row = m0 + wr * 64 + m * 16 + kg * 4 + q;
                    if (row >= Md) continue;
                    size_t ix = (size_t)bz * Md * Nd + (size_t)row * Nd + col;
                    if (PARTBF) ((unsigned short*)Cpart)[ix] = f2bf(acc[m][n][q]);
                    else        ((float*)Cpart)[ix] = acc[m][n][q];
                }
        }
    } else {
        #pragma unroll
        for (int n = 0; n < 2; n++) {
            int col = n0 + wc * 32 + n * 16 + l15;
            if (col >= Nd) continue;
            float bv = BIAS ? bias[col] : 0.f;
            #pragma unroll
            for (int m = 0; m < 4; m++)
                #pragma unroll
                for (int q = 0; q < 4; q++) {
                    int row = m0 + wr * 64 + m * 16 + kg * 4 + q;
                    if (row >= Md) continue;
                    float v = acc[m][n][q] + bv;
                    if (ACT == 1) v = fmaxf(v, 0.f) + log1pf(expf(-fabsf(v)));  // softplus
                    if (W32) C32[(size_t)row * Nd + col] = v;
                    if (W16) C16[(size_t)row * Nd + col] = f2bf(v);
                }
        }
    }
}

// ---------------------------------------------------------------------------
// Sum S fp32 split-K partials + bias/act -> fp32/bf16. total % 1024 == 0.
// ---------------------------------------------------------------------------
template<int S, bool BIAS, int ACT, bool W32, bool W16>
__global__ __launch_bounds__(256) void reduce_split(
    const float* __restrict__ P, const float* __restrict__ bias,
    float* __restrict__ C32, unsigned short* __restrict__ C16,
    int total, int nmask)
{
    int i = (blockIdx.x * 256 + threadIdx.x) * 4;
    float4 v = *(const float4*)&P[i];
    #pragma unroll
    for (int s = 1; s < S; s++) {
        float4 p = *(const float4*)&P[(size_t)s * total + i];
        v.x += p.x; v.y += p.y; v.z += p.z; v.w += p.w;
    }
    float r[4] = {v.x, v.y, v.z, v.w};
    #pragma unroll
    for (int j = 0; j < 4; j++) {
        float t = r[j];
        if (BIAS) t += bias[(i + j) & nmask];
        if (ACT == 1) t = fmaxf(t, 0.f) + log1pf(expf(-fabsf(t)));
        if (W32) C32[i + j] = t;
        if (W16) C16[i + j] = f2bf(t);
    }
}

// ---------------------------------------------------------------------------
// Sum S bf16 split-K partials + bias -> bf16. total % 2048 == 0.
// ---------------------------------------------------------------------------
template<int S, bool BIAS>
__global__ __launch_bounds__(256) void reduce_split_bf(
    const unsigned short* __restrict__ P, const float* __restrict__ bias,
    unsigned short* __restrict__ C16, int total, int nmask)
{
    int i = (blockIdx.x * 256 + threadIdx.x) * 8;
    float r[8] = {};
    #pragma unroll
    for (int s = 0; s < S; s++) {
        short8 p = *(const short8*)&P[(size_t)s * total + i];
        #pragma unroll
        for (int j = 0; j < 8; j++) r[j] += bf2f((unsigned short)p[j]);
    }
    short8 o;
    #pragma unroll
    for (int j = 0; j < 8; j++) {
        float t = r[j];
        if (BIAS) t += bias[(i + j) & nmask];
        o[j] = (short)f2bf(t);
    }
    *(short8*)&C16[i] = o;
}

// ---------------------------------------------------------------------------
// fp32 -> bf16 flat convert (n % 1024 == 0)
// ---------------------------------------------------------------------------
__global__ __launch_bounds__(256) void f32_to_bf16_kernel(
    const float* __restrict__ in, unsigned short* __restrict__ out, int n4)
{
    int i = (blockIdx.x * 256 + threadIdx.x) * 4;
    float4 v = *(const float4*)&in[i];
    out[i + 0] = f2bf(v.x);
    out[i + 1] = f2bf(v.y);
    out[i + 2] = f2bf(v.z);
    out[i + 3] = f2bf(v.w);
}

// ---------------------------------------------------------------------------
// Transpose fp32 [K][N] -> bf16 [N][K]  (K,N multiples of 32)
// ---------------------------------------------------------------------------
__global__ __launch_bounds__(256) void transpose_f32_bf16(
    const float* __restrict__ in, unsigned short* __restrict__ out, int K, int N)
{
    __shared__ float t[32][33];
    int k0 = blockIdx.x * 32, n0 = blockIdx.y * 32;
    int tx = threadIdx.x & 31, ty = threadIdx.x >> 5;   // ty 0..7
    #pragma unroll
    for (int i = 0; i < 4; i++)
        t[ty + i * 8][tx] = in[(size_t)(k0 + ty + i * 8) * N + n0 + tx];
    __syncthreads();
    #pragma unroll
    for (int i = 0; i < 4; i++)
        out[(size_t)(n0 + ty + i * 8) * K + k0 + tx] = f2bf(t[tx][ty + i * 8]);
}

// ---------------------------------------------------------------------------
// Causal depthwise conv (K=4) + bias + SiLU; xz is bf16 with row stride 2*DI.
// Writes xc as fp32 (for scan) and bf16 (for proj GEMM).
// ---------------------------------------------------------------------------
__global__ __launch_bounds__(256) void conv_silu_kernel(
    const unsigned short* __restrict__ xz, const float* __restrict__ conv_w,
    const float* __restrict__ conv_b, float* __restrict__ xc,
    unsigned short* __restrict__ xc_bf)
{
    int idx = blockIdx.x * 256 + threadIdx.x;
    if (idx >= Bb * Ll * DI) return;
    int d  = idx & (DI - 1);
    int bl = idx >> 11;
    int l  = bl % Ll;

    float acc = conv_b[d];
    #pragma unroll
    for (int k = 0; k < Kc; k++) {
        int ls = l + k - (Kc - 1);
        if (ls >= 0)
            acc = fmaf(conv_w[d * Kc + k], bf2f(xz[(size_t)(bl + ls - l) * (2 * DI) + d]), acc);
    }
    float s = acc / (1.f + expf(-acc));
    xc[idx] = s;
    xc_bf[idx] = f2bf(s);
}

// ---------------------------------------------------------------------------
// Selective scan, state-parallel: 4 states per thread, 4 threads per (b,d).
// Block 256 thr = 64 d-channels; grid (DI/64, Bb) = 512 blocks (8 waves/CU).
// y-reduce across the 4-thread quad via shfl_xor. Fused D*xc + silu(z) gate.
// ---------------------------------------------------------------------------
__global__ __launch_bounds__(256) void scan_kernel(
    const float* __restrict__ delta, const float* __restrict__ xc,
    const unsigned short* __restrict__ xz, const float* __restrict__ proj,
    const float* __restrict__ A_log, const float* __restrict__ Dv,
    unsigned short* __restrict__ y)
{
    const int t    = threadIdx.x;
    const int nq   = t & 3;          // state quad: states 4*nq .. 4*nq+3
    const int dloc = t >> 2;         // 0..63
    const int d    = blockIdx.x * 64 + dloc;
    const int b    = blockIdx.y;

    float4 Alq = *(const float4*)&A_log[(size_t)d * Nst + nq * 4];
    float Ar0 = -expf(Alq.x), Ar1 = -expf(Alq.y), Ar2 = -expf(Alq.z), Ar3 = -expf(Alq.w);
    const float Dd = Dv[d];

    float h0 = 0.f, h1 = 0.f, h2 = 0.f, h3 = 0.f;

    for (int l = 0; l < Ll; l++) {
        size_t bl = (size_t)b * Ll + l;
        float dl  = delta[bl * DI + d];
        float xcv = xc[bl * DI + d];
        float zv  = bf2f(xz[bl * (2 * DI) + DI + d]);
        float dx  = dl * xcv;
        const float* p = proj + bl * (DTR + 2 * Nst);
        float4 Bv = *(const float4*)&p[DTR + nq * 4];
        float4 Cv = *(const float4*)&p[DTR + Nst + nq * 4];

        h0 = fmaf(expf(dl * Ar0), h0, dx * Bv.x);
        h1 = fmaf(expf(dl * Ar1), h1, dx * Bv.y);
        h2 = fmaf(expf(dl * Ar2), h2, dx * Bv.z);
        h3 = fmaf(expf(dl * Ar3), h3, dx * Bv.w);

        float yac = h0 * Cv.x + h1 * Cv.y + h2 * Cv.z + h3 * Cv.w;
        yac += __shfl_xor(yac, 1);
        yac += __shfl_xor(yac, 2);

        if (nq == 0) {
            float yv = yac + Dd * xcv;
            yv *= zv / (1.f + expf(-zv));
            y[bl * DI + d] = f2bf(yv);
        }
    }
}

// ---------------------------------------------------------------------------
// logits[M,16] = out_bf[M,1024] @ W_out[1024,16] + b_out
// ---------------------------------------------------------------------------
__global__ __launch_bounds__(256) void gemm_n16(
    const unsigned short* __restrict__ A, const float* __restrict__ W,
    const float* __restrict__ bias, float* __restrict__ C, int Kd)
{
    int m  = blockIdx.x;
    int t  = threadIdx.x;
    int c  = t & 15;
    int kg = t >> 4;
    const unsigned short* a = A + (size_t)m * Kd;

    float acc = 0.f;
    for (int k = kg; k < Kd; k += 16)
        acc = fmaf(bf2f(a[k]), W[k * NC + c], acc);

    __shared__ float red[256];
    red[t] = acc;
    __syncthreads();
    #pragma unroll
    for (int s = 128; s >= 16; s >>= 1) {
        if (t < s) red[t] += red[t + s];
        __syncthreads();
    }
    if (t < 16) C[(size_t)m * NC + t] = red[t] + bias[t];
}

// ---------------------------------------------------------------------------
extern "C" void kernel_launch(void* const* d_in, const int* in_sizes, int n_in,
                              void* d_out, int out_size, void* d_ws, size_t ws_size,
                              hipStream_t stream) {
    const float* x         = (const float*)d_in[0];
    const float* W_in      = (const float*)d_in[1];
    const float* b_in      = (const float*)d_in[2];
    const float* in_proj_w = (const float*)d_in[3];
    const float* conv_w    = (const float*)d_in[4];
    const float* conv_b    = (const float*)d_in[5];
    const float* x_proj_w  = (const float*)d_in[6];
    const float* dt_proj_w = (const float*)d_in[7];
    const float* dt_proj_b = (const float*)d_in[8];
    const float* A_log     = (const float*)d_in[9];
    const float* Dv        = (const float*)d_in[10];
    const float* out_proj  = (const float*)d_in[11];
    const float* W_out     = (const float*)d_in[12];
    const float* b_out     = (const float*)d_in[13];
    float* logits = (float*)d_out;

    // Workspace layout (bytes, 256-aligned). xc+delta (26.2MB adjacent) double
    // as split-K partial space: P14 bf16 [8][1600][1024] for GEMM1/GEMM7
    // (consumed before xc/delta written, or after they're dead); P8 fp32
    // [8][1600][96] in delta for proj (consumed before GEMM5 writes delta).
    char* base = (char*)d_ws;
    size_t off = 0;
    auto alloc = [&](size_t bytes) {
        char* p = base + off;
        off += (bytes + 255) & ~(size_t)255;
        return p;
    };
    unsigned short* x_bf    = (unsigned short*)alloc((size_t)M * DIN * 2);
    unsigned short* Wt_in   = (unsigned short*)alloc((size_t)Hh * DIN * 2);
    unsigned short* Wt_ip   = (unsigned short*)alloc((size_t)(2 * DI) * Hh * 2);
    unsigned short* Wt_op   = (unsigned short*)alloc((size_t)Hh * DI * 2);
    unsigned short* xpw_t   = (unsigned short*)alloc((size_t)96 * DI * 2);
    unsigned short* dtw_t   = (unsigned short*)alloc((size_t)DI * DTR * 2);
    unsigned short* h_bf    = (unsigned short*)alloc((size_t)M * Hh * 2);
    unsigned short* xz_bf   = (unsigned short*)alloc((size_t)M * 2 * DI * 2);
    float*          xc      = (float*)alloc((size_t)M * DI * 4);       // | 26.2MB partial
    float*          delta   = (float*)alloc((size_t)M * DI * 4);       // | region
    unsigned short* xc_bf   = (unsigned short*)alloc((size_t)M * DI * 2);
    float*          proj_f  = (float*)alloc((size_t)M * 96 * 4);
    unsigned short* proj_bf = (unsigned short*)alloc((size_t)M * 96 * 2);
    unsigned short* y_bf    = (unsigned short*)alloc((size_t)M * DI * 2);
    unsigned short* out_bf  = (unsigned short*)alloc((size_t)M * Hh * 2);

    unsigned short* P14 = (unsigned short*)xc;   // bf16 [8][1600][1024] = 26.2MB
    float*          P8  = delta;                 // fp32 [8][1600][96]  = 4.9MB

    dim3 blk(256);

    // 0) conversions / weight transposes
    f32_to_bf16_kernel<<<dim3((M * DIN) / 1024), blk, 0, stream>>>(x, x_bf, M * DIN);
    transpose_f32_bf16<<<dim3(DIN / 32, Hh / 32), blk, 0, stream>>>(W_in, Wt_in, DIN, Hh);
    transpose_f32_bf16<<<dim3(Hh / 32, (2 * DI) / 32), blk, 0, stream>>>(in_proj_w, Wt_ip, Hh, 2 * DI);
    transpose_f32_bf16<<<dim3(DI / 32, Hh / 32), blk, 0, stream>>>(out_proj, Wt_op, DI, Hh);
    transpose_f32_bf16<<<dim3(DI / 32, 96 / 32), blk, 0, stream>>>(x_proj_w, xpw_t, DI, 96);
    transpose_f32_bf16<<<dim3(DTR / 32, DI / 32), blk, 0, stream>>>(dt_proj_w, dtw_t, DTR, DI);

    // 1) h = x @ W_in + b_in   [1600,6144]@[6144,1024], split-K 8 -> 1664 blocks
    gemm_mfma<true, true, false, 0, false, false><<<dim3(13, Hh / 64, 8), blk, 0, stream>>>(
        x_bf, DIN, Wt_in, DIN, nullptr, nullptr, nullptr, P14, M, Hh, DIN / 8);
    reduce_split_bf<8, true><<<dim3((M * Hh) / 2048), blk, 0, stream>>>(
        P14, b_in, h_bf, M * Hh, Hh - 1);

    // 2) xz = h @ in_proj_w    [1600,1024]@[1024,4096], 832 blocks
    gemm_mfma<false, false, false, 0, false, true><<<dim3(13, (2 * DI) / 64, 1), blk, 0, stream>>>(
        h_bf, Hh, Wt_ip, Hh, nullptr, nullptr, xz_bf, nullptr, M, 2 * DI, Hh);

    // 3) xc = silu(conv(xm) + conv_b)  -> fp32 + bf16
    conv_silu_kernel<<<dim3((Bb * Ll * DI) / 256), blk, 0, stream>>>(
        xz_bf, conv_w, conv_b, xc, xc_bf);

    // 4) proj = xc @ x_proj_w  [1600,2048]@[2048,96], split-K 8 -> 208 blocks
    gemm_mfma<true, false, false, 0, false, false><<<dim3(13, 2, 8), blk, 0, stream>>>(
        xc_bf, DI, xpw_t, DI, nullptr, nullptr, nullptr, P8, M, 96, DI / 8);
    reduce_split<8, false, 0, true, true><<<dim3((M * 96) / 1024), blk, 0, stream>>>(
        P8, nullptr, proj_f, proj_bf, M * 96, 0);

    // 5) delta = softplus(proj[:,:64] @ dt_proj_w + dt_proj_b)  [1600,64]@[64,2048]
    gemm_mfma<false, false, true, 1, true, false><<<dim3(13, DI / 64, 1), blk, 0, stream>>>(
        proj_bf, 96, dtw_t, DTR, dt_proj_b, delta, nullptr, nullptr, M, DI, DTR);

    // 6) selective scan (state-parallel)
    scan_kernel<<<dim3(DI / 64, Bb), blk, 0, stream>>>(
        delta, xc, xz_bf, proj_f, A_log, Dv, y_bf);

    // 7) out = y @ out_proj_w  [1600,2048]@[2048,1024], split-K 8 -> 1664 blocks
    gemm_mfma<true, true, false, 0, false, false><<<dim3(13, Hh / 64, 8), blk, 0, stream>>>(
        y_bf, DI, Wt_op, DI, nullptr, nullptr, nullptr, P14, M, Hh, DI / 8);
    reduce_split_bf<8, false><<<dim3((M * Hh) / 2048), blk, 0, stream>>>(
        P14, nullptr, out_bf, M * Hh, 0);

    // 8) logits = out @ W_out + b_out  [1600,1024]@[1024,16]
    gemm_n16<<<dim3(M), blk, 0, stream>>>(out_bf, W_out, b_out, logits, Hh);
}

// Round 6
// 348.388 us; speedup vs baseline: 5.6666x; 1.0388x over previous
//
#include <hip/hip_runtime.h>
#include <hip/hip_bf16.h>
#include <stdint.h>

// Problem constants
constexpr int Bb  = 16;
constexpr int Ll  = 100;
constexpr int DIN = 6144;
constexpr int Hh  = 1024;
constexpr int DI  = 2048;
constexpr int Nst = 16;
constexpr int DTR = 64;
constexpr int Kc  = 4;
constexpr int NC  = 16;
constexpr int M   = Bb * Ll;   // 1600 tokens

typedef __attribute__((ext_vector_type(8))) short short8;
typedef __attribute__((ext_vector_type(4))) float floatx4;

__device__ __forceinline__ float bf2f(unsigned short u) {
    union { uint32_t b; float f; } x; x.b = ((uint32_t)u) << 16; return x.f;
}
__device__ __forceinline__ unsigned short f2bf(float f) {
    union { float f; uint32_t b; } x; x.f = f;
    uint32_t r = x.b + 0x7FFF + ((x.b >> 16) & 1);   // RNE
    return (unsigned short)(r >> 16);
}
// Fast silu using native v_exp_f32 (~1ulp; margin is 3.2x, fine)
__device__ __forceinline__ float fast_silu(float x) {
    return x / (1.f + __expf(-x));
}

// ---------------------------------------------------------------------------
// bf16 MFMA GEMM: C[M,N] = A[M,K] @ Bt[N,K]^T, fp32 acc.
// BM=128, BN=64, BK=64, double-buffered LDS (2-phase pipeline).
// 256 threads = 4 waves (2x2), wave tile 64x32: 16 MFMA/step.
// XCD-aware chunked swizzle (requires gridtotal % 8 == 0; falls back if not).
// SPLIT: z slices K; partials (fp32 or bf16) to Cpart[z][Md][Nd]; reduce_split*
// sums + bias/act. Deterministic (no atomics).
// ---------------------------------------------------------------------------
template<bool SPLIT, bool PARTBF, bool BIAS, int ACT, bool W32, bool W16>
__global__ __launch_bounds__(256) void gemm_mfma(
    const unsigned short* __restrict__ A, int lda,    // [Md x lda]
    const unsigned short* __restrict__ Bt, int ldb,   // [Nd x ldb]
    const float* __restrict__ bias,                   // [Nd]
    float* __restrict__ C32,
    unsigned short* __restrict__ C16,
    void* __restrict__ Cpart,
    int Md, int Nd, int Kslab)                        // Kslab = K per z-slice
{
    __shared__ short As[2][8 * 128 * 8];   // 16 KB per buf
    __shared__ short Bs[2][8 * 64 * 8];    // 8 KB per buf

    // XCD-aware block remap (bijective chunked transform)
    const int nx = gridDim.x, ny = gridDim.y, nz = gridDim.z;
    const int nb = nx * ny * nz;
    int id = blockIdx.x + nx * (blockIdx.y + ny * blockIdx.z);
    int bx, by, bz;
    if ((nb & 7) == 0) {
        int swz = (id & 7) * (nb >> 3) + (id >> 3);
        bx = swz % nx;
        int rem = swz / nx;
        by = rem % ny;
        bz = rem / ny;
    } else {
        bx = blockIdx.x; by = blockIdx.y; bz = blockIdx.z;
    }

    const int tid  = threadIdx.x;
    const int lane = tid & 63;
    const int wid  = tid >> 6;
    const int wr   = wid >> 1;
    const int wc   = wid & 1;
    const int l15  = lane & 15;
    const int kg   = lane >> 4;
    const int m0   = bx * 128;
    const int n0   = by * 64;
    const int kbeg = SPLIT ? bz * Kslab : 0;

    floatx4 acc[4][2];
    #pragma unroll
    for (int m = 0; m < 4; m++)
        #pragma unroll
        for (int n = 0; n < 2; n++)
            acc[m][n] = (floatx4){0.f, 0.f, 0.f, 0.f};

    auto stage = [&](int buf, int k0) {
        #pragma unroll
        for (int j = 0; j < 4; j++) {
            int c = j * 256 + tid;
            int g = c >> 7, r = c & 127;
            int grow = m0 + r; grow = grow < Md ? grow : Md - 1;
            const __attribute__((address_space(1))) short* src =
                (const __attribute__((address_space(1))) short*)(A + (size_t)grow * lda + k0 + g * 8);
            __builtin_amdgcn_global_load_lds(
                (const __attribute__((address_space(1))) void*)src,
                (__attribute__((address_space(3))) void*)&As[buf][c * 8], 16, 0, 0);
        }
        #pragma unroll
        for (int j = 0; j < 2; j++) {
            int c = j * 256 + tid;
            int g = c >> 6, r = c & 63;
            int brow = n0 + r; brow = brow < Nd ? brow : Nd - 1;
            const __attribute__((address_space(1))) short* src =
                (const __attribute__((address_space(1))) short*)(Bt + (size_t)brow * ldb + k0 + g * 8);
            __builtin_amdgcn_global_load_lds(
                (const __attribute__((address_space(1))) void*)src,
                (__attribute__((address_space(3))) void*)&Bs[buf][c * 8], 16, 0, 0);
        }
    };

    stage(0, kbeg);
    __syncthreads();

    const int nt = Kslab >> 6;
    for (int t = 0; t < nt; t++) {
        const int cur = t & 1;
        if (t + 1 < nt) stage(cur ^ 1, kbeg + (t + 1) * 64);   // prefetch next

        short8 a[2][4], b[2][2];
        #pragma unroll
        for (int kk = 0; kk < 2; kk++) {
            #pragma unroll
            for (int m = 0; m < 4; m++)
                a[kk][m] = *(const short8*)&As[cur][((kk * 4 + kg) * 128 + wr * 64 + m * 16 + l15) * 8];
            #pragma unroll
            for (int n = 0; n < 2; n++)
                b[kk][n] = *(const short8*)&Bs[cur][((kk * 4 + kg) * 64 + wc * 32 + n * 16 + l15) * 8];
        }
        #pragma unroll
        for (int kk = 0; kk < 2; kk++)
            #pragma unroll
            for (int m = 0; m < 4; m++)
                #pragma unroll
                for (int n = 0; n < 2; n++)
                    acc[m][n] = __builtin_amdgcn_mfma_f32_16x16x32_bf16(a[kk][m], b[kk][n], acc[m][n], 0, 0, 0);

        __syncthreads();
    }

    // Epilogue: D layout col=lane&15, row=(lane>>4)*4+q
    if (SPLIT) {
        #pragma unroll
        for (int n = 0; n < 2; n++) {
            int col = n0 + wc * 32 + n * 16 + l15;
            if (col >= Nd) continue;
            #pragma unroll
            for (int m = 0; m < 4; m++)
                #pragma unroll
                for (int q = 0; q < 4; q++) {
                    int row = m0 + wr * 64 + m * 16 + kg * 4 + q;
                    if (row >= Md) continue;
                    size_t ix = (size_t)bz * Md * Nd + (size_t)row * Nd + col;
                    if (PARTBF) ((unsigned short*)Cpart)[ix] = f2bf(acc[m][n][q]);
                    else        ((float*)Cpart)[ix] = acc[m][n][q];
                }
        }
    } else {
        #pragma unroll
        for (int n = 0; n < 2; n++) {
            int col = n0 + wc * 32 + n * 16 + l15;
            if (col >= Nd) continue;
            float bv = BIAS ? bias[col] : 0.f;
            #pragma unroll
            for (int m = 0; m < 4; m++)
                #pragma unroll
                for (int q = 0; q < 4; q++) {
                    int row = m0 + wr * 64 + m * 16 + kg * 4 + q;
                    if (row >= Md) continue;
                    float v = acc[m][n][q] + bv;
                    if (ACT == 1) v = fmaxf(v, 0.f) + log1pf(expf(-fabsf(v)));  // softplus
                    if (W32) C32[(size_t)row * Nd + col] = v;
                    if (W16) C16[(size_t)row * Nd + col] = f2bf(v);
                }
        }
    }
}

// ---------------------------------------------------------------------------
// Sum S fp32 split-K partials + bias/act -> fp32/bf16. total % 1024 == 0.
// ---------------------------------------------------------------------------
template<int S, bool BIAS, int ACT, bool W32, bool W16>
__global__ __launch_bounds__(256) void reduce_split(
    const float* __restrict__ P, const float* __restrict__ bias,
    float* __restrict__ C32, unsigned short* __restrict__ C16,
    int total, int nmask)
{
    int i = (blockIdx.x * 256 + threadIdx.x) * 4;
    float4 v = *(const float4*)&P[i];
    #pragma unroll
    for (int s = 1; s < S; s++) {
        float4 p = *(const float4*)&P[(size_t)s * total + i];
        v.x += p.x; v.y += p.y; v.z += p.z; v.w += p.w;
    }
    float r[4] = {v.x, v.y, v.z, v.w};
    #pragma unroll
    for (int j = 0; j < 4; j++) {
        float t = r[j];
        if (BIAS) t += bias[(i + j) & nmask];
        if (ACT == 1) t = fmaxf(t, 0.f) + log1pf(expf(-fabsf(t)));
        if (W32) C32[i + j] = t;
        if (W16) C16[i + j] = f2bf(t);
    }
}

// ---------------------------------------------------------------------------
// Sum S bf16 split-K partials + bias -> bf16. total % 2048 == 0.
// ---------------------------------------------------------------------------
template<int S, bool BIAS>
__global__ __launch_bounds__(256) void reduce_split_bf(
    const unsigned short* __restrict__ P, const float* __restrict__ bias,
    unsigned short* __restrict__ C16, int total, int nmask)
{
    int i = (blockIdx.x * 256 + threadIdx.x) * 8;
    float r[8] = {};
    #pragma unroll
    for (int s = 0; s < S; s++) {
        short8 p = *(const short8*)&P[(size_t)s * total + i];
        #pragma unroll
        for (int j = 0; j < 8; j++) r[j] += bf2f((unsigned short)p[j]);
    }
    short8 o;
    #pragma unroll
    for (int j = 0; j < 8; j++) {
        float t = r[j];
        if (BIAS) t += bias[(i + j) & nmask];
        o[j] = (short)f2bf(t);
    }
    *(short8*)&C16[i] = o;
}

// ---------------------------------------------------------------------------
// fp32 -> bf16 flat convert (n % 1024 == 0)
// ---------------------------------------------------------------------------
__global__ __launch_bounds__(256) void f32_to_bf16_kernel(
    const float* __restrict__ in, unsigned short* __restrict__ out, int n4)
{
    int i = (blockIdx.x * 256 + threadIdx.x) * 4;
    float4 v = *(const float4*)&in[i];
    out[i + 0] = f2bf(v.x);
    out[i + 1] = f2bf(v.y);
    out[i + 2] = f2bf(v.z);
    out[i + 3] = f2bf(v.w);
}

// ---------------------------------------------------------------------------
// Transpose fp32 [K][N] -> bf16 [N][K]  (K,N multiples of 32)
// ---------------------------------------------------------------------------
__global__ __launch_bounds__(256) void transpose_f32_bf16(
    const float* __restrict__ in, unsigned short* __restrict__ out, int K, int N)
{
    __shared__ float t[32][33];
    int k0 = blockIdx.x * 32, n0 = blockIdx.y * 32;
    int tx = threadIdx.x & 31, ty = threadIdx.x >> 5;   // ty 0..7
    #pragma unroll
    for (int i = 0; i < 4; i++)
        t[ty + i * 8][tx] = in[(size_t)(k0 + ty + i * 8) * N + n0 + tx];
    __syncthreads();
    #pragma unroll
    for (int i = 0; i < 4; i++)
        out[(size_t)(n0 + ty + i * 8) * K + k0 + tx] = f2bf(t[tx][ty + i * 8]);
}

// ---------------------------------------------------------------------------
// Causal depthwise conv (K=4) + bias + SiLU; xz is bf16 with row stride 2*DI.
// Writes xc as fp32 (for scan) and bf16 (for proj GEMM).
// ---------------------------------------------------------------------------
__global__ __launch_bounds__(256) void conv_silu_kernel(
    const unsigned short* __restrict__ xz, const float* __restrict__ conv_w,
    const float* __restrict__ conv_b, float* __restrict__ xc,
    unsigned short* __restrict__ xc_bf)
{
    int idx = blockIdx.x * 256 + threadIdx.x;
    if (idx >= Bb * Ll * DI) return;
    int d  = idx & (DI - 1);
    int bl = idx >> 11;
    int l  = bl % Ll;

    float acc = conv_b[d];
    #pragma unroll
    for (int k = 0; k < Kc; k++) {
        int ls = l + k - (Kc - 1);
        if (ls >= 0)
            acc = fmaf(conv_w[d * Kc + k], bf2f(xz[(size_t)(bl + ls - l) * (2 * DI) + d]), acc);
    }
    float s = fast_silu(acc);
    xc[idx] = s;
    xc_bf[idx] = f2bf(s);
}

// ---------------------------------------------------------------------------
// Selective scan, state-parallel: 4 states per thread, 4 threads per (b,d).
// Block 256 thr = 64 d-channels; grid (DI/64, Bb) = 512 blocks.
// dA via native v_exp_f32 (__expf): the l-loop is exp-throughput critical;
// libm expf (~25 instr) made this kernel 90us -> native exp is the fix.
// y-reduce across the 4-thread quad via shfl_xor. Fused D*xc + silu(z) gate.
// ---------------------------------------------------------------------------
__global__ __launch_bounds__(256) void scan_kernel(
    const float* __restrict__ delta, const float* __restrict__ xc,
    const unsigned short* __restrict__ xz, const float* __restrict__ proj,
    const float* __restrict__ A_log, const float* __restrict__ Dv,
    unsigned short* __restrict__ y)
{
    const int t    = threadIdx.x;
    const int nq   = t & 3;          // state quad: states 4*nq .. 4*nq+3
    const int dloc = t >> 2;         // 0..63
    const int d    = blockIdx.x * 64 + dloc;
    const int b    = blockIdx.y;

    float4 Alq = *(const float4*)&A_log[(size_t)d * Nst + nq * 4];
    float Ar0 = -expf(Alq.x), Ar1 = -expf(Alq.y), Ar2 = -expf(Alq.z), Ar3 = -expf(Alq.w);
    const float Dd = Dv[d];

    float h0 = 0.f, h1 = 0.f, h2 = 0.f, h3 = 0.f;

    for (int l = 0; l < Ll; l++) {
        size_t bl = (size_t)b * Ll + l;
        float dl  = delta[bl * DI + d];
        float xcv = xc[bl * DI + d];
        float zv  = bf2f(xz[bl * (2 * DI) + DI + d]);
        float dx  = dl * xcv;
        const float* p = proj + bl * (DTR + 2 * Nst);
        float4 Bv = *(const float4*)&p[DTR + nq * 4];
        float4 Cv = *(const float4*)&p[DTR + Nst + nq * 4];

        h0 = fmaf(__expf(dl * Ar0), h0, dx * Bv.x);
        h1 = fmaf(__expf(dl * Ar1), h1, dx * Bv.y);
        h2 = fmaf(__expf(dl * Ar2), h2, dx * Bv.z);
        h3 = fmaf(__expf(dl * Ar3), h3, dx * Bv.w);

        float yac = h0 * Cv.x + h1 * Cv.y + h2 * Cv.z + h3 * Cv.w;
        yac += __shfl_xor(yac, 1);
        yac += __shfl_xor(yac, 2);

        if (nq == 0) {
            float yv = yac + Dd * xcv;
            yv *= fast_silu(zv);
            y[bl * DI + d] = f2bf(yv);
        }
    }
}

// ---------------------------------------------------------------------------
// logits[M,16] = out_bf[M,1024] @ W_out[1024,16] + b_out
// ---------------------------------------------------------------------------
__global__ __launch_bounds__(256) void gemm_n16(
    const unsigned short* __restrict__ A, const float* __restrict__ W,
    const float* __restrict__ bias, float* __restrict__ C, int Kd)
{
    int m  = blockIdx.x;
    int t  = threadIdx.x;
    int c  = t & 15;
    int kg = t >> 4;
    const unsigned short* a = A + (size_t)m * Kd;

    float acc = 0.f;
    for (int k = kg; k < Kd; k += 16)
        acc = fmaf(bf2f(a[k]), W[k * NC + c], acc);

    __shared__ float red[256];
    red[t] = acc;
    __syncthreads();
    #pragma unroll
    for (int s = 128; s >= 16; s >>= 1) {
        if (t < s) red[t] += red[t + s];
        __syncthreads();
    }
    if (t < 16) C[(size_t)m * NC + t] = red[t] + bias[t];
}

// ---------------------------------------------------------------------------
extern "C" void kernel_launch(void* const* d_in, const int* in_sizes, int n_in,
                              void* d_out, int out_size, void* d_ws, size_t ws_size,
                              hipStream_t stream) {
    const float* x         = (const float*)d_in[0];
    const float* W_in      = (const float*)d_in[1];
    const float* b_in      = (const float*)d_in[2];
    const float* in_proj_w = (const float*)d_in[3];
    const float* conv_w    = (const float*)d_in[4];
    const float* conv_b    = (const float*)d_in[5];
    const float* x_proj_w  = (const float*)d_in[6];
    const float* dt_proj_w = (const float*)d_in[7];
    const float* dt_proj_b = (const float*)d_in[8];
    const float* A_log     = (const float*)d_in[9];
    const float* Dv        = (const float*)d_in[10];
    const float* out_proj  = (const float*)d_in[11];
    const float* W_out     = (const float*)d_in[12];
    const float* b_out     = (const float*)d_in[13];
    float* logits = (float*)d_out;

    // Workspace layout (bytes, 256-aligned). xc+delta (26.2MB adjacent) double
    // as split-K partial space: P14 bf16 [8][1600][1024] for GEMM1/GEMM7;
    // P8 fp32 [8][1600][96] in delta for proj.
    char* base = (char*)d_ws;
    size_t off = 0;
    auto alloc = [&](size_t bytes) {
        char* p = base + off;
        off += (bytes + 255) & ~(size_t)255;
        return p;
    };
    unsigned short* x_bf    = (unsigned short*)alloc((size_t)M * DIN * 2);
    unsigned short* Wt_in   = (unsigned short*)alloc((size_t)Hh * DIN * 2);
    unsigned short* Wt_ip   = (unsigned short*)alloc((size_t)(2 * DI) * Hh * 2);
    unsigned short* Wt_op   = (unsigned short*)alloc((size_t)Hh * DI * 2);
    unsigned short* xpw_t   = (unsigned short*)alloc((size_t)96 * DI * 2);
    unsigned short* dtw_t   = (unsigned short*)alloc((size_t)DI * DTR * 2);
    unsigned short* h_bf    = (unsigned short*)alloc((size_t)M * Hh * 2);
    unsigned short* xz_bf   = (unsigned short*)alloc((size_t)M * 2 * DI * 2);
    float*          xc      = (float*)alloc((size_t)M * DI * 4);       // | 26.2MB partial
    float*          delta   = (float*)alloc((size_t)M * DI * 4);       // | region
    unsigned short* xc_bf   = (unsigned short*)alloc((size_t)M * DI * 2);
    float*          proj_f  = (float*)alloc((size_t)M * 96 * 4);
    unsigned short* proj_bf = (unsigned short*)alloc((size_t)M * 96 * 2);
    unsigned short* y_bf    = (unsigned short*)alloc((size_t)M * DI * 2);
    unsigned short* out_bf  = (unsigned short*)alloc((size_t)M * Hh * 2);

    unsigned short* P14 = (unsigned short*)xc;   // bf16 [8][1600][1024] = 26.2MB
    float*          P8  = delta;                 // fp32 [8][1600][96]  = 4.9MB

    dim3 blk(256);

    // 0) conversions / weight transposes
    f32_to_bf16_kernel<<<dim3((M * DIN) / 1024), blk, 0, stream>>>(x, x_bf, M * DIN);
    transpose_f32_bf16<<<dim3(DIN / 32, Hh / 32), blk, 0, stream>>>(W_in, Wt_in, DIN, Hh);
    transpose_f32_bf16<<<dim3(Hh / 32, (2 * DI) / 32), blk, 0, stream>>>(in_proj_w, Wt_ip, Hh, 2 * DI);
    transpose_f32_bf16<<<dim3(DI / 32, Hh / 32), blk, 0, stream>>>(out_proj, Wt_op, DI, Hh);
    transpose_f32_bf16<<<dim3(DI / 32, 96 / 32), blk, 0, stream>>>(x_proj_w, xpw_t, DI, 96);
    transpose_f32_bf16<<<dim3(DTR / 32, DI / 32), blk, 0, stream>>>(dt_proj_w, dtw_t, DTR, DI);

    // 1) h = x @ W_in + b_in   [1600,6144]@[6144,1024], split-K 8 -> 1664 blocks
    gemm_mfma<true, true, false, 0, false, false><<<dim3(13, Hh / 64, 8), blk, 0, stream>>>(
        x_bf, DIN, Wt_in, DIN, nullptr, nullptr, nullptr, P14, M, Hh, DIN / 8);
    reduce_split_bf<8, true><<<dim3((M * Hh) / 2048), blk, 0, stream>>>(
        P14, b_in, h_bf, M * Hh, Hh - 1);

    // 2) xz = h @ in_proj_w    [1600,1024]@[1024,4096], 832 blocks
    gemm_mfma<false, false, false, 0, false, true><<<dim3(13, (2 * DI) / 64, 1), blk, 0, stream>>>(
        h_bf, Hh, Wt_ip, Hh, nullptr, nullptr, xz_bf, nullptr, M, 2 * DI, Hh);

    // 3) xc = silu(conv(xm) + conv_b)  -> fp32 + bf16
    conv_silu_kernel<<<dim3((Bb * Ll * DI) / 256), blk, 0, stream>>>(
        xz_bf, conv_w, conv_b, xc, xc_bf);

    // 4) proj = xc @ x_proj_w  [1600,2048]@[2048,96], split-K 8 -> 208 blocks
    gemm_mfma<true, false, false, 0, false, false><<<dim3(13, 2, 8), blk, 0, stream>>>(
        xc_bf, DI, xpw_t, DI, nullptr, nullptr, nullptr, P8, M, 96, DI / 8);
    reduce_split<8, false, 0, true, true><<<dim3((M * 96) / 1024), blk, 0, stream>>>(
        P8, nullptr, proj_f, proj_bf, M * 96, 0);

    // 5) delta = softplus(proj[:,:64] @ dt_proj_w + dt_proj_b)  [1600,64]@[64,2048]
    gemm_mfma<false, false, true, 1, true, false><<<dim3(13, DI / 64, 1), blk, 0, stream>>>(
        proj_bf, 96, dtw_t, DTR, dt_proj_b, delta, nullptr, nullptr, M, DI, DTR);

    // 6) selective scan (state-parallel, native exp)
    scan_kernel<<<dim3(DI / 64, Bb), blk, 0, stream>>>(
        delta, xc, xz_bf, proj_f, A_log, Dv, y_bf);

    // 7) out = y @ out_proj_w  [1600,2048]@[2048,1024], split-K 8 -> 1664 blocks
    gemm_mfma<true, true, false, 0, false, false><<<dim3(13, Hh / 64, 8), blk, 0, stream>>>(
        y_bf, DI, Wt_op, DI, nullptr, nullptr, nullptr, P14, M, Hh, DI / 8);
    reduce_split_bf<8, false><<<dim3((M * Hh) / 2048), blk, 0, stream>>>(
        P14, nullptr, out_bf, M * Hh, 0);

    // 8) logits = out @ W_out + b_out  [1600,1024]@[1024,16]
    gemm_n16<<<dim3(M), blk, 0, stream>>>(out_bf, W_out, b_out, logits, Hh);
}

// Round 7
// 340.890 us; speedup vs baseline: 5.7913x; 1.0220x over previous
//
#include <hip/hip_runtime.h>
#include <hip/hip_bf16.h>
#include <stdint.h>

// Problem constants
constexpr int Bb  = 16;
constexpr int Ll  = 100;
constexpr int DIN = 6144;
constexpr int Hh  = 1024;
constexpr int DI  = 2048;
constexpr int Nst = 16;
constexpr int DTR = 64;
constexpr int Kc  = 4;
constexpr int NC  = 16;
constexpr int M   = Bb * Ll;   // 1600 tokens

typedef __attribute__((ext_vector_type(8))) short short8;
typedef __attribute__((ext_vector_type(4))) float floatx4;

__device__ __forceinline__ float bf2f(unsigned short u) {
    union { uint32_t b; float f; } x; x.b = ((uint32_t)u) << 16; return x.f;
}
__device__ __forceinline__ unsigned short f2bf(float f) {
    union { float f; uint32_t b; } x; x.f = f;
    uint32_t r = x.b + 0x7FFF + ((x.b >> 16) & 1);   // RNE
    return (unsigned short)(r >> 16);
}
__device__ __forceinline__ float fast_silu(float x) {
    return x / (1.f + __expf(-x));
}

// ---------------------------------------------------------------------------
// bf16 MFMA GEMM: C[M,N] = A[M,K] @ Bt[N,K]^T, fp32 acc.
// BM=128, BN=128, BK=64, double-buffered LDS, counted-vmcnt pipeline (T4):
// per K-step: issue next stage (8 gload_lds/thread) -> s_waitcnt vmcnt(8)
// (waits only the PREVIOUS tile's loads; prefetch stays in flight across the
// barrier) -> raw s_barrier -> ds_read+MFMA -> s_barrier. sched_barrier(0)
// pins ordering (rule #18). 4 waves (2x2), wave tile 64x64, 32 MFMA/step.
// XCD-aware chunked swizzle (gridtotal % 8 == 0 everywhere here).
// SPLIT: z slices K; partials to Cpart[z][Md][Nd]; reduce_split* sums.
// ---------------------------------------------------------------------------
template<bool SPLIT, bool PARTBF, bool BIAS, int ACT, bool W32, bool W16>
__global__ __launch_bounds__(256) void gemm_mfma(
    const unsigned short* __restrict__ A, int lda,    // [Md x lda]
    const unsigned short* __restrict__ Bt, int ldb,   // [Nd x ldb]
    const float* __restrict__ bias,                   // [Nd]
    float* __restrict__ C32,
    unsigned short* __restrict__ C16,
    void* __restrict__ Cpart,
    int Md, int Nd, int Kslab)                        // Kslab = K per z-slice
{
    __shared__ short As[2][8 * 128 * 8];   // 16 KB per buf
    __shared__ short Bs[2][8 * 128 * 8];   // 16 KB per buf  (64 KB total)

    // XCD-aware block remap (bijective chunked transform)
    const int nx = gridDim.x, ny = gridDim.y, nz = gridDim.z;
    const int nb = nx * ny * nz;
    int id = blockIdx.x + nx * (blockIdx.y + ny * blockIdx.z);
    int bx, by, bz;
    if ((nb & 7) == 0) {
        int swz = (id & 7) * (nb >> 3) + (id >> 3);
        bx = swz % nx;
        int rem = swz / nx;
        by = rem % ny;
        bz = rem / ny;
    } else {
        bx = blockIdx.x; by = blockIdx.y; bz = blockIdx.z;
    }

    const int tid  = threadIdx.x;
    const int lane = tid & 63;
    const int wid  = tid >> 6;
    const int wr   = wid >> 1;      // 0..1, 64 rows each
    const int wc   = wid & 1;       // 0..1, 64 cols each
    const int l15  = lane & 15;
    const int kg   = lane >> 4;
    const int m0   = bx * 128;
    const int n0   = by * 128;
    const int kbeg = SPLIT ? bz * Kslab : 0;

    floatx4 acc[4][4];
    #pragma unroll
    for (int m = 0; m < 4; m++)
        #pragma unroll
        for (int n = 0; n < 4; n++)
            acc[m][n] = (floatx4){0.f, 0.f, 0.f, 0.f};

    auto stage = [&](int buf, int k0) {
        // A: 1024 cells x 16B (128 rows x 8 k-groups), 4 per thread
        #pragma unroll
        for (int j = 0; j < 4; j++) {
            int c = j * 256 + tid;
            int g = c >> 7, r = c & 127;
            int grow = m0 + r; grow = grow < Md ? grow : Md - 1;
            const __attribute__((address_space(1))) short* src =
                (const __attribute__((address_space(1))) short*)(A + (size_t)grow * lda + k0 + g * 8);
            __builtin_amdgcn_global_load_lds(
                (const __attribute__((address_space(1))) void*)src,
                (__attribute__((address_space(3))) void*)&As[buf][c * 8], 16, 0, 0);
        }
        // B: 1024 cells x 16B (128 rows x 8 k-groups), 4 per thread
        #pragma unroll
        for (int j = 0; j < 4; j++) {
            int c = j * 256 + tid;
            int g = c >> 7, r = c & 127;
            int brow = n0 + r; brow = brow < Nd ? brow : Nd - 1;
            const __attribute__((address_space(1))) short* src =
                (const __attribute__((address_space(1))) short*)(Bt + (size_t)brow * ldb + k0 + g * 8);
            __builtin_amdgcn_global_load_lds(
                (const __attribute__((address_space(1))) void*)src,
                (__attribute__((address_space(3))) void*)&Bs[buf][c * 8], 16, 0, 0);
        }
    };

    stage(0, kbeg);
    asm volatile("s_waitcnt vmcnt(0)" ::: "memory");
    __builtin_amdgcn_s_barrier();
    __builtin_amdgcn_sched_barrier(0);

    const int nt = Kslab >> 6;
    for (int t = 0; t < nt; t++) {
        const int cur = t & 1;
        if (t + 1 < nt) {
            stage(cur ^ 1, kbeg + (t + 1) * 64);            // 8 loads in flight
            asm volatile("s_waitcnt vmcnt(8)" ::: "memory"); // prev tile done
        } else {
            asm volatile("s_waitcnt vmcnt(0)" ::: "memory");
        }
        __builtin_amdgcn_s_barrier();      // buf cur fully staged for all waves
        __builtin_amdgcn_sched_barrier(0);

        short8 a[2][4], bfr[2][4];
        #pragma unroll
        for (int kk = 0; kk < 2; kk++) {
            #pragma unroll
            for (int m = 0; m < 4; m++)
                a[kk][m] = *(const short8*)&As[cur][((kk * 4 + kg) * 128 + wr * 64 + m * 16 + l15) * 8];
            #pragma unroll
            for (int n = 0; n < 4; n++)
                bfr[kk][n] = *(const short8*)&Bs[cur][((kk * 4 + kg) * 128 + wc * 64 + n * 16 + l15) * 8];
        }
        #pragma unroll
        for (int kk = 0; kk < 2; kk++)
            #pragma unroll
            for (int m = 0; m < 4; m++)
                #pragma unroll
                for (int n = 0; n < 4; n++)
                    acc[m][n] = __builtin_amdgcn_mfma_f32_16x16x32_bf16(a[kk][m], bfr[kk][n], acc[m][n], 0, 0, 0);

        __builtin_amdgcn_sched_barrier(0);
        __builtin_amdgcn_s_barrier();      // all waves done reading cur
    }

    // Epilogue: D layout col=lane&15, row=(lane>>4)*4+q
    if (SPLIT) {
        #pragma unroll
        for (int n = 0; n < 4; n++) {
            int col = n0 + wc * 64 + n * 16 + l15;
            if (col >= Nd) continue;
            #pragma unroll
            for (int m = 0; m < 4; m++)
                #pragma unroll
                for (int q = 0; q < 4; q++) {
                    int row = m0 + wr * 64 + m * 16 + kg * 4 + q;
                    if (row >= Md) continue;
                    size_t ix = (size_t)bz * Md * Nd + (size_t)row * Nd + col;
                    if (PARTBF) ((unsigned short*)Cpart)[ix] = f2bf(acc[m][n][q]);
                    else        ((float*)Cpart)[ix] = acc[m][n][q];
                }
        }
    } else {
        #pragma unroll
        for (int n = 0; n < 4; n++) {
            int col = n0 + wc * 64 + n * 16 + l15;
            if (col >= Nd) continue;
            float bv = BIAS ? bias[col] : 0.f;
            #pragma unroll
            for (int m = 0; m < 4; m++)
                #pragma unroll
                for (int q = 0; q < 4; q++) {
                    int row = m0 + wr * 64 + m * 16 + kg * 4 + q;
                    if (row >= Md) continue;
                    float v = acc[m][n][q] + bv;
                    if (ACT == 1) v = fmaxf(v, 0.f) + log1pf(expf(-fabsf(v)));  // softplus
                    if (W32) C32[(size_t)row * Nd + col] = v;
                    if (W16) C16[(size_t)row * Nd + col] = f2bf(v);
                }
        }
    }
}

// ---------------------------------------------------------------------------
// Sum S fp32 split-K partials + bias/act -> fp32/bf16. total % 1024 == 0.
// ---------------------------------------------------------------------------
template<int S, bool BIAS, int ACT, bool W32, bool W16>
__global__ __launch_bounds__(256) void reduce_split(
    const float* __restrict__ P, const float* __restrict__ bias,
    float* __restrict__ C32, unsigned short* __restrict__ C16,
    int total, int nmask)
{
    int i = (blockIdx.x * 256 + threadIdx.x) * 4;
    float4 v = *(const float4*)&P[i];
    #pragma unroll
    for (int s = 1; s < S; s++) {
        float4 p = *(const float4*)&P[(size_t)s * total + i];
        v.x += p.x; v.y += p.y; v.z += p.z; v.w += p.w;
    }
    float r[4] = {v.x, v.y, v.z, v.w};
    #pragma unroll
    for (int j = 0; j < 4; j++) {
        float t = r[j];
        if (BIAS) t += bias[(i + j) & nmask];
        if (ACT == 1) t = fmaxf(t, 0.f) + log1pf(expf(-fabsf(t)));
        if (W32) C32[i + j] = t;
        if (W16) C16[i + j] = f2bf(t);
    }
}

// ---------------------------------------------------------------------------
// Sum S bf16 split-K partials + bias -> bf16. total % 2048 == 0.
// ---------------------------------------------------------------------------
template<int S, bool BIAS>
__global__ __launch_bounds__(256) void reduce_split_bf(
    const unsigned short* __restrict__ P, const float* __restrict__ bias,
    unsigned short* __restrict__ C16, int total, int nmask)
{
    int i = (blockIdx.x * 256 + threadIdx.x) * 8;
    float r[8] = {};
    #pragma unroll
    for (int s = 0; s < S; s++) {
        short8 p = *(const short8*)&P[(size_t)s * total + i];
        #pragma unroll
        for (int j = 0; j < 8; j++) r[j] += bf2f((unsigned short)p[j]);
    }
    short8 o;
    #pragma unroll
    for (int j = 0; j < 8; j++) {
        float t = r[j];
        if (BIAS) t += bias[(i + j) & nmask];
        o[j] = (short)f2bf(t);
    }
    *(short8*)&C16[i] = o;
}

// ---------------------------------------------------------------------------
// fp32 -> bf16 flat convert (n % 1024 == 0)
// ---------------------------------------------------------------------------
__global__ __launch_bounds__(256) void f32_to_bf16_kernel(
    const float* __restrict__ in, unsigned short* __restrict__ out, int n4)
{
    int i = (blockIdx.x * 256 + threadIdx.x) * 4;
    float4 v = *(const float4*)&in[i];
    out[i + 0] = f2bf(v.x);
    out[i + 1] = f2bf(v.y);
    out[i + 2] = f2bf(v.z);
    out[i + 3] = f2bf(v.w);
}

// ---------------------------------------------------------------------------
// Transpose fp32 [K][N] -> bf16 [N][K]  (K,N multiples of 32)
// ---------------------------------------------------------------------------
__global__ __launch_bounds__(256) void transpose_f32_bf16(
    const float* __restrict__ in, unsigned short* __restrict__ out, int K, int N)
{
    __shared__ float t[32][33];
    int k0 = blockIdx.x * 32, n0 = blockIdx.y * 32;
    int tx = threadIdx.x & 31, ty = threadIdx.x >> 5;   // ty 0..7
    #pragma unroll
    for (int i = 0; i < 4; i++)
        t[ty + i * 8][tx] = in[(size_t)(k0 + ty + i * 8) * N + n0 + tx];
    __syncthreads();
    #pragma unroll
    for (int i = 0; i < 4; i++)
        out[(size_t)(n0 + ty + i * 8) * K + k0 + tx] = f2bf(t[tx][ty + i * 8]);
}

// ---------------------------------------------------------------------------
// Causal depthwise conv (K=4) + bias + SiLU; xz is bf16 with row stride 2*DI.
// Writes xc as fp32 (for scan) and bf16 (for proj GEMM).
// ---------------------------------------------------------------------------
__global__ __launch_bounds__(256) void conv_silu_kernel(
    const unsigned short* __restrict__ xz, const float* __restrict__ conv_w,
    const float* __restrict__ conv_b, float* __restrict__ xc,
    unsigned short* __restrict__ xc_bf)
{
    int idx = blockIdx.x * 256 + threadIdx.x;
    if (idx >= Bb * Ll * DI) return;
    int d  = idx & (DI - 1);
    int bl = idx >> 11;
    int l  = bl % Ll;

    float acc = conv_b[d];
    #pragma unroll
    for (int k = 0; k < Kc; k++) {
        int ls = l + k - (Kc - 1);
        if (ls >= 0)
            acc = fmaf(conv_w[d * Kc + k], bf2f(xz[(size_t)(bl + ls - l) * (2 * DI) + d]), acc);
    }
    float s = fast_silu(acc);
    xc[idx] = s;
    xc_bf[idx] = f2bf(s);
}

// ---------------------------------------------------------------------------
// Selective scan, fully state-parallel: 1 state per thread, 16 threads/(b,d).
// 524288 threads = 8192 waves = 32 waves/CU (max occupancy) -> memory latency
// hidden by TLP (R6's 4-state version had only 2048 waves and was
// latency-bound at 75us). y-reduce = 4x shfl_xor within the 16-lane group.
// ---------------------------------------------------------------------------
__global__ __launch_bounds__(256) void scan_kernel(
    const float* __restrict__ delta, const float* __restrict__ xc,
    const unsigned short* __restrict__ xz, const float* __restrict__ proj,
    const float* __restrict__ A_log, const float* __restrict__ Dv,
    unsigned short* __restrict__ y)
{
    const int t    = threadIdx.x;
    const int nq   = t & 15;         // state index 0..15
    const int dloc = t >> 4;         // 0..15
    const int d    = blockIdx.x * 16 + dloc;
    const int b    = blockIdx.y;

    const float Ar = -expf(A_log[(size_t)d * Nst + nq]);
    const float Dd = Dv[d];

    float h = 0.f;

    for (int l = 0; l < Ll; l++) {
        size_t bl = (size_t)b * Ll + l;
        float dl  = delta[bl * DI + d];
        float xcv = xc[bl * DI + d];
        float zv  = bf2f(xz[bl * (2 * DI) + DI + d]);
        const float* p = proj + bl * (DTR + 2 * Nst);
        float Bn = p[DTR + nq];
        float Cn = p[DTR + Nst + nq];

        h = fmaf(__expf(dl * Ar), h, dl * xcv * Bn);

        float yac = h * Cn;
        yac += __shfl_xor(yac, 1);
        yac += __shfl_xor(yac, 2);
        yac += __shfl_xor(yac, 4);
        yac += __shfl_xor(yac, 8);

        if (nq == 0) {
            float yv = yac + Dd * xcv;
            yv *= fast_silu(zv);
            y[bl * DI + d] = f2bf(yv);
        }
    }
}

// ---------------------------------------------------------------------------
// logits[M,16] = out_bf[M,1024] @ W_out[1024,16] + b_out
// ---------------------------------------------------------------------------
__global__ __launch_bounds__(256) void gemm_n16(
    const unsigned short* __restrict__ A, const float* __restrict__ W,
    const float* __restrict__ bias, float* __restrict__ C, int Kd)
{
    int m  = blockIdx.x;
    int t  = threadIdx.x;
    int c  = t & 15;
    int kg = t >> 4;
    const unsigned short* a = A + (size_t)m * Kd;

    float acc = 0.f;
    for (int k = kg; k < Kd; k += 16)
        acc = fmaf(bf2f(a[k]), W[k * NC + c], acc);

    __shared__ float red[256];
    red[t] = acc;
    __syncthreads();
    #pragma unroll
    for (int s = 128; s >= 16; s >>= 1) {
        if (t < s) red[t] += red[t + s];
        __syncthreads();
    }
    if (t < 16) C[(size_t)m * NC + t] = red[t] + bias[t];
}

// ---------------------------------------------------------------------------
extern "C" void kernel_launch(void* const* d_in, const int* in_sizes, int n_in,
                              void* d_out, int out_size, void* d_ws, size_t ws_size,
                              hipStream_t stream) {
    const float* x         = (const float*)d_in[0];
    const float* W_in      = (const float*)d_in[1];
    const float* b_in      = (const float*)d_in[2];
    const float* in_proj_w = (const float*)d_in[3];
    const float* conv_w    = (const float*)d_in[4];
    const float* conv_b    = (const float*)d_in[5];
    const float* x_proj_w  = (const float*)d_in[6];
    const float* dt_proj_w = (const float*)d_in[7];
    const float* dt_proj_b = (const float*)d_in[8];
    const float* A_log     = (const float*)d_in[9];
    const float* Dv        = (const float*)d_in[10];
    const float* out_proj  = (const float*)d_in[11];
    const float* W_out     = (const float*)d_in[12];
    const float* b_out     = (const float*)d_in[13];
    float* logits = (float*)d_out;

    // Workspace layout (bytes, 256-aligned). xc+delta (26.2MB adjacent) double
    // as split-K partial space: P14 bf16 [8][1600][1024] for GEMM1/GEMM7;
    // P8 fp32 [8][1600][96] in delta for proj.
    char* base = (char*)d_ws;
    size_t off = 0;
    auto alloc = [&](size_t bytes) {
        char* p = base + off;
        off += (bytes + 255) & ~(size_t)255;
        return p;
    };
    unsigned short* x_bf    = (unsigned short*)alloc((size_t)M * DIN * 2);
    unsigned short* Wt_in   = (unsigned short*)alloc((size_t)Hh * DIN * 2);
    unsigned short* Wt_ip   = (unsigned short*)alloc((size_t)(2 * DI) * Hh * 2);
    unsigned short* Wt_op   = (unsigned short*)alloc((size_t)Hh * DI * 2);
    unsigned short* xpw_t   = (unsigned short*)alloc((size_t)96 * DI * 2);
    unsigned short* dtw_t   = (unsigned short*)alloc((size_t)DI * DTR * 2);
    unsigned short* h_bf    = (unsigned short*)alloc((size_t)M * Hh * 2);
    unsigned short* xz_bf   = (unsigned short*)alloc((size_t)M * 2 * DI * 2);
    float*          xc      = (float*)alloc((size_t)M * DI * 4);       // | 26.2MB partial
    float*          delta   = (float*)alloc((size_t)M * DI * 4);       // | region
    unsigned short* xc_bf   = (unsigned short*)alloc((size_t)M * DI * 2);
    float*          proj_f  = (float*)alloc((size_t)M * 96 * 4);
    unsigned short* proj_bf = (unsigned short*)alloc((size_t)M * 96 * 2);
    unsigned short* y_bf    = (unsigned short*)alloc((size_t)M * DI * 2);
    unsigned short* out_bf  = (unsigned short*)alloc((size_t)M * Hh * 2);

    unsigned short* P14 = (unsigned short*)xc;   // bf16 [8][1600][1024] = 26.2MB
    float*          P8  = delta;                 // fp32 [8][1600][96]  = 4.9MB

    dim3 blk(256);

    // 0) conversions / weight transposes
    f32_to_bf16_kernel<<<dim3((M * DIN) / 1024), blk, 0, stream>>>(x, x_bf, M * DIN);
    transpose_f32_bf16<<<dim3(DIN / 32, Hh / 32), blk, 0, stream>>>(W_in, Wt_in, DIN, Hh);
    transpose_f32_bf16<<<dim3(Hh / 32, (2 * DI) / 32), blk, 0, stream>>>(in_proj_w, Wt_ip, Hh, 2 * DI);
    transpose_f32_bf16<<<dim3(DI / 32, Hh / 32), blk, 0, stream>>>(out_proj, Wt_op, DI, Hh);
    transpose_f32_bf16<<<dim3(DI / 32, 96 / 32), blk, 0, stream>>>(x_proj_w, xpw_t, DI, 96);
    transpose_f32_bf16<<<dim3(DTR / 32, DI / 32), blk, 0, stream>>>(dt_proj_w, dtw_t, DTR, DI);

    // 1) h = x @ W_in + b_in   [1600,6144]@[6144,1024], split-K 8 -> 832 blocks
    gemm_mfma<true, true, false, 0, false, false><<<dim3(13, Hh / 128, 8), blk, 0, stream>>>(
        x_bf, DIN, Wt_in, DIN, nullptr, nullptr, nullptr, P14, M, Hh, DIN / 8);
    reduce_split_bf<8, true><<<dim3((M * Hh) / 2048), blk, 0, stream>>>(
        P14, b_in, h_bf, M * Hh, Hh - 1);

    // 2) xz = h @ in_proj_w    [1600,1024]@[1024,4096], 416 blocks
    gemm_mfma<false, false, false, 0, false, true><<<dim3(13, (2 * DI) / 128, 1), blk, 0, stream>>>(
        h_bf, Hh, Wt_ip, Hh, nullptr, nullptr, xz_bf, nullptr, M, 2 * DI, Hh);

    // 3) xc = silu(conv(xm) + conv_b)  -> fp32 + bf16
    conv_silu_kernel<<<dim3((Bb * Ll * DI) / 256), blk, 0, stream>>>(
        xz_bf, conv_w, conv_b, xc, xc_bf);

    // 4) proj = xc @ x_proj_w  [1600,2048]@[2048,96], split-K 8 -> 104 blocks
    gemm_mfma<true, false, false, 0, false, false><<<dim3(13, 1, 8), blk, 0, stream>>>(
        xc_bf, DI, xpw_t, DI, nullptr, nullptr, nullptr, P8, M, 96, DI / 8);
    reduce_split<8, false, 0, true, true><<<dim3((M * 96) / 1024), blk, 0, stream>>>(
        P8, nullptr, proj_f, proj_bf, M * 96, 0);

    // 5) delta = softplus(proj[:,:64] @ dt_proj_w + dt_proj_b)  [1600,64]@[64,2048]
    gemm_mfma<false, false, true, 1, true, false><<<dim3(13, DI / 128, 1), blk, 0, stream>>>(
        proj_bf, 96, dtw_t, DTR, dt_proj_b, delta, nullptr, nullptr, M, DI, DTR);

    // 6) selective scan (1 state/thread, 32 waves/CU)
    scan_kernel<<<dim3(DI / 16, Bb), blk, 0, stream>>>(
        delta, xc, xz_bf, proj_f, A_log, Dv, y_bf);

    // 7) out = y @ out_proj_w  [1600,2048]@[2048,1024], split-K 8 -> 832 blocks
    gemm_mfma<true, true, false, 0, false, false><<<dim3(13, Hh / 128, 8), blk, 0, stream>>>(
        y_bf, DI, Wt_op, DI, nullptr, nullptr, nullptr, P14, M, Hh, DI / 8);
    reduce_split_bf<8, false><<<dim3((M * Hh) / 2048), blk, 0, stream>>>(
        P14, nullptr, out_bf, M * Hh, 0);

    // 8) logits = out @ W_out + b_out  [1600,1024]@[1024,16]
    gemm_n16<<<dim3(M), blk, 0, stream>>>(out_bf, W_out, b_out, logits, Hh);
}

// Round 8
// 299.809 us; speedup vs baseline: 6.5848x; 1.1370x over previous
//
#include <hip/hip_runtime.h>
#include <hip/hip_bf16.h>
#include <stdint.h>

// Problem constants
constexpr int Bb  = 16;
constexpr int Ll  = 100;
constexpr int DIN = 6144;
constexpr int Hh  = 1024;
constexpr int DI  = 2048;
constexpr int Nst = 16;
constexpr int DTR = 64;
constexpr int Kc  = 4;
constexpr int NC  = 16;
constexpr int M   = Bb * Ll;   // 1600 tokens
constexpr int NCH = 4;         // scan L-chunks
constexpr int CL  = Ll / NCH;  // 25

typedef __attribute__((ext_vector_type(8))) short short8;
typedef __attribute__((ext_vector_type(4))) float floatx4;

__device__ __forceinline__ float bf2f(unsigned short u) {
    union { uint32_t b; float f; } x; x.b = ((uint32_t)u) << 16; return x.f;
}
__device__ __forceinline__ unsigned short f2bf(float f) {
    union { float f; uint32_t b; } x; x.f = f;
    uint32_t r = x.b + 0x7FFF + ((x.b >> 16) & 1);   // RNE
    return (unsigned short)(r >> 16);
}
__device__ __forceinline__ float fast_silu(float x) {
    return x / (1.f + __expf(-x));
}

// ---------------------------------------------------------------------------
// bf16 MFMA GEMM: C[M,N] = A[M,K] @ Bt[N,K]^T, fp32 acc.
// BM=128, BN=128, BK=64, double-buffered LDS, counted-vmcnt pipeline (T4).
// 4 waves (2x2), wave tile 64x64, 32 MFMA/step. XCD-aware chunked swizzle.
// SPLIT: z slices K; partials to Cpart[z][Md][Nd]; reduce_split* sums.
// ---------------------------------------------------------------------------
template<bool SPLIT, bool PARTBF, bool BIAS, int ACT, bool W32, bool W16>
__global__ __launch_bounds__(256) void gemm_mfma(
    const unsigned short* __restrict__ A, int lda,    // [Md x lda]
    const unsigned short* __restrict__ Bt, int ldb,   // [Nd x ldb]
    const float* __restrict__ bias,                   // [Nd]
    float* __restrict__ C32,
    unsigned short* __restrict__ C16,
    void* __restrict__ Cpart,
    int Md, int Nd, int Kslab)                        // Kslab = K per z-slice
{
    __shared__ short As[2][8 * 128 * 8];   // 16 KB per buf
    __shared__ short Bs[2][8 * 128 * 8];   // 16 KB per buf  (64 KB total)

    // XCD-aware block remap (bijective chunked transform)
    const int nx = gridDim.x, ny = gridDim.y, nz = gridDim.z;
    const int nb = nx * ny * nz;
    int id = blockIdx.x + nx * (blockIdx.y + ny * blockIdx.z);
    int bx, by, bz;
    if ((nb & 7) == 0) {
        int swz = (id & 7) * (nb >> 3) + (id >> 3);
        bx = swz % nx;
        int rem = swz / nx;
        by = rem % ny;
        bz = rem / ny;
    } else {
        bx = blockIdx.x; by = blockIdx.y; bz = blockIdx.z;
    }

    const int tid  = threadIdx.x;
    const int lane = tid & 63;
    const int wid  = tid >> 6;
    const int wr   = wid >> 1;      // 0..1, 64 rows each
    const int wc   = wid & 1;       // 0..1, 64 cols each
    const int l15  = lane & 15;
    const int kg   = lane >> 4;
    const int m0   = bx * 128;
    const int n0   = by * 128;
    const int kbeg = SPLIT ? bz * Kslab : 0;

    floatx4 acc[4][4];
    #pragma unroll
    for (int m = 0; m < 4; m++)
        #pragma unroll
        for (int n = 0; n < 4; n++)
            acc[m][n] = (floatx4){0.f, 0.f, 0.f, 0.f};

    auto stage = [&](int buf, int k0) {
        #pragma unroll
        for (int j = 0; j < 4; j++) {
            int c = j * 256 + tid;
            int g = c >> 7, r = c & 127;
            int grow = m0 + r; grow = grow < Md ? grow : Md - 1;
            const __attribute__((address_space(1))) short* src =
                (const __attribute__((address_space(1))) short*)(A + (size_t)grow * lda + k0 + g * 8);
            __builtin_amdgcn_global_load_lds(
                (const __attribute__((address_space(1))) void*)src,
                (__attribute__((address_space(3))) void*)&As[buf][c * 8], 16, 0, 0);
        }
        #pragma unroll
        for (int j = 0; j < 4; j++) {
            int c = j * 256 + tid;
            int g = c >> 7, r = c & 127;
            int brow = n0 + r; brow = brow < Nd ? brow : Nd - 1;
            const __attribute__((address_space(1))) short* src =
                (const __attribute__((address_space(1))) short*)(Bt + (size_t)brow * ldb + k0 + g * 8);
            __builtin_amdgcn_global_load_lds(
                (const __attribute__((address_space(1))) void*)src,
                (__attribute__((address_space(3))) void*)&Bs[buf][c * 8], 16, 0, 0);
        }
    };

    stage(0, kbeg);
    asm volatile("s_waitcnt vmcnt(0)" ::: "memory");
    __builtin_amdgcn_s_barrier();
    __builtin_amdgcn_sched_barrier(0);

    const int nt = Kslab >> 6;
    for (int t = 0; t < nt; t++) {
        const int cur = t & 1;
        if (t + 1 < nt) {
            stage(cur ^ 1, kbeg + (t + 1) * 64);            // 8 loads in flight
            asm volatile("s_waitcnt vmcnt(8)" ::: "memory"); // prev tile done
        } else {
            asm volatile("s_waitcnt vmcnt(0)" ::: "memory");
        }
        __builtin_amdgcn_s_barrier();      // buf cur fully staged for all waves
        __builtin_amdgcn_sched_barrier(0);

        short8 a[2][4], bfr[2][4];
        #pragma unroll
        for (int kk = 0; kk < 2; kk++) {
            #pragma unroll
            for (int m = 0; m < 4; m++)
                a[kk][m] = *(const short8*)&As[cur][((kk * 4 + kg) * 128 + wr * 64 + m * 16 + l15) * 8];
            #pragma unroll
            for (int n = 0; n < 4; n++)
                bfr[kk][n] = *(const short8*)&Bs[cur][((kk * 4 + kg) * 128 + wc * 64 + n * 16 + l15) * 8];
        }
        #pragma unroll
        for (int kk = 0; kk < 2; kk++)
            #pragma unroll
            for (int m = 0; m < 4; m++)
                #pragma unroll
                for (int n = 0; n < 4; n++)
                    acc[m][n] = __builtin_amdgcn_mfma_f32_16x16x32_bf16(a[kk][m], bfr[kk][n], acc[m][n], 0, 0, 0);

        __builtin_amdgcn_sched_barrier(0);
        __builtin_amdgcn_s_barrier();      // all waves done reading cur
    }

    // Epilogue: D layout col=lane&15, row=(lane>>4)*4+q
    if (SPLIT) {
        #pragma unroll
        for (int n = 0; n < 4; n++) {
            int col = n0 + wc * 64 + n * 16 + l15;
            if (col >= Nd) continue;
            #pragma unroll
            for (int m = 0; m < 4; m++)
                #pragma unroll
                for (int q = 0; q < 4; q++) {
                    int row = m0 + wr * 64 + m * 16 + kg * 4 + q;
                    if (row >= Md) continue;
                    size_t ix = (size_t)bz * Md * Nd + (size_t)row * Nd + col;
                    if (PARTBF) ((unsigned short*)Cpart)[ix] = f2bf(acc[m][n][q]);
                    else        ((float*)Cpart)[ix] = acc[m][n][q];
                }
        }
    } else {
        #pragma unroll
        for (int n = 0; n < 4; n++) {
            int col = n0 + wc * 64 + n * 16 + l15;
            if (col >= Nd) continue;
            float bv = BIAS ? bias[col] : 0.f;
            #pragma unroll
            for (int m = 0; m < 4; m++)
                #pragma unroll
                for (int q = 0; q < 4; q++) {
                    int row = m0 + wr * 64 + m * 16 + kg * 4 + q;
                    if (row >= Md) continue;
                    float v = acc[m][n][q] + bv;
                    if (ACT == 1) v = fmaxf(v, 0.f) + log1pf(expf(-fabsf(v)));  // softplus
                    if (W32) C32[(size_t)row * Nd + col] = v;
                    if (W16) C16[(size_t)row * Nd + col] = f2bf(v);
                }
        }
    }
}

// ---------------------------------------------------------------------------
// Sum S fp32 split-K partials + bias/act -> fp32/bf16. total % 1024 == 0.
// ---------------------------------------------------------------------------
template<int S, bool BIAS, int ACT, bool W32, bool W16>
__global__ __launch_bounds__(256) void reduce_split(
    const float* __restrict__ P, const float* __restrict__ bias,
    float* __restrict__ C32, unsigned short* __restrict__ C16,
    int total, int nmask)
{
    int i = (blockIdx.x * 256 + threadIdx.x) * 4;
    float4 v = *(const float4*)&P[i];
    #pragma unroll
    for (int s = 1; s < S; s++) {
        float4 p = *(const float4*)&P[(size_t)s * total + i];
        v.x += p.x; v.y += p.y; v.z += p.z; v.w += p.w;
    }
    float r[4] = {v.x, v.y, v.z, v.w};
    #pragma unroll
    for (int j = 0; j < 4; j++) {
        float t = r[j];
        if (BIAS) t += bias[(i + j) & nmask];
        if (ACT == 1) t = fmaxf(t, 0.f) + log1pf(expf(-fabsf(t)));
        if (W32) C32[i + j] = t;
        if (W16) C16[i + j] = f2bf(t);
    }
}

// ---------------------------------------------------------------------------
// Sum S bf16 split-K partials + bias -> bf16. total % 2048 == 0.
// ---------------------------------------------------------------------------
template<int S, bool BIAS>
__global__ __launch_bounds__(256) void reduce_split_bf(
    const unsigned short* __restrict__ P, const float* __restrict__ bias,
    unsigned short* __restrict__ C16, int total, int nmask)
{
    int i = (blockIdx.x * 256 + threadIdx.x) * 8;
    float r[8] = {};
    #pragma unroll
    for (int s = 0; s < S; s++) {
        short8 p = *(const short8*)&P[(size_t)s * total + i];
        #pragma unroll
        for (int j = 0; j < 8; j++) r[j] += bf2f((unsigned short)p[j]);
    }
    short8 o;
    #pragma unroll
    for (int j = 0; j < 8; j++) {
        float t = r[j];
        if (BIAS) t += bias[(i + j) & nmask];
        o[j] = (short)f2bf(t);
    }
    *(short8*)&C16[i] = o;
}

// ---------------------------------------------------------------------------
// fp32 -> bf16 flat convert (n % 1024 == 0)
// ---------------------------------------------------------------------------
__global__ __launch_bounds__(256) void f32_to_bf16_kernel(
    const float* __restrict__ in, unsigned short* __restrict__ out, int n4)
{
    int i = (blockIdx.x * 256 + threadIdx.x) * 4;
    float4 v = *(const float4*)&in[i];
    out[i + 0] = f2bf(v.x);
    out[i + 1] = f2bf(v.y);
    out[i + 2] = f2bf(v.z);
    out[i + 3] = f2bf(v.w);
}

// ---------------------------------------------------------------------------
// Transpose fp32 [K][N] -> bf16 [N][K]  (K,N multiples of 32)
// ---------------------------------------------------------------------------
__global__ __launch_bounds__(256) void transpose_f32_bf16(
    const float* __restrict__ in, unsigned short* __restrict__ out, int K, int N)
{
    __shared__ float t[32][33];
    int k0 = blockIdx.x * 32, n0 = blockIdx.y * 32;
    int tx = threadIdx.x & 31, ty = threadIdx.x >> 5;   // ty 0..7
    #pragma unroll
    for (int i = 0; i < 4; i++)
        t[ty + i * 8][tx] = in[(size_t)(k0 + ty + i * 8) * N + n0 + tx];
    __syncthreads();
    #pragma unroll
    for (int i = 0; i < 4; i++)
        out[(size_t)(n0 + ty + i * 8) * K + k0 + tx] = f2bf(t[tx][ty + i * 8]);
}

// ---------------------------------------------------------------------------
// Causal depthwise conv (K=4) + bias + SiLU; xz is bf16 with row stride 2*DI.
// Writes xc as fp32 (for scan) and bf16 (for proj GEMM).
// ---------------------------------------------------------------------------
__global__ __launch_bounds__(256) void conv_silu_kernel(
    const unsigned short* __restrict__ xz, const float* __restrict__ conv_w,
    const float* __restrict__ conv_b, float* __restrict__ xc,
    unsigned short* __restrict__ xc_bf)
{
    int idx = blockIdx.x * 256 + threadIdx.x;
    if (idx >= Bb * Ll * DI) return;
    int d  = idx & (DI - 1);
    int bl = idx >> 11;
    int l  = bl % Ll;

    float acc = conv_b[d];
    #pragma unroll
    for (int k = 0; k < Kc; k++) {
        int ls = l + k - (Kc - 1);
        if (ls >= 0)
            acc = fmaf(conv_w[d * Kc + k], bf2f(xz[(size_t)(bl + ls - l) * (2 * DI) + d]), acc);
    }
    float s = fast_silu(acc);
    xc[idx] = s;
    xc_bf[idx] = f2bf(s);
}

// ---------------------------------------------------------------------------
// Chunked selective scan, 2-pass (h_l = dA_l h_{l-1} + dl*xc_l*B_l):
// L=100 split into NCH=4 chunks of CL=25. Thread layout (R5's, efficient):
// 4 states/thread, 4 threads per (b,d); block = 64 d-channels.
//
// Pass 1 (chunks 0..2): local scan from h=0 -> S = final local h;
//   P = exp(Ar * sum(delta)) = product of chunk's dA (exact closed form).
// Pass 2 (all chunks): h_start = fold of prior (P,S) (<=3 fma4), then plain
//   recurrence seeded with h_start + y output (C-dot, 2x shfl, D*xc, silu(z)).
// Serial depth 100 -> 25; waves 2048 -> 8192 (8/SIMD, latency hideable).
// ---------------------------------------------------------------------------
__global__ __launch_bounds__(256) void scan_part1(
    const float* __restrict__ delta, const float* __restrict__ xc,
    const float* __restrict__ proj,  const float* __restrict__ A_log,
    float* __restrict__ Pbuf, float* __restrict__ Sbuf)
{
    const int t    = threadIdx.x;
    const int nq   = t & 3;
    const int dloc = t >> 2;
    const int d    = blockIdx.x * 64 + dloc;
    const int b    = blockIdx.y;
    const int c    = blockIdx.z;          // chunk 0..NCH-2

    float4 Alq = *(const float4*)&A_log[(size_t)d * Nst + nq * 4];
    float Ar0 = -expf(Alq.x), Ar1 = -expf(Alq.y), Ar2 = -expf(Alq.z), Ar3 = -expf(Alq.w);

    float h0 = 0.f, h1 = 0.f, h2 = 0.f, h3 = 0.f;
    float sdl = 0.f;

    for (int l = c * CL; l < (c + 1) * CL; l++) {
        size_t bl = (size_t)b * Ll + l;
        float dl  = delta[bl * DI + d];
        float xcv = xc[bl * DI + d];
        float dx  = dl * xcv;
        float4 Bv = *(const float4*)&proj[bl * (DTR + 2 * Nst) + DTR + nq * 4];

        h0 = fmaf(__expf(dl * Ar0), h0, dx * Bv.x);
        h1 = fmaf(__expf(dl * Ar1), h1, dx * Bv.y);
        h2 = fmaf(__expf(dl * Ar2), h2, dx * Bv.z);
        h3 = fmaf(__expf(dl * Ar3), h3, dx * Bv.w);
        sdl += dl;
    }

    size_t o = (((size_t)c * Bb + b) * DI + d) * Nst + nq * 4;
    *(float4*)&Pbuf[o] = (float4){__expf(sdl * Ar0), __expf(sdl * Ar1),
                                  __expf(sdl * Ar2), __expf(sdl * Ar3)};
    *(float4*)&Sbuf[o] = (float4){h0, h1, h2, h3};
}

__global__ __launch_bounds__(256) void scan_part2(
    const float* __restrict__ delta, const float* __restrict__ xc,
    const unsigned short* __restrict__ xz, const float* __restrict__ proj,
    const float* __restrict__ A_log, const float* __restrict__ Dv,
    const float* __restrict__ Pbuf, const float* __restrict__ Sbuf,
    unsigned short* __restrict__ y)
{
    const int t    = threadIdx.x;
    const int nq   = t & 3;
    const int dloc = t >> 2;
    const int d    = blockIdx.x * 64 + dloc;
    const int b    = blockIdx.y;
    const int c    = blockIdx.z;          // chunk 0..NCH-1

    float4 Alq = *(const float4*)&A_log[(size_t)d * Nst + nq * 4];
    float Ar0 = -expf(Alq.x), Ar1 = -expf(Alq.y), Ar2 = -expf(Alq.z), Ar3 = -expf(Alq.w);
    const float Dd = Dv[d];

    // h_start = fold of prior chunks' (P,S)
    float h0 = 0.f, h1 = 0.f, h2 = 0.f, h3 = 0.f;
    for (int cc = 0; cc < c; cc++) {
        size_t o = (((size_t)cc * Bb + b) * DI + d) * Nst + nq * 4;
        float4 Pv = *(const float4*)&Pbuf[o];
        float4 Sv = *(const float4*)&Sbuf[o];
        h0 = fmaf(Pv.x, h0, Sv.x);
        h1 = fmaf(Pv.y, h1, Sv.y);
        h2 = fmaf(Pv.z, h2, Sv.z);
        h3 = fmaf(Pv.w, h3, Sv.w);
    }

    for (int l = c * CL; l < (c + 1) * CL; l++) {
        size_t bl = (size_t)b * Ll + l;
        float dl  = delta[bl * DI + d];
        float xcv = xc[bl * DI + d];
        float zv  = bf2f(xz[bl * (2 * DI) + DI + d]);
        float dx  = dl * xcv;
        const float* p = proj + bl * (DTR + 2 * Nst);
        float4 Bv = *(const float4*)&p[DTR + nq * 4];
        float4 Cv = *(const float4*)&p[DTR + Nst + nq * 4];

        h0 = fmaf(__expf(dl * Ar0), h0, dx * Bv.x);
        h1 = fmaf(__expf(dl * Ar1), h1, dx * Bv.y);
        h2 = fmaf(__expf(dl * Ar2), h2, dx * Bv.z);
        h3 = fmaf(__expf(dl * Ar3), h3, dx * Bv.w);

        float yac = h0 * Cv.x + h1 * Cv.y + h2 * Cv.z + h3 * Cv.w;
        yac += __shfl_xor(yac, 1);
        yac += __shfl_xor(yac, 2);

        if (nq == 0) {
            float yv = yac + Dd * xcv;
            yv *= fast_silu(zv);
            y[bl * DI + d] = f2bf(yv);
        }
    }
}

// ---------------------------------------------------------------------------
// logits[M,16] = out_bf[M,1024] @ W_out[1024,16] + b_out
// ---------------------------------------------------------------------------
__global__ __launch_bounds__(256) void gemm_n16(
    const unsigned short* __restrict__ A, const float* __restrict__ W,
    const float* __restrict__ bias, float* __restrict__ C, int Kd)
{
    int m  = blockIdx.x;
    int t  = threadIdx.x;
    int c  = t & 15;
    int kg = t >> 4;
    const unsigned short* a = A + (size_t)m * Kd;

    float acc = 0.f;
    for (int k = kg; k < Kd; k += 16)
        acc = fmaf(bf2f(a[k]), W[k * NC + c], acc);

    __shared__ float red[256];
    red[t] = acc;
    __syncthreads();
    #pragma unroll
    for (int s = 128; s >= 16; s >>= 1) {
        if (t < s) red[t] += red[t + s];
        __syncthreads();
    }
    if (t < 16) C[(size_t)m * NC + t] = red[t] + bias[t];
}

// ---------------------------------------------------------------------------
extern "C" void kernel_launch(void* const* d_in, const int* in_sizes, int n_in,
                              void* d_out, int out_size, void* d_ws, size_t ws_size,
                              hipStream_t stream) {
    const float* x         = (const float*)d_in[0];
    const float* W_in      = (const float*)d_in[1];
    const float* b_in      = (const float*)d_in[2];
    const float* in_proj_w = (const float*)d_in[3];
    const float* conv_w    = (const float*)d_in[4];
    const float* conv_b    = (const float*)d_in[5];
    const float* x_proj_w  = (const float*)d_in[6];
    const float* dt_proj_w = (const float*)d_in[7];
    const float* dt_proj_b = (const float*)d_in[8];
    const float* A_log     = (const float*)d_in[9];
    const float* Dv        = (const float*)d_in[10];
    const float* out_proj  = (const float*)d_in[11];
    const float* W_out     = (const float*)d_in[12];
    const float* b_out     = (const float*)d_in[13];
    float* logits = (float*)d_out;

    // Workspace layout (bytes, 256-aligned). xc+delta (26.2MB adjacent) double
    // as split-K partial space; x_bf (19.7MB, dead after GEMM1) doubles as
    // scan P/S chunk buffers (2 x 6.3MB).
    char* base = (char*)d_ws;
    size_t off = 0;
    auto alloc = [&](size_t bytes) {
        char* p = base + off;
        off += (bytes + 255) & ~(size_t)255;
        return p;
    };
    unsigned short* x_bf    = (unsigned short*)alloc((size_t)M * DIN * 2);
    unsigned short* Wt_in   = (unsigned short*)alloc((size_t)Hh * DIN * 2);
    unsigned short* Wt_ip   = (unsigned short*)alloc((size_t)(2 * DI) * Hh * 2);
    unsigned short* Wt_op   = (unsigned short*)alloc((size_t)Hh * DI * 2);
    unsigned short* xpw_t   = (unsigned short*)alloc((size_t)96 * DI * 2);
    unsigned short* dtw_t   = (unsigned short*)alloc((size_t)DI * DTR * 2);
    unsigned short* h_bf    = (unsigned short*)alloc((size_t)M * Hh * 2);
    unsigned short* xz_bf   = (unsigned short*)alloc((size_t)M * 2 * DI * 2);
    float*          xc      = (float*)alloc((size_t)M * DI * 4);       // | 26.2MB partial
    float*          delta   = (float*)alloc((size_t)M * DI * 4);       // | region
    unsigned short* xc_bf   = (unsigned short*)alloc((size_t)M * DI * 2);
    float*          proj_f  = (float*)alloc((size_t)M * 96 * 4);
    unsigned short* proj_bf = (unsigned short*)alloc((size_t)M * 96 * 2);
    unsigned short* y_bf    = (unsigned short*)alloc((size_t)M * DI * 2);
    unsigned short* out_bf  = (unsigned short*)alloc((size_t)M * Hh * 2);

    unsigned short* P14 = (unsigned short*)xc;   // bf16 [8][1600][1024] = 26.2MB
    float*          P8  = delta;                 // fp32 [8][1600][96]  = 4.9MB
    float*          Pbuf = (float*)x_bf;                         // [3][16][2048][16] f32
    float*          Sbuf = Pbuf + (size_t)(NCH - 1) * Bb * DI * Nst;

    dim3 blk(256);

    // 0) conversions / weight transposes
    f32_to_bf16_kernel<<<dim3((M * DIN) / 1024), blk, 0, stream>>>(x, x_bf, M * DIN);
    transpose_f32_bf16<<<dim3(DIN / 32, Hh / 32), blk, 0, stream>>>(W_in, Wt_in, DIN, Hh);
    transpose_f32_bf16<<<dim3(Hh / 32, (2 * DI) / 32), blk, 0, stream>>>(in_proj_w, Wt_ip, Hh, 2 * DI);
    transpose_f32_bf16<<<dim3(DI / 32, Hh / 32), blk, 0, stream>>>(out_proj, Wt_op, DI, Hh);
    transpose_f32_bf16<<<dim3(DI / 32, 96 / 32), blk, 0, stream>>>(x_proj_w, xpw_t, DI, 96);
    transpose_f32_bf16<<<dim3(DTR / 32, DI / 32), blk, 0, stream>>>(dt_proj_w, dtw_t, DTR, DI);

    // 1) h = x @ W_in + b_in   [1600,6144]@[6144,1024], split-K 8 -> 832 blocks
    gemm_mfma<true, true, false, 0, false, false><<<dim3(13, Hh / 128, 8), blk, 0, stream>>>(
        x_bf, DIN, Wt_in, DIN, nullptr, nullptr, nullptr, P14, M, Hh, DIN / 8);
    reduce_split_bf<8, true><<<dim3((M * Hh) / 2048), blk, 0, stream>>>(
        P14, b_in, h_bf, M * Hh, Hh - 1);

    // 2) xz = h @ in_proj_w    [1600,1024]@[1024,4096], 416 blocks
    gemm_mfma<false, false, false, 0, false, true><<<dim3(13, (2 * DI) / 128, 1), blk, 0, stream>>>(
        h_bf, Hh, Wt_ip, Hh, nullptr, nullptr, xz_bf, nullptr, M, 2 * DI, Hh);

    // 3) xc = silu(conv(xm) + conv_b)  -> fp32 + bf16
    conv_silu_kernel<<<dim3((Bb * Ll * DI) / 256), blk, 0, stream>>>(
        xz_bf, conv_w, conv_b, xc, xc_bf);

    // 4) proj = xc @ x_proj_w  [1600,2048]@[2048,96], split-K 8 -> 104 blocks
    gemm_mfma<true, false, false, 0, false, false><<<dim3(13, 1, 8), blk, 0, stream>>>(
        xc_bf, DI, xpw_t, DI, nullptr, nullptr, nullptr, P8, M, 96, DI / 8);
    reduce_split<8, false, 0, true, true><<<dim3((M * 96) / 1024), blk, 0, stream>>>(
        P8, nullptr, proj_f, proj_bf, M * 96, 0);

    // 5) delta = softplus(proj[:,:64] @ dt_proj_w + dt_proj_b)  [1600,64]@[64,2048]
    gemm_mfma<false, false, true, 1, true, false><<<dim3(13, DI / 128, 1), blk, 0, stream>>>(
        proj_bf, 96, dtw_t, DTR, dt_proj_b, delta, nullptr, nullptr, M, DI, DTR);

    // 6) chunked selective scan: pass1 (chunks 0..2) then pass2 (all 4)
    scan_part1<<<dim3(DI / 64, Bb, NCH - 1), blk, 0, stream>>>(
        delta, xc, proj_f, A_log, Pbuf, Sbuf);
    scan_part2<<<dim3(DI / 64, Bb, NCH), blk, 0, stream>>>(
        delta, xc, xz_bf, proj_f, A_log, Dv, Pbuf, Sbuf, y_bf);

    // 7) out = y @ out_proj_w  [1600,2048]@[2048,1024], split-K 8 -> 832 blocks
    gemm_mfma<true, true, false, 0, false, false><<<dim3(13, Hh / 128, 8), blk, 0, stream>>>(
        y_bf, DI, Wt_op, DI, nullptr, nullptr, nullptr, P14, M, Hh, DI / 8);
    reduce_split_bf<8, false><<<dim3((M * Hh) / 2048), blk, 0, stream>>>(
        P14, nullptr, out_bf, M * Hh, 0);

    // 8) logits = out @ W_out + b_out  [1600,1024]@[1024,16]
    gemm_n16<<<dim3(M), blk, 0, stream>>>(out_bf, W_out, b_out, logits, Hh);
}

// Round 9
// 296.580 us; speedup vs baseline: 6.6565x; 1.0109x over previous
//
#include <hip/hip_runtime.h>
#include <hip/hip_bf16.h>
#include <stdint.h>

// Problem constants
constexpr int Bb  = 16;
constexpr int Ll  = 100;
constexpr int DIN = 6144;
constexpr int Hh  = 1024;
constexpr int DI  = 2048;
constexpr int Nst = 16;
constexpr int DTR = 64;
constexpr int Kc  = 4;
constexpr int NC  = 16;
constexpr int M   = Bb * Ll;   // 1600 tokens
constexpr int NCH = 4;         // scan L-chunks
constexpr int CL  = Ll / NCH;  // 25

typedef __attribute__((ext_vector_type(8))) short short8;
typedef __attribute__((ext_vector_type(4))) float floatx4;

__device__ __forceinline__ float bf2f(unsigned short u) {
    union { uint32_t b; float f; } x; x.b = ((uint32_t)u) << 16; return x.f;
}
__device__ __forceinline__ unsigned short f2bf(float f) {
    union { float f; uint32_t b; } x; x.f = f;
    uint32_t r = x.b + 0x7FFF + ((x.b >> 16) & 1);   // RNE
    return (unsigned short)(r >> 16);
}
__device__ __forceinline__ float fast_silu(float x) {
    return x / (1.f + __expf(-x));
}

// ---------------------------------------------------------------------------
// Deep-pipelined bf16 MFMA GEMM (for the 3 big GEMMs):
// BM=256, BN=128, BK=64; 512 threads = 8 waves (4m x 2n), wave tile 64x64,
// 32 MFMA/K-step/wave. LDS: 3-buffer ring (144 KB, 1 block/CU, 2 waves/SIMD).
// 2-tile-deep prefetch with counted vmcnt (T4): per iter
//   stage(t+2) -> vmcnt(12) [= 2 stages x 6 loads; waits ONLY tile t]
//   -> s_barrier -> ds_read buf[t%3] -> setprio(1) MFMA setprio(0)
//   -> s_barrier.  Loads stay in flight across barriers; never drains mid-loop.
// LDS cell layout (g*ROWS+r)*16B: linear for global_load_lds, 0 bank conflicts
// on ds_read_b128 (measured).  XCD-aware chunked swizzle (grid % 8 == 0).
// SPLIT: z slices K; partials to Cpart[z][Md][Nd]; reduce_split* sums.
// ---------------------------------------------------------------------------
template<bool SPLIT, bool PARTBF, bool BIAS, bool W32, bool W16>
__global__ __launch_bounds__(512) void gemm_deep(
    const unsigned short* __restrict__ A, int lda,    // [Md x lda]
    const unsigned short* __restrict__ Bt, int ldb,   // [Nd x ldb]
    const float* __restrict__ bias,                   // [Nd]
    float* __restrict__ C32,
    unsigned short* __restrict__ C16,
    void* __restrict__ Cpart,
    int Md, int Nd, int Kslab)
{
    __shared__ short As[3 * 8 * 256 * 8];   // 3 x 32 KB
    __shared__ short Bs[3 * 8 * 128 * 8];   // 3 x 16 KB

    // XCD-aware block remap
    const int nx = gridDim.x, ny = gridDim.y, nz = gridDim.z;
    const int nb = nx * ny * nz;
    int id = blockIdx.x + nx * (blockIdx.y + ny * blockIdx.z);
    int bx, by, bz;
    if ((nb & 7) == 0) {
        int swz = (id & 7) * (nb >> 3) + (id >> 3);
        bx = swz % nx;
        int rem = swz / nx;
        by = rem % ny;
        bz = rem / ny;
    } else {
        bx = blockIdx.x; by = blockIdx.y; bz = blockIdx.z;
    }

    const int tid  = threadIdx.x;
    const int lane = tid & 63;
    const int wid  = tid >> 6;      // 0..7
    const int wr   = wid >> 1;      // 0..3 (m), 64 rows each
    const int wc   = wid & 1;       // 0..1 (n), 64 cols each
    const int l15  = lane & 15;
    const int kg   = lane >> 4;
    const int m0   = bx * 256;
    const int n0   = by * 128;
    const int kbeg = SPLIT ? bz * Kslab : 0;

    floatx4 acc[4][4];
    #pragma unroll
    for (int m = 0; m < 4; m++)
        #pragma unroll
        for (int n = 0; n < 4; n++)
            acc[m][n] = (floatx4){0.f, 0.f, 0.f, 0.f};

    auto stage = [&](int buf, int k0) {
        // A: 2048 cells x 16B (8 kgroups x 256 rows), 4 per thread
        #pragma unroll
        for (int j = 0; j < 4; j++) {
            int c = j * 512 + tid;
            int g = c >> 8, r = c & 255;
            int grow = m0 + r; grow = grow < Md ? grow : Md - 1;
            const __attribute__((address_space(1))) short* src =
                (const __attribute__((address_space(1))) short*)(A + (size_t)grow * lda + k0 + g * 8);
            __builtin_amdgcn_global_load_lds(
                (const __attribute__((address_space(1))) void*)src,
                (__attribute__((address_space(3))) void*)&As[(buf * 2048 + c) * 8], 16, 0, 0);
        }
        // B: 1024 cells x 16B (8 kgroups x 128 rows), 2 per thread
        #pragma unroll
        for (int j = 0; j < 2; j++) {
            int c = j * 512 + tid;
            int g = c >> 7, r = c & 127;
            int brow = n0 + r; brow = brow < Nd ? brow : Nd - 1;
            const __attribute__((address_space(1))) short* src =
                (const __attribute__((address_space(1))) short*)(Bt + (size_t)brow * ldb + k0 + g * 8);
            __builtin_amdgcn_global_load_lds(
                (const __attribute__((address_space(1))) void*)src,
                (__attribute__((address_space(3))) void*)&Bs[(buf * 1024 + c) * 8], 16, 0, 0);
        }
    };

    const int nt = Kslab >> 6;      // >= 3 for all uses (8/16/24)
    stage(0, kbeg);
    stage(1, kbeg + 64);

    for (int t = 0; t < nt; t++) {
        const int cur = t % 3;
        if (t + 2 < nt) {
            stage((t + 2) % 3, kbeg + (t + 2) * 64);
            asm volatile("s_waitcnt vmcnt(12)" ::: "memory");  // tile t landed
        } else if (t + 1 < nt) {
            asm volatile("s_waitcnt vmcnt(6)" ::: "memory");
        } else {
            asm volatile("s_waitcnt vmcnt(0)" ::: "memory");
        }
        __builtin_amdgcn_s_barrier();       // buf cur published to all waves
        __builtin_amdgcn_sched_barrier(0);

        short8 a[2][4], bfr[2][4];
        #pragma unroll
        for (int kk = 0; kk < 2; kk++) {
            #pragma unroll
            for (int m = 0; m < 4; m++)
                a[kk][m] = *(const short8*)&As[(cur * 2048 + (kk * 4 + kg) * 256 + wr * 64 + m * 16 + l15) * 8];
            #pragma unroll
            for (int n = 0; n < 4; n++)
                bfr[kk][n] = *(const short8*)&Bs[(cur * 1024 + (kk * 4 + kg) * 128 + wc * 64 + n * 16 + l15) * 8];
        }
        __builtin_amdgcn_s_setprio(1);
        #pragma unroll
        for (int kk = 0; kk < 2; kk++)
            #pragma unroll
            for (int m = 0; m < 4; m++)
                #pragma unroll
                for (int n = 0; n < 4; n++)
                    acc[m][n] = __builtin_amdgcn_mfma_f32_16x16x32_bf16(a[kk][m], bfr[kk][n], acc[m][n], 0, 0, 0);
        __builtin_amdgcn_s_setprio(0);
        __builtin_amdgcn_sched_barrier(0);
        __builtin_amdgcn_s_barrier();       // all waves done reading buf cur
    }

    // Epilogue: D layout col=lane&15, row=(lane>>4)*4+q
    #pragma unroll
    for (int n = 0; n < 4; n++) {
        int col = n0 + wc * 64 + n * 16 + l15;
        if (col >= Nd) continue;
        float bv = BIAS ? bias[col] : 0.f;
        #pragma unroll
        for (int m = 0; m < 4; m++) {
            #pragma unroll
            for (int q = 0; q < 4; q++) {
                int row = m0 + wr * 64 + m * 16 + kg * 4 + q;
                if (row >= Md) continue;
                if (SPLIT) {
                    size_t ix = (size_t)bz * Md * Nd + (size_t)row * Nd + col;
                    if (PARTBF) ((unsigned short*)Cpart)[ix] = f2bf(acc[m][n][q]);
                    else        ((float*)Cpart)[ix] = acc[m][n][q];
                } else {
                    float v = acc[m][n][q] + bv;
                    if (W32) C32[(size_t)row * Nd + col] = v;
                    if (W16) C16[(size_t)row * Nd + col] = f2bf(v);
                }
            }
        }
    }
}

// ---------------------------------------------------------------------------
// R8's BM=128/BN=128/BK=64 dbuf kernel — kept for the small GEMMs (4 & 5).
// ---------------------------------------------------------------------------
template<bool SPLIT, bool PARTBF, bool BIAS, int ACT, bool W32, bool W16>
__global__ __launch_bounds__(256) void gemm_mfma(
    const unsigned short* __restrict__ A, int lda,
    const unsigned short* __restrict__ Bt, int ldb,
    const float* __restrict__ bias,
    float* __restrict__ C32,
    unsigned short* __restrict__ C16,
    void* __restrict__ Cpart,
    int Md, int Nd, int Kslab)
{
    __shared__ short As[2][8 * 128 * 8];
    __shared__ short Bs[2][8 * 128 * 8];

    const int nx = gridDim.x, ny = gridDim.y, nz = gridDim.z;
    const int nb = nx * ny * nz;
    int id = blockIdx.x + nx * (blockIdx.y + ny * blockIdx.z);
    int bx, by, bz;
    if ((nb & 7) == 0) {
        int swz = (id & 7) * (nb >> 3) + (id >> 3);
        bx = swz % nx;
        int rem = swz / nx;
        by = rem % ny;
        bz = rem / ny;
    } else {
        bx = blockIdx.x; by = blockIdx.y; bz = blockIdx.z;
    }

    const int tid  = threadIdx.x;
    const int lane = tid & 63;
    const int wid  = tid >> 6;
    const int wr   = wid >> 1;
    const int wc   = wid & 1;
    const int l15  = lane & 15;
    const int kg   = lane >> 4;
    const int m0   = bx * 128;
    const int n0   = by * 128;
    const int kbeg = SPLIT ? bz * Kslab : 0;

    floatx4 acc[4][4];
    #pragma unroll
    for (int m = 0; m < 4; m++)
        #pragma unroll
        for (int n = 0; n < 4; n++)
            acc[m][n] = (floatx4){0.f, 0.f, 0.f, 0.f};

    auto stage = [&](int buf, int k0) {
        #pragma unroll
        for (int j = 0; j < 4; j++) {
            int c = j * 256 + tid;
            int g = c >> 7, r = c & 127;
            int grow = m0 + r; grow = grow < Md ? grow : Md - 1;
            const __attribute__((address_space(1))) short* src =
                (const __attribute__((address_space(1))) short*)(A + (size_t)grow * lda + k0 + g * 8);
            __builtin_amdgcn_global_load_lds(
                (const __attribute__((address_space(1))) void*)src,
                (__attribute__((address_space(3))) void*)&As[buf][c * 8], 16, 0, 0);
        }
        #pragma unroll
        for (int j = 0; j < 4; j++) {
            int c = j * 256 + tid;
            int g = c >> 7, r = c & 127;
            int brow = n0 + r; brow = brow < Nd ? brow : Nd - 1;
            const __attribute__((address_space(1))) short* src =
                (const __attribute__((address_space(1))) short*)(Bt + (size_t)brow * ldb + k0 + g * 8);
            __builtin_amdgcn_global_load_lds(
                (const __attribute__((address_space(1))) void*)src,
                (__attribute__((address_space(3))) void*)&Bs[buf][c * 8], 16, 0, 0);
        }
    };

    stage(0, kbeg);
    asm volatile("s_waitcnt vmcnt(0)" ::: "memory");
    __builtin_amdgcn_s_barrier();
    __builtin_amdgcn_sched_barrier(0);

    const int nt = Kslab >> 6;
    for (int t = 0; t < nt; t++) {
        const int cur = t & 1;
        if (t + 1 < nt) {
            stage(cur ^ 1, kbeg + (t + 1) * 64);
            asm volatile("s_waitcnt vmcnt(8)" ::: "memory");
        } else {
            asm volatile("s_waitcnt vmcnt(0)" ::: "memory");
        }
        __builtin_amdgcn_s_barrier();
        __builtin_amdgcn_sched_barrier(0);

        short8 a[2][4], bfr[2][4];
        #pragma unroll
        for (int kk = 0; kk < 2; kk++) {
            #pragma unroll
            for (int m = 0; m < 4; m++)
                a[kk][m] = *(const short8*)&As[cur][((kk * 4 + kg) * 128 + wr * 64 + m * 16 + l15) * 8];
            #pragma unroll
            for (int n = 0; n < 4; n++)
                bfr[kk][n] = *(const short8*)&Bs[cur][((kk * 4 + kg) * 128 + wc * 64 + n * 16 + l15) * 8];
        }
        #pragma unroll
        for (int kk = 0; kk < 2; kk++)
            #pragma unroll
            for (int m = 0; m < 4; m++)
                #pragma unroll
                for (int n = 0; n < 4; n++)
                    acc[m][n] = __builtin_amdgcn_mfma_f32_16x16x32_bf16(a[kk][m], bfr[kk][n], acc[m][n], 0, 0, 0);

        __builtin_amdgcn_sched_barrier(0);
        __builtin_amdgcn_s_barrier();
    }

    if (SPLIT) {
        #pragma unroll
        for (int n = 0; n < 4; n++) {
            int col = n0 + wc * 64 + n * 16 + l15;
            if (col >= Nd) continue;
            #pragma unroll
            for (int m = 0; m < 4; m++)
                #pragma unroll
                for (int q = 0; q < 4; q++) {
                    int row = m0 + wr * 64 + m * 16 + kg * 4 + q;
                    if (row >= Md) continue;
                    size_t ix = (size_t)bz * Md * Nd + (size_t)row * Nd + col;
                    if (PARTBF) ((unsigned short*)Cpart)[ix] = f2bf(acc[m][n][q]);
                    else        ((float*)Cpart)[ix] = acc[m][n][q];
                }
        }
    } else {
        #pragma unroll
        for (int n = 0; n < 4; n++) {
            int col = n0 + wc * 64 + n * 16 + l15;
            if (col >= Nd) continue;
            float bv = BIAS ? bias[col] : 0.f;
            #pragma unroll
            for (int m = 0; m < 4; m++)
                #pragma unroll
                for (int q = 0; q < 4; q++) {
                    int row = m0 + wr * 64 + m * 16 + kg * 4 + q;
                    if (row >= Md) continue;
                    float v = acc[m][n][q] + bv;
                    if (ACT == 1) v = fmaxf(v, 0.f) + log1pf(expf(-fabsf(v)));  // softplus
                    if (W32) C32[(size_t)row * Nd + col] = v;
                    if (W16) C16[(size_t)row * Nd + col] = f2bf(v);
                }
        }
    }
}

// ---------------------------------------------------------------------------
// Sum S fp32 split-K partials + bias/act -> fp32/bf16. total % 1024 == 0.
// ---------------------------------------------------------------------------
template<int S, bool BIAS, int ACT, bool W32, bool W16>
__global__ __launch_bounds__(256) void reduce_split(
    const float* __restrict__ P, const float* __restrict__ bias,
    float* __restrict__ C32, unsigned short* __restrict__ C16,
    int total, int nmask)
{
    int i = (blockIdx.x * 256 + threadIdx.x) * 4;
    float4 v = *(const float4*)&P[i];
    #pragma unroll
    for (int s = 1; s < S; s++) {
        float4 p = *(const float4*)&P[(size_t)s * total + i];
        v.x += p.x; v.y += p.y; v.z += p.z; v.w += p.w;
    }
    float r[4] = {v.x, v.y, v.z, v.w};
    #pragma unroll
    for (int j = 0; j < 4; j++) {
        float t = r[j];
        if (BIAS) t += bias[(i + j) & nmask];
        if (ACT == 1) t = fmaxf(t, 0.f) + log1pf(expf(-fabsf(t)));
        if (W32) C32[i + j] = t;
        if (W16) C16[i + j] = f2bf(t);
    }
}

// ---------------------------------------------------------------------------
// Sum S bf16 split-K partials + bias -> bf16. total % 2048 == 0.
// ---------------------------------------------------------------------------
template<int S, bool BIAS>
__global__ __launch_bounds__(256) void reduce_split_bf(
    const unsigned short* __restrict__ P, const float* __restrict__ bias,
    unsigned short* __restrict__ C16, int total, int nmask)
{
    int i = (blockIdx.x * 256 + threadIdx.x) * 8;
    float r[8] = {};
    #pragma unroll
    for (int s = 0; s < S; s++) {
        short8 p = *(const short8*)&P[(size_t)s * total + i];
        #pragma unroll
        for (int j = 0; j < 8; j++) r[j] += bf2f((unsigned short)p[j]);
    }
    short8 o;
    #pragma unroll
    for (int j = 0; j < 8; j++) {
        float t = r[j];
        if (BIAS) t += bias[(i + j) & nmask];
        o[j] = (short)f2bf(t);
    }
    *(short8*)&C16[i] = o;
}

// ---------------------------------------------------------------------------
// fp32 -> bf16 flat convert (n % 1024 == 0)
// ---------------------------------------------------------------------------
__global__ __launch_bounds__(256) void f32_to_bf16_kernel(
    const float* __restrict__ in, unsigned short* __restrict__ out, int n4)
{
    int i = (blockIdx.x * 256 + threadIdx.x) * 4;
    float4 v = *(const float4*)&in[i];
    out[i + 0] = f2bf(v.x);
    out[i + 1] = f2bf(v.y);
    out[i + 2] = f2bf(v.z);
    out[i + 3] = f2bf(v.w);
}

// ---------------------------------------------------------------------------
// Transpose fp32 [K][N] -> bf16 [N][K]  (K,N multiples of 32)
// ---------------------------------------------------------------------------
__global__ __launch_bounds__(256) void transpose_f32_bf16(
    const float* __restrict__ in, unsigned short* __restrict__ out, int K, int N)
{
    __shared__ float t[32][33];
    int k0 = blockIdx.x * 32, n0 = blockIdx.y * 32;
    int tx = threadIdx.x & 31, ty = threadIdx.x >> 5;   // ty 0..7
    #pragma unroll
    for (int i = 0; i < 4; i++)
        t[ty + i * 8][tx] = in[(size_t)(k0 + ty + i * 8) * N + n0 + tx];
    __syncthreads();
    #pragma unroll
    for (int i = 0; i < 4; i++)
        out[(size_t)(n0 + ty + i * 8) * K + k0 + tx] = f2bf(t[tx][ty + i * 8]);
}

// ---------------------------------------------------------------------------
// Causal depthwise conv (K=4) + bias + SiLU; xz is bf16 with row stride 2*DI.
// ---------------------------------------------------------------------------
__global__ __launch_bounds__(256) void conv_silu_kernel(
    const unsigned short* __restrict__ xz, const float* __restrict__ conv_w,
    const float* __restrict__ conv_b, float* __restrict__ xc,
    unsigned short* __restrict__ xc_bf)
{
    int idx = blockIdx.x * 256 + threadIdx.x;
    if (idx >= Bb * Ll * DI) return;
    int d  = idx & (DI - 1);
    int bl = idx >> 11;
    int l  = bl % Ll;

    float acc = conv_b[d];
    #pragma unroll
    for (int k = 0; k < Kc; k++) {
        int ls = l + k - (Kc - 1);
        if (ls >= 0)
            acc = fmaf(conv_w[d * Kc + k], bf2f(xz[(size_t)(bl + ls - l) * (2 * DI) + d]), acc);
    }
    float s = fast_silu(acc);
    xc[idx] = s;
    xc_bf[idx] = f2bf(s);
}

// ---------------------------------------------------------------------------
// Chunked selective scan, 2-pass. See R8 comments.
// ---------------------------------------------------------------------------
__global__ __launch_bounds__(256) void scan_part1(
    const float* __restrict__ delta, const float* __restrict__ xc,
    const float* __restrict__ proj,  const float* __restrict__ A_log,
    float* __restrict__ Pbuf, float* __restrict__ Sbuf)
{
    const int t    = threadIdx.x;
    const int nq   = t & 3;
    const int dloc = t >> 2;
    const int d    = blockIdx.x * 64 + dloc;
    const int b    = blockIdx.y;
    const int c    = blockIdx.z;

    float4 Alq = *(const float4*)&A_log[(size_t)d * Nst + nq * 4];
    float Ar0 = -expf(Alq.x), Ar1 = -expf(Alq.y), Ar2 = -expf(Alq.z), Ar3 = -expf(Alq.w);

    float h0 = 0.f, h1 = 0.f, h2 = 0.f, h3 = 0.f;
    float sdl = 0.f;

    for (int l = c * CL; l < (c + 1) * CL; l++) {
        size_t bl = (size_t)b * Ll + l;
        float dl  = delta[bl * DI + d];
        float xcv = xc[bl * DI + d];
        float dx  = dl * xcv;
        float4 Bv = *(const float4*)&proj[bl * (DTR + 2 * Nst) + DTR + nq * 4];

        h0 = fmaf(__expf(dl * Ar0), h0, dx * Bv.x);
        h1 = fmaf(__expf(dl * Ar1), h1, dx * Bv.y);
        h2 = fmaf(__expf(dl * Ar2), h2, dx * Bv.z);
        h3 = fmaf(__expf(dl * Ar3), h3, dx * Bv.w);
        sdl += dl;
    }

    size_t o = (((size_t)c * Bb + b) * DI + d) * Nst + nq * 4;
    *(float4*)&Pbuf[o] = (float4){__expf(sdl * Ar0), __expf(sdl * Ar1),
                                  __expf(sdl * Ar2), __expf(sdl * Ar3)};
    *(float4*)&Sbuf[o] = (float4){h0, h1, h2, h3};
}

__global__ __launch_bounds__(256) void scan_part2(
    const float* __restrict__ delta, const float* __restrict__ xc,
    const unsigned short* __restrict__ xz, const float* __restrict__ proj,
    const float* __restrict__ A_log, const float* __restrict__ Dv,
    const float* __restrict__ Pbuf, const float* __restrict__ Sbuf,
    unsigned short* __restrict__ y)
{
    const int t    = threadIdx.x;
    const int nq   = t & 3;
    const int dloc = t >> 2;
    const int d    = blockIdx.x * 64 + dloc;
    const int b    = blockIdx.y;
    const int c    = blockIdx.z;

    float4 Alq = *(const float4*)&A_log[(size_t)d * Nst + nq * 4];
    float Ar0 = -expf(Alq.x), Ar1 = -expf(Alq.y), Ar2 = -expf(Alq.z), Ar3 = -expf(Alq.w);
    const float Dd = Dv[d];

    float h0 = 0.f, h1 = 0.f, h2 = 0.f, h3 = 0.f;
    for (int cc = 0; cc < c; cc++) {
        size_t o = (((size_t)cc * Bb + b) * DI + d) * Nst + nq * 4;
        float4 Pv = *(const float4*)&Pbuf[o];
        float4 Sv = *(const float4*)&Sbuf[o];
        h0 = fmaf(Pv.x, h0, Sv.x);
        h1 = fmaf(Pv.y, h1, Sv.y);
        h2 = fmaf(Pv.z, h2, Sv.z);
        h3 = fmaf(Pv.w, h3, Sv.w);
    }

    for (int l = c * CL; l < (c + 1) * CL; l++) {
        size_t bl = (size_t)b * Ll + l;
        float dl  = delta[bl * DI + d];
        float xcv = xc[bl * DI + d];
        float zv  = bf2f(xz[bl * (2 * DI) + DI + d]);
        float dx  = dl * xcv;
        const float* p = proj + bl * (DTR + 2 * Nst);
        float4 Bv = *(const float4*)&p[DTR + nq * 4];
        float4 Cv = *(const float4*)&p[DTR + Nst + nq * 4];

        h0 = fmaf(__expf(dl * Ar0), h0, dx * Bv.x);
        h1 = fmaf(__expf(dl * Ar1), h1, dx * Bv.y);
        h2 = fmaf(__expf(dl * Ar2), h2, dx * Bv.z);
        h3 = fmaf(__expf(dl * Ar3), h3, dx * Bv.w);

        float yac = h0 * Cv.x + h1 * Cv.y + h2 * Cv.z + h3 * Cv.w;
        yac += __shfl_xor(yac, 1);
        yac += __shfl_xor(yac, 2);

        if (nq == 0) {
            float yv = yac + Dd * xcv;
            yv *= fast_silu(zv);
            y[bl * DI + d] = f2bf(yv);
        }
    }
}

// ---------------------------------------------------------------------------
// logits[M,16] = out_bf[M,1024] @ W_out[1024,16] + b_out
// ---------------------------------------------------------------------------
__global__ __launch_bounds__(256) void gemm_n16(
    const unsigned short* __restrict__ A, const float* __restrict__ W,
    const float* __restrict__ bias, float* __restrict__ C, int Kd)
{
    int m  = blockIdx.x;
    int t  = threadIdx.x;
    int c  = t & 15;
    int kg = t >> 4;
    const unsigned short* a = A + (size_t)m * Kd;

    float acc = 0.f;
    for (int k = kg; k < Kd; k += 16)
        acc = fmaf(bf2f(a[k]), W[k * NC + c], acc);

    __shared__ float red[256];
    red[t] = acc;
    __syncthreads();
    #pragma unroll
    for (int s = 128; s >= 16; s >>= 1) {
        if (t < s) red[t] += red[t + s];
        __syncthreads();
    }
    if (t < 16) C[(size_t)m * NC + t] = red[t] + bias[t];
}

// ---------------------------------------------------------------------------
extern "C" void kernel_launch(void* const* d_in, const int* in_sizes, int n_in,
                              void* d_out, int out_size, void* d_ws, size_t ws_size,
                              hipStream_t stream) {
    const float* x         = (const float*)d_in[0];
    const float* W_in      = (const float*)d_in[1];
    const float* b_in      = (const float*)d_in[2];
    const float* in_proj_w = (const float*)d_in[3];
    const float* conv_w    = (const float*)d_in[4];
    const float* conv_b    = (const float*)d_in[5];
    const float* x_proj_w  = (const float*)d_in[6];
    const float* dt_proj_w = (const float*)d_in[7];
    const float* dt_proj_b = (const float*)d_in[8];
    const float* A_log     = (const float*)d_in[9];
    const float* Dv        = (const float*)d_in[10];
    const float* out_proj  = (const float*)d_in[11];
    const float* W_out     = (const float*)d_in[12];
    const float* b_out     = (const float*)d_in[13];
    float* logits = (float*)d_out;

    char* base = (char*)d_ws;
    size_t off = 0;
    auto alloc = [&](size_t bytes) {
        char* p = base + off;
        off += (bytes + 255) & ~(size_t)255;
        return p;
    };
    unsigned short* x_bf    = (unsigned short*)alloc((size_t)M * DIN * 2);
    unsigned short* Wt_in   = (unsigned short*)alloc((size_t)Hh * DIN * 2);
    unsigned short* Wt_ip   = (unsigned short*)alloc((size_t)(2 * DI) * Hh * 2);
    unsigned short* Wt_op   = (unsigned short*)alloc((size_t)Hh * DI * 2);
    unsigned short* xpw_t   = (unsigned short*)alloc((size_t)96 * DI * 2);
    unsigned short* dtw_t   = (unsigned short*)alloc((size_t)DI * DTR * 2);
    unsigned short* h_bf    = (unsigned short*)alloc((size_t)M * Hh * 2);
    unsigned short* xz_bf   = (unsigned short*)alloc((size_t)M * 2 * DI * 2);
    float*          xc      = (float*)alloc((size_t)M * DI * 4);       // | partials alias
    float*          delta   = (float*)alloc((size_t)M * DI * 4);       // | region
    unsigned short* xc_bf   = (unsigned short*)alloc((size_t)M * DI * 2);
    float*          proj_f  = (float*)alloc((size_t)M * 96 * 4);
    unsigned short* proj_bf = (unsigned short*)alloc((size_t)M * 96 * 2);
    unsigned short* y_bf    = (unsigned short*)alloc((size_t)M * DI * 2);
    unsigned short* out_bf  = (unsigned short*)alloc((size_t)M * Hh * 2);

    unsigned short* P14 = (unsigned short*)xc;   // bf16 [4][1600][1024] = 13.1MB (fits xc)
    float*          P8  = delta;                 // fp32 [8][1600][96]  = 4.9MB
    float*          Pbuf = (float*)x_bf;         // scan chunk buffers (x_bf dead)
    float*          Sbuf = Pbuf + (size_t)(NCH - 1) * Bb * DI * Nst;

    dim3 blk(256), blk5(512);

    // 0) conversions / weight transposes
    f32_to_bf16_kernel<<<dim3((M * DIN) / 1024), blk, 0, stream>>>(x, x_bf, M * DIN);
    transpose_f32_bf16<<<dim3(DIN / 32, Hh / 32), blk, 0, stream>>>(W_in, Wt_in, DIN, Hh);
    transpose_f32_bf16<<<dim3(Hh / 32, (2 * DI) / 32), blk, 0, stream>>>(in_proj_w, Wt_ip, Hh, 2 * DI);
    transpose_f32_bf16<<<dim3(DI / 32, Hh / 32), blk, 0, stream>>>(out_proj, Wt_op, DI, Hh);
    transpose_f32_bf16<<<dim3(DI / 32, 96 / 32), blk, 0, stream>>>(x_proj_w, xpw_t, DI, 96);
    transpose_f32_bf16<<<dim3(DTR / 32, DI / 32), blk, 0, stream>>>(dt_proj_w, dtw_t, DTR, DI);

    // 1) h = x @ W_in + b_in   [1600,6144]@[6144,1024], split-K 4 -> 224 blocks
    gemm_deep<true, true, false, false, false><<<dim3(7, Hh / 128, 4), blk5, 0, stream>>>(
        x_bf, DIN, Wt_in, DIN, nullptr, nullptr, nullptr, P14, M, Hh, DIN / 4);
    reduce_split_bf<4, true><<<dim3((M * Hh) / 2048), blk, 0, stream>>>(
        P14, b_in, h_bf, M * Hh, Hh - 1);

    // 2) xz = h @ in_proj_w    [1600,1024]@[1024,4096], 224 blocks, no split
    gemm_deep<false, false, false, false, true><<<dim3(7, (2 * DI) / 128, 1), blk5, 0, stream>>>(
        h_bf, Hh, Wt_ip, Hh, nullptr, nullptr, xz_bf, nullptr, M, 2 * DI, Hh);

    // 3) xc = silu(conv(xm) + conv_b)  -> fp32 + bf16
    conv_silu_kernel<<<dim3((Bb * Ll * DI) / 256), blk, 0, stream>>>(
        xz_bf, conv_w, conv_b, xc, xc_bf);

    // 4) proj = xc @ x_proj_w  [1600,2048]@[2048,96], split-K 8 -> 104 blocks
    gemm_mfma<true, false, false, 0, false, false><<<dim3(13, 1, 8), blk, 0, stream>>>(
        xc_bf, DI, xpw_t, DI, nullptr, nullptr, nullptr, P8, M, 96, DI / 8);
    reduce_split<8, false, 0, true, true><<<dim3((M * 96) / 1024), blk, 0, stream>>>(
        P8, nullptr, proj_f, proj_bf, M * 96, 0);

    // 5) delta = softplus(proj[:,:64] @ dt_proj_w + dt_proj_b)  [1600,64]@[64,2048]
    gemm_mfma<false, false, true, 1, true, false><<<dim3(13, DI / 128, 1), blk, 0, stream>>>(
        proj_bf, 96, dtw_t, DTR, dt_proj_b, delta, nullptr, nullptr, M, DI, DTR);

    // 6) chunked selective scan: pass1 (chunks 0..2) then pass2 (all 4)
    scan_part1<<<dim3(DI / 64, Bb, NCH - 1), blk, 0, stream>>>(
        delta, xc, proj_f, A_log, Pbuf, Sbuf);
    scan_part2<<<dim3(DI / 64, Bb, NCH), blk, 0, stream>>>(
        delta, xc, xz_bf, proj_f, A_log, Dv, Pbuf, Sbuf, y_bf);

    // 7) out = y @ out_proj_w  [1600,2048]@[2048,1024], split-K 4 -> 224 blocks
    gemm_deep<true, true, false, false, false><<<dim3(7, Hh / 128, 4), blk5, 0, stream>>>(
        y_bf, DI, Wt_op, DI, nullptr, nullptr, nullptr, P14, M, Hh, DI / 4);
    reduce_split_bf<4, false><<<dim3((M * Hh) / 2048), blk, 0, stream>>>(
        P14, nullptr, out_bf, M * Hh, 0);

    // 8) logits = out @ W_out + b_out  [1600,1024]@[1024,16]
    gemm_n16<<<dim3(M), blk, 0, stream>>>(out_bf, W_out, b_out, logits, Hh);
}

// Round 10
// 294.550 us; speedup vs baseline: 6.7024x; 1.0069x over previous
//
#include <hip/hip_runtime.h>
#include <hip/hip_bf16.h>
#include <stdint.h>

// Problem constants
constexpr int Bb  = 16;
constexpr int Ll  = 100;
constexpr int DIN = 6144;
constexpr int Hh  = 1024;
constexpr int DI  = 2048;
constexpr int Nst = 16;
constexpr int DTR = 64;
constexpr int Kc  = 4;
constexpr int NC  = 16;
constexpr int M   = Bb * Ll;   // 1600 tokens
constexpr int NCH = 4;         // scan L-chunks
constexpr int CL  = Ll / NCH;  // 25

typedef __attribute__((ext_vector_type(8))) short short8;
typedef __attribute__((ext_vector_type(4))) float floatx4;

__device__ __forceinline__ float bf2f(unsigned short u) {
    union { uint32_t b; float f; } x; x.b = ((uint32_t)u) << 16; return x.f;
}
__device__ __forceinline__ unsigned short f2bf(float f) {
    union { float f; uint32_t b; } x; x.f = f;
    uint32_t r = x.b + 0x7FFF + ((x.b >> 16) & 1);   // RNE
    return (unsigned short)(r >> 16);
}
__device__ __forceinline__ float fast_silu(float x) {
    return x / (1.f + __expf(-x));
}

// ---------------------------------------------------------------------------
// Deep-pipelined bf16 MFMA GEMM (big GEMMs 1/2/7): BM=256, BN=128, BK=64;
// 512 thr = 8 waves (4m x 2n), wave tile 64x64. 3-buffer LDS ring, 2-deep
// counted-vmcnt prefetch. NEW (R10): LDS-staged coalesced epilogue —
// the former per-element 2B global stores (64/thread) were the fixed
// ~64us cost (duration invariant to K-depth). Now: scatter acc -> LDS
// [256][136] bf16 (pad kills 4-row bank aliasing), barrier, then short8
// read + dwordx4 global store, fully coalesced (8 stores/thread).
// ---------------------------------------------------------------------------
template<bool SPLIT, bool BIAS, bool W16>
__global__ __launch_bounds__(512) void gemm_deep(
    const unsigned short* __restrict__ A, int lda,    // [Md x lda]
    const unsigned short* __restrict__ Bt, int ldb,   // [Nd x ldb]
    const float* __restrict__ bias,                   // [Nd]
    unsigned short* __restrict__ C16,                 // final bf16 out
    unsigned short* __restrict__ Cpart,               // bf16 partials
    int Md, int Nd, int Kslab)
{
    __shared__ short As[3 * 8 * 256 * 8];   // 96 KB
    __shared__ short Bs[3 * 8 * 128 * 8];   // 48 KB

    // XCD-aware block remap
    const int nx = gridDim.x, ny = gridDim.y, nz = gridDim.z;
    const int nb = nx * ny * nz;
    int id = blockIdx.x + nx * (blockIdx.y + ny * blockIdx.z);
    int bx, by, bz;
    if ((nb & 7) == 0) {
        int swz = (id & 7) * (nb >> 3) + (id >> 3);
        bx = swz % nx;
        int rem = swz / nx;
        by = rem % ny;
        bz = rem / ny;
    } else {
        bx = blockIdx.x; by = blockIdx.y; bz = blockIdx.z;
    }

    const int tid  = threadIdx.x;
    const int lane = tid & 63;
    const int wid  = tid >> 6;      // 0..7
    const int wr   = wid >> 1;      // 0..3 (m)
    const int wc   = wid & 1;       // 0..1 (n)
    const int l15  = lane & 15;
    const int kg   = lane >> 4;
    const int m0   = bx * 256;
    const int n0   = by * 128;
    const int kbeg = SPLIT ? bz * Kslab : 0;

    floatx4 acc[4][4];
    #pragma unroll
    for (int m = 0; m < 4; m++)
        #pragma unroll
        for (int n = 0; n < 4; n++)
            acc[m][n] = (floatx4){0.f, 0.f, 0.f, 0.f};

    auto stage = [&](int buf, int k0) {
        #pragma unroll
        for (int j = 0; j < 4; j++) {
            int c = j * 512 + tid;
            int g = c >> 8, r = c & 255;
            int grow = m0 + r; grow = grow < Md ? grow : Md - 1;
            const __attribute__((address_space(1))) short* src =
                (const __attribute__((address_space(1))) short*)(A + (size_t)grow * lda + k0 + g * 8);
            __builtin_amdgcn_global_load_lds(
                (const __attribute__((address_space(1))) void*)src,
                (__attribute__((address_space(3))) void*)&As[(buf * 2048 + c) * 8], 16, 0, 0);
        }
        #pragma unroll
        for (int j = 0; j < 2; j++) {
            int c = j * 512 + tid;
            int g = c >> 7, r = c & 127;
            int brow = n0 + r; brow = brow < Nd ? brow : Nd - 1;
            const __attribute__((address_space(1))) short* src =
                (const __attribute__((address_space(1))) short*)(Bt + (size_t)brow * ldb + k0 + g * 8);
            __builtin_amdgcn_global_load_lds(
                (const __attribute__((address_space(1))) void*)src,
                (__attribute__((address_space(3))) void*)&Bs[(buf * 1024 + c) * 8], 16, 0, 0);
        }
    };

    const int nt = Kslab >> 6;
    stage(0, kbeg);
    stage(1, kbeg + 64);

    for (int t = 0; t < nt; t++) {
        const int cur = t % 3;
        if (t + 2 < nt) {
            stage((t + 2) % 3, kbeg + (t + 2) * 64);
            asm volatile("s_waitcnt vmcnt(12)" ::: "memory");  // tile t landed
        } else if (t + 1 < nt) {
            asm volatile("s_waitcnt vmcnt(6)" ::: "memory");
        } else {
            asm volatile("s_waitcnt vmcnt(0)" ::: "memory");
        }
        __builtin_amdgcn_s_barrier();
        __builtin_amdgcn_sched_barrier(0);

        short8 a[2][4], bfr[2][4];
        #pragma unroll
        for (int kk = 0; kk < 2; kk++) {
            #pragma unroll
            for (int m = 0; m < 4; m++)
                a[kk][m] = *(const short8*)&As[(cur * 2048 + (kk * 4 + kg) * 256 + wr * 64 + m * 16 + l15) * 8];
            #pragma unroll
            for (int n = 0; n < 4; n++)
                bfr[kk][n] = *(const short8*)&Bs[(cur * 1024 + (kk * 4 + kg) * 128 + wc * 64 + n * 16 + l15) * 8];
        }
        __builtin_amdgcn_s_setprio(1);
        #pragma unroll
        for (int kk = 0; kk < 2; kk++)
            #pragma unroll
            for (int m = 0; m < 4; m++)
                #pragma unroll
                for (int n = 0; n < 4; n++)
                    acc[m][n] = __builtin_amdgcn_mfma_f32_16x16x32_bf16(a[kk][m], bfr[kk][n], acc[m][n], 0, 0, 0);
        __builtin_amdgcn_s_setprio(0);
        __builtin_amdgcn_sched_barrier(0);
        __builtin_amdgcn_s_barrier();   // also protects As before C-staging
    }

    // ---- LDS-staged coalesced epilogue ----
    unsigned short* Cs = (unsigned short*)As;   // [256][136] bf16 = 69.6 KB
    #pragma unroll
    for (int n = 0; n < 4; n++) {
        int col = wc * 64 + n * 16 + l15;
        float bv = BIAS ? bias[n0 + col] : 0.f;
        #pragma unroll
        for (int m = 0; m < 4; m++) {
            #pragma unroll
            for (int q = 0; q < 4; q++) {
                int row = wr * 64 + m * 16 + kg * 4 + q;
                Cs[row * 136 + col] = f2bf(acc[m][n][q] + bv);
            }
        }
    }
    __syncthreads();
    #pragma unroll
    for (int j = 0; j < 8; j++) {
        int c = j * 512 + tid;          // 16B cell; 16 cells/row
        int row = c >> 4, cc = c & 15;
        int grow = m0 + row;
        if (grow >= Md) continue;
        short8 v = *(const short8*)&Cs[row * 136 + cc * 8];
        if (SPLIT)
            *(short8*)&Cpart[(size_t)bz * Md * Nd + (size_t)grow * Nd + n0 + cc * 8] = v;
        else if (W16)
            *(short8*)&C16[(size_t)grow * Nd + n0 + cc * 8] = v;
    }
}

// ---------------------------------------------------------------------------
// 128x128 dbuf kernel — small GEMMs (proj, delta). Scalar f32 epilogue
// (quarter-coalesced 64B chunks; left unchanged this round for attribution).
// ---------------------------------------------------------------------------
template<bool SPLIT, bool PARTBF, bool BIAS, int ACT, bool W32, bool W16>
__global__ __launch_bounds__(256) void gemm_mfma(
    const unsigned short* __restrict__ A, int lda,
    const unsigned short* __restrict__ Bt, int ldb,
    const float* __restrict__ bias,
    float* __restrict__ C32,
    unsigned short* __restrict__ C16,
    void* __restrict__ Cpart,
    int Md, int Nd, int Kslab)
{
    __shared__ short As[2][8 * 128 * 8];
    __shared__ short Bs[2][8 * 128 * 8];

    const int nx = gridDim.x, ny = gridDim.y, nz = gridDim.z;
    const int nb = nx * ny * nz;
    int id = blockIdx.x + nx * (blockIdx.y + ny * blockIdx.z);
    int bx, by, bz;
    if ((nb & 7) == 0) {
        int swz = (id & 7) * (nb >> 3) + (id >> 3);
        bx = swz % nx;
        int rem = swz / nx;
        by = rem % ny;
        bz = rem / ny;
    } else {
        bx = blockIdx.x; by = blockIdx.y; bz = blockIdx.z;
    }

    const int tid  = threadIdx.x;
    const int lane = tid & 63;
    const int wid  = tid >> 6;
    const int wr   = wid >> 1;
    const int wc   = wid & 1;
    const int l15  = lane & 15;
    const int kg   = lane >> 4;
    const int m0   = bx * 128;
    const int n0   = by * 128;
    const int kbeg = SPLIT ? bz * Kslab : 0;

    floatx4 acc[4][4];
    #pragma unroll
    for (int m = 0; m < 4; m++)
        #pragma unroll
        for (int n = 0; n < 4; n++)
            acc[m][n] = (floatx4){0.f, 0.f, 0.f, 0.f};

    auto stage = [&](int buf, int k0) {
        #pragma unroll
        for (int j = 0; j < 4; j++) {
            int c = j * 256 + tid;
            int g = c >> 7, r = c & 127;
            int grow = m0 + r; grow = grow < Md ? grow : Md - 1;
            const __attribute__((address_space(1))) short* src =
                (const __attribute__((address_space(1))) short*)(A + (size_t)grow * lda + k0 + g * 8);
            __builtin_amdgcn_global_load_lds(
                (const __attribute__((address_space(1))) void*)src,
                (__attribute__((address_space(3))) void*)&As[buf][c * 8], 16, 0, 0);
        }
        #pragma unroll
        for (int j = 0; j < 4; j++) {
            int c = j * 256 + tid;
            int g = c >> 7, r = c & 127;
            int brow = n0 + r; brow = brow < Nd ? brow : Nd - 1;
            const __attribute__((address_space(1))) short* src =
                (const __attribute__((address_space(1))) short*)(Bt + (size_t)brow * ldb + k0 + g * 8);
            __builtin_amdgcn_global_load_lds(
                (const __attribute__((address_space(1))) void*)src,
                (__attribute__((address_space(3))) void*)&Bs[buf][c * 8], 16, 0, 0);
        }
    };

    stage(0, kbeg);
    asm volatile("s_waitcnt vmcnt(0)" ::: "memory");
    __builtin_amdgcn_s_barrier();
    __builtin_amdgcn_sched_barrier(0);

    const int nt = Kslab >> 6;
    for (int t = 0; t < nt; t++) {
        const int cur = t & 1;
        if (t + 1 < nt) {
            stage(cur ^ 1, kbeg + (t + 1) * 64);
            asm volatile("s_waitcnt vmcnt(8)" ::: "memory");
        } else {
            asm volatile("s_waitcnt vmcnt(0)" ::: "memory");
        }
        __builtin_amdgcn_s_barrier();
        __builtin_amdgcn_sched_barrier(0);

        short8 a[2][4], bfr[2][4];
        #pragma unroll
        for (int kk = 0; kk < 2; kk++) {
            #pragma unroll
            for (int m = 0; m < 4; m++)
                a[kk][m] = *(const short8*)&As[cur][((kk * 4 + kg) * 128 + wr * 64 + m * 16 + l15) * 8];
            #pragma unroll
            for (int n = 0; n < 4; n++)
                bfr[kk][n] = *(const short8*)&Bs[cur][((kk * 4 + kg) * 128 + wc * 64 + n * 16 + l15) * 8];
        }
        #pragma unroll
        for (int kk = 0; kk < 2; kk++)
            #pragma unroll
            for (int m = 0; m < 4; m++)
                #pragma unroll
                for (int n = 0; n < 4; n++)
                    acc[m][n] = __builtin_amdgcn_mfma_f32_16x16x32_bf16(a[kk][m], bfr[kk][n], acc[m][n], 0, 0, 0);

        __builtin_amdgcn_sched_barrier(0);
        __builtin_amdgcn_s_barrier();
    }

    if (SPLIT) {
        #pragma unroll
        for (int n = 0; n < 4; n++) {
            int col = n0 + wc * 64 + n * 16 + l15;
            if (col >= Nd) continue;
            #pragma unroll
            for (int m = 0; m < 4; m++)
                #pragma unroll
                for (int q = 0; q < 4; q++) {
                    int row = m0 + wr * 64 + m * 16 + kg * 4 + q;
                    if (row >= Md) continue;
                    size_t ix = (size_t)bz * Md * Nd + (size_t)row * Nd + col;
                    if (PARTBF) ((unsigned short*)Cpart)[ix] = f2bf(acc[m][n][q]);
                    else        ((float*)Cpart)[ix] = acc[m][n][q];
                }
        }
    } else {
        #pragma unroll
        for (int n = 0; n < 4; n++) {
            int col = n0 + wc * 64 + n * 16 + l15;
            if (col >= Nd) continue;
            float bv = BIAS ? bias[col] : 0.f;
            #pragma unroll
            for (int m = 0; m < 4; m++)
                #pragma unroll
                for (int q = 0; q < 4; q++) {
                    int row = m0 + wr * 64 + m * 16 + kg * 4 + q;
                    if (row >= Md) continue;
                    float v = acc[m][n][q] + bv;
                    if (ACT == 1) v = fmaxf(v, 0.f) + log1pf(expf(-fabsf(v)));  // softplus
                    if (W32) C32[(size_t)row * Nd + col] = v;
                    if (W16) C16[(size_t)row * Nd + col] = f2bf(v);
                }
        }
    }
}

// ---------------------------------------------------------------------------
// Sum S fp32 split-K partials + bias/act -> fp32/bf16. total % 1024 == 0.
// ---------------------------------------------------------------------------
template<int S, bool BIAS, int ACT, bool W32, bool W16>
__global__ __launch_bounds__(256) void reduce_split(
    const float* __restrict__ P, const float* __restrict__ bias,
    float* __restrict__ C32, unsigned short* __restrict__ C16,
    int total, int nmask)
{
    int i = (blockIdx.x * 256 + threadIdx.x) * 4;
    float4 v = *(const float4*)&P[i];
    #pragma unroll
    for (int s = 1; s < S; s++) {
        float4 p = *(const float4*)&P[(size_t)s * total + i];
        v.x += p.x; v.y += p.y; v.z += p.z; v.w += p.w;
    }
    float r[4] = {v.x, v.y, v.z, v.w};
    #pragma unroll
    for (int j = 0; j < 4; j++) {
        float t = r[j];
        if (BIAS) t += bias[(i + j) & nmask];
        if (ACT == 1) t = fmaxf(t, 0.f) + log1pf(expf(-fabsf(t)));
        if (W32) C32[i + j] = t;
        if (W16) C16[i + j] = f2bf(t);
    }
}

// ---------------------------------------------------------------------------
// Sum S bf16 split-K partials + bias -> bf16. total % 2048 == 0.
// ---------------------------------------------------------------------------
template<int S, bool BIAS>
__global__ __launch_bounds__(256) void reduce_split_bf(
    const unsigned short* __restrict__ P, const float* __restrict__ bias,
    unsigned short* __restrict__ C16, int total, int nmask)
{
    int i = (blockIdx.x * 256 + threadIdx.x) * 8;
    float r[8] = {};
    #pragma unroll
    for (int s = 0; s < S; s++) {
        short8 p = *(const short8*)&P[(size_t)s * total + i];
        #pragma unroll
        for (int j = 0; j < 8; j++) r[j] += bf2f((unsigned short)p[j]);
    }
    short8 o;
    #pragma unroll
    for (int j = 0; j < 8; j++) {
        float t = r[j];
        if (BIAS) t += bias[(i + j) & nmask];
        o[j] = (short)f2bf(t);
    }
    *(short8*)&C16[i] = o;
}

// ---------------------------------------------------------------------------
// fp32 -> bf16 flat convert (n % 1024 == 0)
// ---------------------------------------------------------------------------
__global__ __launch_bounds__(256) void f32_to_bf16_kernel(
    const float* __restrict__ in, unsigned short* __restrict__ out, int n4)
{
    int i = (blockIdx.x * 256 + threadIdx.x) * 4;
    float4 v = *(const float4*)&in[i];
    out[i + 0] = f2bf(v.x);
    out[i + 1] = f2bf(v.y);
    out[i + 2] = f2bf(v.z);
    out[i + 3] = f2bf(v.w);
}

// ---------------------------------------------------------------------------
// Transpose fp32 [K][N] -> bf16 [N][K]  (K,N multiples of 32)
// ---------------------------------------------------------------------------
__global__ __launch_bounds__(256) void transpose_f32_bf16(
    const float* __restrict__ in, unsigned short* __restrict__ out, int K, int N)
{
    __shared__ float t[32][33];
    int k0 = blockIdx.x * 32, n0 = blockIdx.y * 32;
    int tx = threadIdx.x & 31, ty = threadIdx.x >> 5;   // ty 0..7
    #pragma unroll
    for (int i = 0; i < 4; i++)
        t[ty + i * 8][tx] = in[(size_t)(k0 + ty + i * 8) * N + n0 + tx];
    __syncthreads();
    #pragma unroll
    for (int i = 0; i < 4; i++)
        out[(size_t)(n0 + ty + i * 8) * K + k0 + tx] = f2bf(t[tx][ty + i * 8]);
}

// ---------------------------------------------------------------------------
// Causal depthwise conv (K=4) + bias + SiLU; xz is bf16 with row stride 2*DI.
// ---------------------------------------------------------------------------
__global__ __launch_bounds__(256) void conv_silu_kernel(
    const unsigned short* __restrict__ xz, const float* __restrict__ conv_w,
    const float* __restrict__ conv_b, float* __restrict__ xc,
    unsigned short* __restrict__ xc_bf)
{
    int idx = blockIdx.x * 256 + threadIdx.x;
    if (idx >= Bb * Ll * DI) return;
    int d  = idx & (DI - 1);
    int bl = idx >> 11;
    int l  = bl % Ll;

    float acc = conv_b[d];
    #pragma unroll
    for (int k = 0; k < Kc; k++) {
        int ls = l + k - (Kc - 1);
        if (ls >= 0)
            acc = fmaf(conv_w[d * Kc + k], bf2f(xz[(size_t)(bl + ls - l) * (2 * DI) + d]), acc);
    }
    float s = fast_silu(acc);
    xc[idx] = s;
    xc_bf[idx] = f2bf(s);
}

// ---------------------------------------------------------------------------
// Chunked selective scan, 2-pass. See R8 comments.
// ---------------------------------------------------------------------------
__global__ __launch_bounds__(256) void scan_part1(
    const float* __restrict__ delta, const float* __restrict__ xc,
    const float* __restrict__ proj,  const float* __restrict__ A_log,
    float* __restrict__ Pbuf, float* __restrict__ Sbuf)
{
    const int t    = threadIdx.x;
    const int nq   = t & 3;
    const int dloc = t >> 2;
    const int d    = blockIdx.x * 64 + dloc;
    const int b    = blockIdx.y;
    const int c    = blockIdx.z;

    float4 Alq = *(const float4*)&A_log[(size_t)d * Nst + nq * 4];
    float Ar0 = -expf(Alq.x), Ar1 = -expf(Alq.y), Ar2 = -expf(Alq.z), Ar3 = -expf(Alq.w);

    float h0 = 0.f, h1 = 0.f, h2 = 0.f, h3 = 0.f;
    float sdl = 0.f;

    for (int l = c * CL; l < (c + 1) * CL; l++) {
        size_t bl = (size_t)b * Ll + l;
        float dl  = delta[bl * DI + d];
        float xcv = xc[bl * DI + d];
        float dx  = dl * xcv;
        float4 Bv = *(const float4*)&proj[bl * (DTR + 2 * Nst) + DTR + nq * 4];

        h0 = fmaf(__expf(dl * Ar0), h0, dx * Bv.x);
        h1 = fmaf(__expf(dl * Ar1), h1, dx * Bv.y);
        h2 = fmaf(__expf(dl * Ar2), h2, dx * Bv.z);
        h3 = fmaf(__expf(dl * Ar3), h3, dx * Bv.w);
        sdl += dl;
    }

    size_t o = (((size_t)c * Bb + b) * DI + d) * Nst + nq * 4;
    *(float4*)&Pbuf[o] = (float4){__expf(sdl * Ar0), __expf(sdl * Ar1),
                                  __expf(sdl * Ar2), __expf(sdl * Ar3)};
    *(float4*)&Sbuf[o] = (float4){h0, h1, h2, h3};
}

__global__ __launch_bounds__(256) void scan_part2(
    const float* __restrict__ delta, const float* __restrict__ xc,
    const unsigned short* __restrict__ xz, const float* __restrict__ proj,
    const float* __restrict__ A_log, const float* __restrict__ Dv,
    const float* __restrict__ Pbuf, const float* __restrict__ Sbuf,
    unsigned short* __restrict__ y)
{
    const int t    = threadIdx.x;
    const int nq   = t & 3;
    const int dloc = t >> 2;
    const int d    = blockIdx.x * 64 + dloc;
    const int b    = blockIdx.y;
    const int c    = blockIdx.z;

    float4 Alq = *(const float4*)&A_log[(size_t)d * Nst + nq * 4];
    float Ar0 = -expf(Alq.x), Ar1 = -expf(Alq.y), Ar2 = -expf(Alq.z), Ar3 = -expf(Alq.w);
    const float Dd = Dv[d];

    float h0 = 0.f, h1 = 0.f, h2 = 0.f, h3 = 0.f;
    for (int cc = 0; cc < c; cc++) {
        size_t o = (((size_t)cc * Bb + b) * DI + d) * Nst + nq * 4;
        float4 Pv = *(const float4*)&Pbuf[o];
        float4 Sv = *(const float4*)&Sbuf[o];
        h0 = fmaf(Pv.x, h0, Sv.x);
        h1 = fmaf(Pv.y, h1, Sv.y);
        h2 = fmaf(Pv.z, h2, Sv.z);
        h3 = fmaf(Pv.w, h3, Sv.w);
    }

    for (int l = c * CL; l < (c + 1) * CL; l++) {
        size_t bl = (size_t)b * Ll + l;
        float dl  = delta[bl * DI + d];
        float xcv = xc[bl * DI + d];
        float zv  = bf2f(xz[bl * (2 * DI) + DI + d]);
        float dx  = dl * xcv;
        const float* p = proj + bl * (DTR + 2 * Nst);
        float4 Bv = *(const float4*)&p[DTR + nq * 4];
        float4 Cv = *(const float4*)&p[DTR + Nst + nq * 4];

        h0 = fmaf(__expf(dl * Ar0), h0, dx * Bv.x);
        h1 = fmaf(__expf(dl * Ar1), h1, dx * Bv.y);
        h2 = fmaf(__expf(dl * Ar2), h2, dx * Bv.z);
        h3 = fmaf(__expf(dl * Ar3), h3, dx * Bv.w);

        float yac = h0 * Cv.x + h1 * Cv.y + h2 * Cv.z + h3 * Cv.w;
        yac += __shfl_xor(yac, 1);
        yac += __shfl_xor(yac, 2);

        if (nq == 0) {
            float yv = yac + Dd * xcv;
            yv *= fast_silu(zv);
            y[bl * DI + d] = f2bf(yv);
        }
    }
}

// ---------------------------------------------------------------------------
// logits[M,16] = out_bf[M,1024] @ W_out[1024,16] + b_out
// ---------------------------------------------------------------------------
__global__ __launch_bounds__(256) void gemm_n16(
    const unsigned short* __restrict__ A, const float* __restrict__ W,
    const float* __restrict__ bias, float* __restrict__ C, int Kd)
{
    int m  = blockIdx.x;
    int t  = threadIdx.x;
    int c  = t & 15;
    int kg = t >> 4;
    const unsigned short* a = A + (size_t)m * Kd;

    float acc = 0.f;
    for (int k = kg; k < Kd; k += 16)
        acc = fmaf(bf2f(a[k]), W[k * NC + c], acc);

    __shared__ float red[256];
    red[t] = acc;
    __syncthreads();
    #pragma unroll
    for (int s = 128; s >= 16; s >>= 1) {
        if (t < s) red[t] += red[t + s];
        __syncthreads();
    }
    if (t < 16) C[(size_t)m * NC + t] = red[t] + bias[t];
}

// ---------------------------------------------------------------------------
extern "C" void kernel_launch(void* const* d_in, const int* in_sizes, int n_in,
                              void* d_out, int out_size, void* d_ws, size_t ws_size,
                              hipStream_t stream) {
    const float* x         = (const float*)d_in[0];
    const float* W_in      = (const float*)d_in[1];
    const float* b_in      = (const float*)d_in[2];
    const float* in_proj_w = (const float*)d_in[3];
    const float* conv_w    = (const float*)d_in[4];
    const float* conv_b    = (const float*)d_in[5];
    const float* x_proj_w  = (const float*)d_in[6];
    const float* dt_proj_w = (const float*)d_in[7];
    const float* dt_proj_b = (const float*)d_in[8];
    const float* A_log     = (const float*)d_in[9];
    const float* Dv        = (const float*)d_in[10];
    const float* out_proj  = (const float*)d_in[11];
    const float* W_out     = (const float*)d_in[12];
    const float* b_out     = (const float*)d_in[13];
    float* logits = (float*)d_out;

    char* base = (char*)d_ws;
    size_t off = 0;
    auto alloc = [&](size_t bytes) {
        char* p = base + off;
        off += (bytes + 255) & ~(size_t)255;
        return p;
    };
    unsigned short* x_bf    = (unsigned short*)alloc((size_t)M * DIN * 2);
    unsigned short* Wt_in   = (unsigned short*)alloc((size_t)Hh * DIN * 2);
    unsigned short* Wt_ip   = (unsigned short*)alloc((size_t)(2 * DI) * Hh * 2);
    unsigned short* Wt_op   = (unsigned short*)alloc((size_t)Hh * DI * 2);
    unsigned short* xpw_t   = (unsigned short*)alloc((size_t)96 * DI * 2);
    unsigned short* dtw_t   = (unsigned short*)alloc((size_t)DI * DTR * 2);
    unsigned short* h_bf    = (unsigned short*)alloc((size_t)M * Hh * 2);
    unsigned short* xz_bf   = (unsigned short*)alloc((size_t)M * 2 * DI * 2);
    float*          xc      = (float*)alloc((size_t)M * DI * 4);       // | partials alias
    float*          delta   = (float*)alloc((size_t)M * DI * 4);       // | region
    unsigned short* xc_bf   = (unsigned short*)alloc((size_t)M * DI * 2);
    float*          proj_f  = (float*)alloc((size_t)M * 96 * 4);
    unsigned short* proj_bf = (unsigned short*)alloc((size_t)M * 96 * 2);
    unsigned short* y_bf    = (unsigned short*)alloc((size_t)M * DI * 2);
    unsigned short* out_bf  = (unsigned short*)alloc((size_t)M * Hh * 2);

    unsigned short* P14 = (unsigned short*)xc;   // bf16 [4][1600][1024] = 13.1MB
    float*          P8  = delta;                 // fp32 [8][1600][96]  = 4.9MB
    float*          Pbuf = (float*)x_bf;         // scan chunk buffers (x_bf dead)
    float*          Sbuf = Pbuf + (size_t)(NCH - 1) * Bb * DI * Nst;

    dim3 blk(256), blk5(512);

    // 0) conversions / weight transposes
    f32_to_bf16_kernel<<<dim3((M * DIN) / 1024), blk, 0, stream>>>(x, x_bf, M * DIN);
    transpose_f32_bf16<<<dim3(DIN / 32, Hh / 32), blk, 0, stream>>>(W_in, Wt_in, DIN, Hh);
    transpose_f32_bf16<<<dim3(Hh / 32, (2 * DI) / 32), blk, 0, stream>>>(in_proj_w, Wt_ip, Hh, 2 * DI);
    transpose_f32_bf16<<<dim3(DI / 32, Hh / 32), blk, 0, stream>>>(out_proj, Wt_op, DI, Hh);
    transpose_f32_bf16<<<dim3(DI / 32, 96 / 32), blk, 0, stream>>>(x_proj_w, xpw_t, DI, 96);
    transpose_f32_bf16<<<dim3(DTR / 32, DI / 32), blk, 0, stream>>>(dt_proj_w, dtw_t, DTR, DI);

    // 1) h = x @ W_in + b_in   [1600,6144]@[6144,1024], split-K 4 -> 224 blocks
    gemm_deep<true, false, false><<<dim3(7, Hh / 128, 4), blk5, 0, stream>>>(
        x_bf, DIN, Wt_in, DIN, nullptr, nullptr, P14, M, Hh, DIN / 4);
    reduce_split_bf<4, true><<<dim3((M * Hh) / 2048), blk, 0, stream>>>(
        P14, b_in, h_bf, M * Hh, Hh - 1);

    // 2) xz = h @ in_proj_w    [1600,1024]@[1024,4096], 224 blocks, no split
    gemm_deep<false, false, true><<<dim3(7, (2 * DI) / 128, 1), blk5, 0, stream>>>(
        h_bf, Hh, Wt_ip, Hh, nullptr, xz_bf, nullptr, M, 2 * DI, Hh);

    // 3) xc = silu(conv(xm) + conv_b)  -> fp32 + bf16
    conv_silu_kernel<<<dim3((Bb * Ll * DI) / 256), blk, 0, stream>>>(
        xz_bf, conv_w, conv_b, xc, xc_bf);

    // 4) proj = xc @ x_proj_w  [1600,2048]@[2048,96], split-K 8 -> 104 blocks
    gemm_mfma<true, false, false, 0, false, false><<<dim3(13, 1, 8), blk, 0, stream>>>(
        xc_bf, DI, xpw_t, DI, nullptr, nullptr, nullptr, P8, M, 96, DI / 8);
    reduce_split<8, false, 0, true, true><<<dim3((M * 96) / 1024), blk, 0, stream>>>(
        P8, nullptr, proj_f, proj_bf, M * 96, 0);

    // 5) delta = softplus(proj[:,:64] @ dt_proj_w + dt_proj_b)  [1600,64]@[64,2048]
    gemm_mfma<false, false, true, 1, true, false><<<dim3(13, DI / 128, 1), blk, 0, stream>>>(
        proj_bf, 96, dtw_t, DTR, dt_proj_b, delta, nullptr, nullptr, M, DI, DTR);

    // 6) chunked selective scan: pass1 (chunks 0..2) then pass2 (all 4)
    scan_part1<<<dim3(DI / 64, Bb, NCH - 1), blk, 0, stream>>>(
        delta, xc, proj_f, A_log, Pbuf, Sbuf);
    scan_part2<<<dim3(DI / 64, Bb, NCH), blk, 0, stream>>>(
        delta, xc, xz_bf, proj_f, A_log, Dv, Pbuf, Sbuf, y_bf);

    // 7) out = y @ out_proj_w  [1600,2048]@[2048,1024], split-K 4 -> 224 blocks
    gemm_deep<true, false, false><<<dim3(7, Hh / 128, 4), blk5, 0, stream>>>(
        y_bf, DI, Wt_op, DI, nullptr, nullptr, P14, M, Hh, DI / 4);
    reduce_split_bf<4, false><<<dim3((M * Hh) / 2048), blk, 0, stream>>>(
        P14, nullptr, out_bf, M * Hh, 0);

    // 8) logits = out @ W_out + b_out  [1600,1024]@[1024,16]
    gemm_n16<<<dim3(M), blk, 0, stream>>>(out_bf, W_out, b_out, logits, Hh);
}

// Round 11
// 246.308 us; speedup vs baseline: 8.0152x; 1.1959x over previous
//
#include <hip/hip_runtime.h>
#include <hip/hip_bf16.h>
#include <stdint.h>

// Problem constants
constexpr int Bb  = 16;
constexpr int Ll  = 100;
constexpr int DIN = 6144;
constexpr int Hh  = 1024;
constexpr int DI  = 2048;
constexpr int Nst = 16;
constexpr int DTR = 64;
constexpr int Kc  = 4;
constexpr int NC  = 16;
constexpr int M   = Bb * Ll;   // 1600 tokens
constexpr int NCH = 4;         // scan L-chunks
constexpr int CL  = Ll / NCH;  // 25

typedef __attribute__((ext_vector_type(8))) short short8;
typedef __attribute__((ext_vector_type(4))) float floatx4;

__device__ __forceinline__ float bf2f(unsigned short u) {
    union { uint32_t b; float f; } x; x.b = ((uint32_t)u) << 16; return x.f;
}
__device__ __forceinline__ unsigned short f2bf(float f) {
    union { float f; uint32_t b; } x; x.f = f;
    uint32_t r = x.b + 0x7FFF + ((x.b >> 16) & 1);   // RNE
    return (unsigned short)(r >> 16);
}
__device__ __forceinline__ float fast_silu(float x) {
    return x / (1.f + __expf(-x));
}

// ---------------------------------------------------------------------------
// STAGING LAYOUT (R11): row-major LDS tile + XOR swizzle, both-sides.
// Old (g*ROWS+r) layout made every staging wave-instr touch 64 DIFFERENT
// rows (lda*2B apart) -> 64 line-requests/instr, ~3072 TA-cycles per K-step
// -> the 6250-cyc/step wall (duration invariant to pipeline depth).
// New: LDS cell c -> row=c>>3, g_lds=c&7; global src g_glob = g_lds^(row&7).
// A wave's 8 lanes per row read that row's full 128B (permuted 16B chunks)
// -> 16 lines/wave-instr (4x fewer requests). LDS dest stays lane-linear
// (gload_lds requirement); ds_read XORs the same way: g^(l15&7) ->
// 32 banks, 2-way aliasing = free (m136).
// ---------------------------------------------------------------------------

// Deep-pipelined bf16 MFMA GEMM (big GEMMs 1/2/7): BM=256, BN=128, BK=64;
// 512 thr = 8 waves (4m x 2n), wave tile 64x64. 3-buffer LDS ring, 2-deep
// counted-vmcnt prefetch, LDS-staged coalesced epilogue.
template<bool SPLIT, bool BIAS, bool W16>
__global__ __launch_bounds__(512) void gemm_deep(
    const unsigned short* __restrict__ A, int lda,    // [Md x lda]
    const unsigned short* __restrict__ Bt, int ldb,   // [Nd x ldb]
    const float* __restrict__ bias,                   // [Nd]
    unsigned short* __restrict__ C16,                 // final bf16 out
    unsigned short* __restrict__ Cpart,               // bf16 partials
    int Md, int Nd, int Kslab)
{
    __shared__ short As[3 * 256 * 64];   // 96 KB  (3 bufs x 256 rows x 64 bf16)
    __shared__ short Bs[3 * 128 * 64];   // 48 KB

    // XCD-aware block remap
    const int nx = gridDim.x, ny = gridDim.y, nz = gridDim.z;
    const int nb = nx * ny * nz;
    int id = blockIdx.x + nx * (blockIdx.y + ny * blockIdx.z);
    int bx, by, bz;
    if ((nb & 7) == 0) {
        int swz = (id & 7) * (nb >> 3) + (id >> 3);
        bx = swz % nx;
        int rem = swz / nx;
        by = rem % ny;
        bz = rem / ny;
    } else {
        bx = blockIdx.x; by = blockIdx.y; bz = blockIdx.z;
    }

    const int tid  = threadIdx.x;
    const int lane = tid & 63;
    const int wid  = tid >> 6;      // 0..7
    const int wr   = wid >> 1;      // 0..3 (m)
    const int wc   = wid & 1;       // 0..1 (n)
    const int l15  = lane & 15;
    const int kg   = lane >> 4;
    const int gsw  = l15 & 7;       // ds_read swizzle term
    const int m0   = bx * 256;
    const int n0   = by * 128;
    const int kbeg = SPLIT ? bz * Kslab : 0;

    floatx4 acc[4][4];
    #pragma unroll
    for (int m = 0; m < 4; m++)
        #pragma unroll
        for (int n = 0; n < 4; n++)
            acc[m][n] = (floatx4){0.f, 0.f, 0.f, 0.f};

    auto stage = [&](int buf, int k0) {
        // A: 2048 cells (256 rows x 8 g-chunks of 16B)
        #pragma unroll
        for (int j = 0; j < 4; j++) {
            int c = j * 512 + tid;
            int row = c >> 3, gl = c & 7;
            int gg = gl ^ (row & 7);                 // inverse-swizzled source
            int grow = m0 + row; grow = grow < Md ? grow : Md - 1;
            const __attribute__((address_space(1))) short* src =
                (const __attribute__((address_space(1))) short*)(A + (size_t)grow * lda + k0 + gg * 8);
            __builtin_amdgcn_global_load_lds(
                (const __attribute__((address_space(1))) void*)src,
                (__attribute__((address_space(3))) void*)&As[(buf * 2048 + c) * 8], 16, 0, 0);
        }
        // B: 1024 cells (128 rows x 8 g-chunks)
        #pragma unroll
        for (int j = 0; j < 2; j++) {
            int c = j * 512 + tid;
            int row = c >> 3, gl = c & 7;
            int gg = gl ^ (row & 7);
            int brow = n0 + row; brow = brow < Nd ? brow : Nd - 1;
            const __attribute__((address_space(1))) short* src =
                (const __attribute__((address_space(1))) short*)(Bt + (size_t)brow * ldb + k0 + gg * 8);
            __builtin_amdgcn_global_load_lds(
                (const __attribute__((address_space(1))) void*)src,
                (__attribute__((address_space(3))) void*)&Bs[(buf * 1024 + c) * 8], 16, 0, 0);
        }
    };

    const int nt = Kslab >> 6;
    stage(0, kbeg);
    stage(1, kbeg + 64);

    for (int t = 0; t < nt; t++) {
        const int cur = t % 3;
        if (t + 2 < nt) {
            stage((t + 2) % 3, kbeg + (t + 2) * 64);
            asm volatile("s_waitcnt vmcnt(12)" ::: "memory");  // tile t landed
        } else if (t + 1 < nt) {
            asm volatile("s_waitcnt vmcnt(6)" ::: "memory");
        } else {
            asm volatile("s_waitcnt vmcnt(0)" ::: "memory");
        }
        __builtin_amdgcn_s_barrier();
        __builtin_amdgcn_sched_barrier(0);

        short8 a[2][4], bfr[2][4];
        #pragma unroll
        for (int kk = 0; kk < 2; kk++) {
            #pragma unroll
            for (int m = 0; m < 4; m++) {
                int row = wr * 64 + m * 16 + l15;
                int gs  = (kk * 4 + kg) ^ gsw;
                a[kk][m] = *(const short8*)&As[(cur * 2048 + row * 8 + gs) * 8];
            }
            #pragma unroll
            for (int n = 0; n < 4; n++) {
                int row = wc * 64 + n * 16 + l15;
                int gs  = (kk * 4 + kg) ^ gsw;
                bfr[kk][n] = *(const short8*)&Bs[(cur * 1024 + row * 8 + gs) * 8];
            }
        }
        __builtin_amdgcn_s_setprio(1);
        #pragma unroll
        for (int kk = 0; kk < 2; kk++)
            #pragma unroll
            for (int m = 0; m < 4; m++)
                #pragma unroll
                for (int n = 0; n < 4; n++)
                    acc[m][n] = __builtin_amdgcn_mfma_f32_16x16x32_bf16(a[kk][m], bfr[kk][n], acc[m][n], 0, 0, 0);
        __builtin_amdgcn_s_setprio(0);
        __builtin_amdgcn_sched_barrier(0);
        __builtin_amdgcn_s_barrier();   // all waves done reading buf cur
    }

    // ---- LDS-staged coalesced epilogue ----
    unsigned short* Cs = (unsigned short*)As;   // [256][136] bf16 = 69.6 KB
    #pragma unroll
    for (int n = 0; n < 4; n++) {
        int col = wc * 64 + n * 16 + l15;
        float bv = BIAS ? bias[n0 + col] : 0.f;
        #pragma unroll
        for (int m = 0; m < 4; m++) {
            #pragma unroll
            for (int q = 0; q < 4; q++) {
                int row = wr * 64 + m * 16 + kg * 4 + q;
                Cs[row * 136 + col] = f2bf(acc[m][n][q] + bv);
            }
        }
    }
    __syncthreads();
    #pragma unroll
    for (int j = 0; j < 8; j++) {
        int c = j * 512 + tid;          // 16B cell; 16 cells/row
        int row = c >> 4, cc = c & 15;
        int grow = m0 + row;
        if (grow >= Md) continue;
        short8 v = *(const short8*)&Cs[row * 136 + cc * 8];
        if (SPLIT)
            *(short8*)&Cpart[(size_t)bz * Md * Nd + (size_t)grow * Nd + n0 + cc * 8] = v;
        else if (W16)
            *(short8*)&C16[(size_t)grow * Nd + n0 + cc * 8] = v;
    }
}

// ---------------------------------------------------------------------------
// 128x128 dbuf kernel — small GEMMs (proj, delta). Same swizzled staging.
// ---------------------------------------------------------------------------
template<bool SPLIT, bool PARTBF, bool BIAS, int ACT, bool W32, bool W16>
__global__ __launch_bounds__(256) void gemm_mfma(
    const unsigned short* __restrict__ A, int lda,
    const unsigned short* __restrict__ Bt, int ldb,
    const float* __restrict__ bias,
    float* __restrict__ C32,
    unsigned short* __restrict__ C16,
    void* __restrict__ Cpart,
    int Md, int Nd, int Kslab)
{
    __shared__ short As[2][128 * 64];
    __shared__ short Bs[2][128 * 64];

    const int nx = gridDim.x, ny = gridDim.y, nz = gridDim.z;
    const int nb = nx * ny * nz;
    int id = blockIdx.x + nx * (blockIdx.y + ny * blockIdx.z);
    int bx, by, bz;
    if ((nb & 7) == 0) {
        int swz = (id & 7) * (nb >> 3) + (id >> 3);
        bx = swz % nx;
        int rem = swz / nx;
        by = rem % ny;
        bz = rem / ny;
    } else {
        bx = blockIdx.x; by = blockIdx.y; bz = blockIdx.z;
    }

    const int tid  = threadIdx.x;
    const int lane = tid & 63;
    const int wid  = tid >> 6;
    const int wr   = wid >> 1;
    const int wc   = wid & 1;
    const int l15  = lane & 15;
    const int kg   = lane >> 4;
    const int gsw  = l15 & 7;
    const int m0   = bx * 128;
    const int n0   = by * 128;
    const int kbeg = SPLIT ? bz * Kslab : 0;

    floatx4 acc[4][4];
    #pragma unroll
    for (int m = 0; m < 4; m++)
        #pragma unroll
        for (int n = 0; n < 4; n++)
            acc[m][n] = (floatx4){0.f, 0.f, 0.f, 0.f};

    auto stage = [&](int buf, int k0) {
        #pragma unroll
        for (int j = 0; j < 4; j++) {
            int c = j * 256 + tid;
            int row = c >> 3, gl = c & 7;
            int gg = gl ^ (row & 7);
            int grow = m0 + row; grow = grow < Md ? grow : Md - 1;
            const __attribute__((address_space(1))) short* src =
                (const __attribute__((address_space(1))) short*)(A + (size_t)grow * lda + k0 + gg * 8);
            __builtin_amdgcn_global_load_lds(
                (const __attribute__((address_space(1))) void*)src,
                (__attribute__((address_space(3))) void*)&As[buf][c * 8], 16, 0, 0);
        }
        #pragma unroll
        for (int j = 0; j < 4; j++) {
            int c = j * 256 + tid;
            int row = c >> 3, gl = c & 7;
            int gg = gl ^ (row & 7);
            int brow = n0 + row; brow = brow < Nd ? brow : Nd - 1;
            const __attribute__((address_space(1))) short* src =
                (const __attribute__((address_space(1))) short*)(Bt + (size_t)brow * ldb + k0 + gg * 8);
            __builtin_amdgcn_global_load_lds(
                (const __attribute__((address_space(1))) void*)src,
                (__attribute__((address_space(3))) void*)&Bs[buf][c * 8], 16, 0, 0);
        }
    };

    stage(0, kbeg);
    asm volatile("s_waitcnt vmcnt(0)" ::: "memory");
    __builtin_amdgcn_s_barrier();
    __builtin_amdgcn_sched_barrier(0);

    const int nt = Kslab >> 6;
    for (int t = 0; t < nt; t++) {
        const int cur = t & 1;
        if (t + 1 < nt) {
            stage(cur ^ 1, kbeg + (t + 1) * 64);
            asm volatile("s_waitcnt vmcnt(8)" ::: "memory");
        } else {
            asm volatile("s_waitcnt vmcnt(0)" ::: "memory");
        }
        __builtin_amdgcn_s_barrier();
        __builtin_amdgcn_sched_barrier(0);

        short8 a[2][4], bfr[2][4];
        #pragma unroll
        for (int kk = 0; kk < 2; kk++) {
            #pragma unroll
            for (int m = 0; m < 4; m++) {
                int row = wr * 64 + m * 16 + l15;
                int gs  = (kk * 4 + kg) ^ gsw;
                a[kk][m] = *(const short8*)&As[cur][(row * 8 + gs) * 8];
            }
            #pragma unroll
            for (int n = 0; n < 4; n++) {
                int row = wc * 64 + n * 16 + l15;
                int gs  = (kk * 4 + kg) ^ gsw;
                bfr[kk][n] = *(const short8*)&Bs[cur][(row * 8 + gs) * 8];
            }
        }
        #pragma unroll
        for (int kk = 0; kk < 2; kk++)
            #pragma unroll
            for (int m = 0; m < 4; m++)
                #pragma unroll
                for (int n = 0; n < 4; n++)
                    acc[m][n] = __builtin_amdgcn_mfma_f32_16x16x32_bf16(a[kk][m], bfr[kk][n], acc[m][n], 0, 0, 0);

        __builtin_amdgcn_sched_barrier(0);
        __builtin_amdgcn_s_barrier();
    }

    if (SPLIT) {
        #pragma unroll
        for (int n = 0; n < 4; n++) {
            int col = n0 + wc * 64 + n * 16 + l15;
            if (col >= Nd) continue;
            #pragma unroll
            for (int m = 0; m < 4; m++)
                #pragma unroll
                for (int q = 0; q < 4; q++) {
                    int row = m0 + wr * 64 + m * 16 + kg * 4 + q;
                    if (row >= Md) continue;
                    size_t ix = (size_t)bz * Md * Nd + (size_t)row * Nd + col;
                    if (PARTBF) ((unsigned short*)Cpart)[ix] = f2bf(acc[m][n][q]);
                    else        ((float*)Cpart)[ix] = acc[m][n][q];
                }
        }
    } else {
        #pragma unroll
        for (int n = 0; n < 4; n++) {
            int col = n0 + wc * 64 + n * 16 + l15;
            if (col >= Nd) continue;
            float bv = BIAS ? bias[col] : 0.f;
            #pragma unroll
            for (int m = 0; m < 4; m++)
                #pragma unroll
                for (int q = 0; q < 4; q++) {
                    int row = m0 + wr * 64 + m * 16 + kg * 4 + q;
                    if (row >= Md) continue;
                    float v = acc[m][n][q] + bv;
                    if (ACT == 1) v = fmaxf(v, 0.f) + log1pf(expf(-fabsf(v)));  // softplus
                    if (W32) C32[(size_t)row * Nd + col] = v;
                    if (W16) C16[(size_t)row * Nd + col] = f2bf(v);
                }
        }
    }
}

// ---------------------------------------------------------------------------
// Sum S fp32 split-K partials + bias/act -> fp32/bf16. total % 1024 == 0.
// ---------------------------------------------------------------------------
template<int S, bool BIAS, int ACT, bool W32, bool W16>
__global__ __launch_bounds__(256) void reduce_split(
    const float* __restrict__ P, const float* __restrict__ bias,
    float* __restrict__ C32, unsigned short* __restrict__ C16,
    int total, int nmask)
{
    int i = (blockIdx.x * 256 + threadIdx.x) * 4;
    float4 v = *(const float4*)&P[i];
    #pragma unroll
    for (int s = 1; s < S; s++) {
        float4 p = *(const float4*)&P[(size_t)s * total + i];
        v.x += p.x; v.y += p.y; v.z += p.z; v.w += p.w;
    }
    float r[4] = {v.x, v.y, v.z, v.w};
    #pragma unroll
    for (int j = 0; j < 4; j++) {
        float t = r[j];
        if (BIAS) t += bias[(i + j) & nmask];
        if (ACT == 1) t = fmaxf(t, 0.f) + log1pf(expf(-fabsf(t)));
        if (W32) C32[i + j] = t;
        if (W16) C16[i + j] = f2bf(t);
    }
}

// ---------------------------------------------------------------------------
// Sum S bf16 split-K partials + bias -> bf16. total % 2048 == 0.
// ---------------------------------------------------------------------------
template<int S, bool BIAS>
__global__ __launch_bounds__(256) void reduce_split_bf(
    const unsigned short* __restrict__ P, const float* __restrict__ bias,
    unsigned short* __restrict__ C16, int total, int nmask)
{
    int i = (blockIdx.x * 256 + threadIdx.x) * 8;
    float r[8] = {};
    #pragma unroll
    for (int s = 0; s < S; s++) {
        short8 p = *(const short8*)&P[(size_t)s * total + i];
        #pragma unroll
        for (int j = 0; j < 8; j++) r[j] += bf2f((unsigned short)p[j]);
    }
    short8 o;
    #pragma unroll
    for (int j = 0; j < 8; j++) {
        float t = r[j];
        if (BIAS) t += bias[(i + j) & nmask];
        o[j] = (short)f2bf(t);
    }
    *(short8*)&C16[i] = o;
}

// ---------------------------------------------------------------------------
// fp32 -> bf16 flat convert (n % 1024 == 0)
// ---------------------------------------------------------------------------
__global__ __launch_bounds__(256) void f32_to_bf16_kernel(
    const float* __restrict__ in, unsigned short* __restrict__ out, int n4)
{
    int i = (blockIdx.x * 256 + threadIdx.x) * 4;
    float4 v = *(const float4*)&in[i];
    out[i + 0] = f2bf(v.x);
    out[i + 1] = f2bf(v.y);
    out[i + 2] = f2bf(v.z);
    out[i + 3] = f2bf(v.w);
}

// ---------------------------------------------------------------------------
// Transpose fp32 [K][N] -> bf16 [N][K]  (K,N multiples of 32)
// ---------------------------------------------------------------------------
__global__ __launch_bounds__(256) void transpose_f32_bf16(
    const float* __restrict__ in, unsigned short* __restrict__ out, int K, int N)
{
    __shared__ float t[32][33];
    int k0 = blockIdx.x * 32, n0 = blockIdx.y * 32;
    int tx = threadIdx.x & 31, ty = threadIdx.x >> 5;   // ty 0..7
    #pragma unroll
    for (int i = 0; i < 4; i++)
        t[ty + i * 8][tx] = in[(size_t)(k0 + ty + i * 8) * N + n0 + tx];
    __syncthreads();
    #pragma unroll
    for (int i = 0; i < 4; i++)
        out[(size_t)(n0 + ty + i * 8) * K + k0 + tx] = f2bf(t[tx][ty + i * 8]);
}

// ---------------------------------------------------------------------------
// Causal depthwise conv (K=4) + bias + SiLU; xz is bf16 with row stride 2*DI.
// ---------------------------------------------------------------------------
__global__ __launch_bounds__(256) void conv_silu_kernel(
    const unsigned short* __restrict__ xz, const float* __restrict__ conv_w,
    const float* __restrict__ conv_b, float* __restrict__ xc,
    unsigned short* __restrict__ xc_bf)
{
    int idx = blockIdx.x * 256 + threadIdx.x;
    if (idx >= Bb * Ll * DI) return;
    int d  = idx & (DI - 1);
    int bl = idx >> 11;
    int l  = bl % Ll;

    float acc = conv_b[d];
    #pragma unroll
    for (int k = 0; k < Kc; k++) {
        int ls = l + k - (Kc - 1);
        if (ls >= 0)
            acc = fmaf(conv_w[d * Kc + k], bf2f(xz[(size_t)(bl + ls - l) * (2 * DI) + d]), acc);
    }
    float s = fast_silu(acc);
    xc[idx] = s;
    xc_bf[idx] = f2bf(s);
}

// ---------------------------------------------------------------------------
// Chunked selective scan, 2-pass. See R8 comments.
// ---------------------------------------------------------------------------
__global__ __launch_bounds__(256) void scan_part1(
    const float* __restrict__ delta, const float* __restrict__ xc,
    const float* __restrict__ proj,  const float* __restrict__ A_log,
    float* __restrict__ Pbuf, float* __restrict__ Sbuf)
{
    const int t    = threadIdx.x;
    const int nq   = t & 3;
    const int dloc = t >> 2;
    const int d    = blockIdx.x * 64 + dloc;
    const int b    = blockIdx.y;
    const int c    = blockIdx.z;

    float4 Alq = *(const float4*)&A_log[(size_t)d * Nst + nq * 4];
    float Ar0 = -expf(Alq.x), Ar1 = -expf(Alq.y), Ar2 = -expf(Alq.z), Ar3 = -expf(Alq.w);

    float h0 = 0.f, h1 = 0.f, h2 = 0.f, h3 = 0.f;
    float sdl = 0.f;

    for (int l = c * CL; l < (c + 1) * CL; l++) {
        size_t bl = (size_t)b * Ll + l;
        float dl  = delta[bl * DI + d];
        float xcv = xc[bl * DI + d];
        float dx  = dl * xcv;
        float4 Bv = *(const float4*)&proj[bl * (DTR + 2 * Nst) + DTR + nq * 4];

        h0 = fmaf(__expf(dl * Ar0), h0, dx * Bv.x);
        h1 = fmaf(__expf(dl * Ar1), h1, dx * Bv.y);
        h2 = fmaf(__expf(dl * Ar2), h2, dx * Bv.z);
        h3 = fmaf(__expf(dl * Ar3), h3, dx * Bv.w);
        sdl += dl;
    }

    size_t o = (((size_t)c * Bb + b) * DI + d) * Nst + nq * 4;
    *(float4*)&Pbuf[o] = (float4){__expf(sdl * Ar0), __expf(sdl * Ar1),
                                  __expf(sdl * Ar2), __expf(sdl * Ar3)};
    *(float4*)&Sbuf[o] = (float4){h0, h1, h2, h3};
}

__global__ __launch_bounds__(256) void scan_part2(
    const float* __restrict__ delta, const float* __restrict__ xc,
    const unsigned short* __restrict__ xz, const float* __restrict__ proj,
    const float* __restrict__ A_log, const float* __restrict__ Dv,
    const float* __restrict__ Pbuf, const float* __restrict__ Sbuf,
    unsigned short* __restrict__ y)
{
    const int t    = threadIdx.x;
    const int nq   = t & 3;
    const int dloc = t >> 2;
    const int d    = blockIdx.x * 64 + dloc;
    const int b    = blockIdx.y;
    const int c    = blockIdx.z;

    float4 Alq = *(const float4*)&A_log[(size_t)d * Nst + nq * 4];
    float Ar0 = -expf(Alq.x), Ar1 = -expf(Alq.y), Ar2 = -expf(Alq.z), Ar3 = -expf(Alq.w);
    const float Dd = Dv[d];

    float h0 = 0.f, h1 = 0.f, h2 = 0.f, h3 = 0.f;
    for (int cc = 0; cc < c; cc++) {
        size_t o = (((size_t)cc * Bb + b) * DI + d) * Nst + nq * 4;
        float4 Pv = *(const float4*)&Pbuf[o];
        float4 Sv = *(const float4*)&Sbuf[o];
        h0 = fmaf(Pv.x, h0, Sv.x);
        h1 = fmaf(Pv.y, h1, Sv.y);
        h2 = fmaf(Pv.z, h2, Sv.z);
        h3 = fmaf(Pv.w, h3, Sv.w);
    }

    for (int l = c * CL; l < (c + 1) * CL; l++) {
        size_t bl = (size_t)b * Ll + l;
        float dl  = delta[bl * DI + d];
        float xcv = xc[bl * DI + d];
        float zv  = bf2f(xz[bl * (2 * DI) + DI + d]);
        float dx  = dl * xcv;
        const float* p = proj + bl * (DTR + 2 * Nst);
        float4 Bv = *(const float4*)&p[DTR + nq * 4];
        float4 Cv = *(const float4*)&p[DTR + Nst + nq * 4];

        h0 = fmaf(__expf(dl * Ar0), h0, dx * Bv.x);
        h1 = fmaf(__expf(dl * Ar1), h1, dx * Bv.y);
        h2 = fmaf(__expf(dl * Ar2), h2, dx * Bv.z);
        h3 = fmaf(__expf(dl * Ar3), h3, dx * Bv.w);

        float yac = h0 * Cv.x + h1 * Cv.y + h2 * Cv.z + h3 * Cv.w;
        yac += __shfl_xor(yac, 1);
        yac += __shfl_xor(yac, 2);

        if (nq == 0) {
            float yv = yac + Dd * xcv;
            yv *= fast_silu(zv);
            y[bl * DI + d] = f2bf(yv);
        }
    }
}

// ---------------------------------------------------------------------------
// logits[M,16] = out_bf[M,1024] @ W_out[1024,16] + b_out
// ---------------------------------------------------------------------------
__global__ __launch_bounds__(256) void gemm_n16(
    const unsigned short* __restrict__ A, const float* __restrict__ W,
    const float* __restrict__ bias, float* __restrict__ C, int Kd)
{
    int m  = blockIdx.x;
    int t  = threadIdx.x;
    int c  = t & 15;
    int kg = t >> 4;
    const unsigned short* a = A + (size_t)m * Kd;

    float acc = 0.f;
    for (int k = kg; k < Kd; k += 16)
        acc = fmaf(bf2f(a[k]), W[k * NC + c], acc);

    __shared__ float red[256];
    red[t] = acc;
    __syncthreads();
    #pragma unroll
    for (int s = 128; s >= 16; s >>= 1) {
        if (t < s) red[t] += red[t + s];
        __syncthreads();
    }
    if (t < 16) C[(size_t)m * NC + t] = red[t] + bias[t];
}

// ---------------------------------------------------------------------------
extern "C" void kernel_launch(void* const* d_in, const int* in_sizes, int n_in,
                              void* d_out, int out_size, void* d_ws, size_t ws_size,
                              hipStream_t stream) {
    const float* x         = (const float*)d_in[0];
    const float* W_in      = (const float*)d_in[1];
    const float* b_in      = (const float*)d_in[2];
    const float* in_proj_w = (const float*)d_in[3];
    const float* conv_w    = (const float*)d_in[4];
    const float* conv_b    = (const float*)d_in[5];
    const float* x_proj_w  = (const float*)d_in[6];
    const float* dt_proj_w = (const float*)d_in[7];
    const float* dt_proj_b = (const float*)d_in[8];
    const float* A_log     = (const float*)d_in[9];
    const float* Dv        = (const float*)d_in[10];
    const float* out_proj  = (const float*)d_in[11];
    const float* W_out     = (const float*)d_in[12];
    const float* b_out     = (const float*)d_in[13];
    float* logits = (float*)d_out;

    char* base = (char*)d_ws;
    size_t off = 0;
    auto alloc = [&](size_t bytes) {
        char* p = base + off;
        off += (bytes + 255) & ~(size_t)255;
        return p;
    };
    unsigned short* x_bf    = (unsigned short*)alloc((size_t)M * DIN * 2);
    unsigned short* Wt_in   = (unsigned short*)alloc((size_t)Hh * DIN * 2);
    unsigned short* Wt_ip   = (unsigned short*)alloc((size_t)(2 * DI) * Hh * 2);
    unsigned short* Wt_op   = (unsigned short*)alloc((size_t)Hh * DI * 2);
    unsigned short* xpw_t   = (unsigned short*)alloc((size_t)96 * DI * 2);
    unsigned short* dtw_t   = (unsigned short*)alloc((size_t)DI * DTR * 2);
    unsigned short* h_bf    = (unsigned short*)alloc((size_t)M * Hh * 2);
    unsigned short* xz_bf   = (unsigned short*)alloc((size_t)M * 2 * DI * 2);
    float*          xc      = (float*)alloc((size_t)M * DI * 4);       // | partials alias
    float*          delta   = (float*)alloc((size_t)M * DI * 4);       // | region
    unsigned short* xc_bf   = (unsigned short*)alloc((size_t)M * DI * 2);
    float*          proj_f  = (float*)alloc((size_t)M * 96 * 4);
    unsigned short* proj_bf = (unsigned short*)alloc((size_t)M * 96 * 2);
    unsigned short* y_bf    = (unsigned short*)alloc((size_t)M * DI * 2);
    unsigned short* out_bf  = (unsigned short*)alloc((size_t)M * Hh * 2);

    unsigned short* P14 = (unsigned short*)xc;   // bf16 [4][1600][1024] = 13.1MB
    float*          P8  = delta;                 // fp32 [8][1600][96]  = 4.9MB
    float*          Pbuf = (float*)x_bf;         // scan chunk buffers (x_bf dead)
    float*          Sbuf = Pbuf + (size_t)(NCH - 1) * Bb * DI * Nst;

    dim3 blk(256), blk5(512);

    // 0) conversions / weight transposes
    f32_to_bf16_kernel<<<dim3((M * DIN) / 1024), blk, 0, stream>>>(x, x_bf, M * DIN);
    transpose_f32_bf16<<<dim3(DIN / 32, Hh / 32), blk, 0, stream>>>(W_in, Wt_in, DIN, Hh);
    transpose_f32_bf16<<<dim3(Hh / 32, (2 * DI) / 32), blk, 0, stream>>>(in_proj_w, Wt_ip, Hh, 2 * DI);
    transpose_f32_bf16<<<dim3(DI / 32, Hh / 32), blk, 0, stream>>>(out_proj, Wt_op, DI, Hh);
    transpose_f32_bf16<<<dim3(DI / 32, 96 / 32), blk, 0, stream>>>(x_proj_w, xpw_t, DI, 96);
    transpose_f32_bf16<<<dim3(DTR / 32, DI / 32), blk, 0, stream>>>(dt_proj_w, dtw_t, DTR, DI);

    // 1) h = x @ W_in + b_in   [1600,6144]@[6144,1024], split-K 4 -> 224 blocks
    gemm_deep<true, false, false><<<dim3(7, Hh / 128, 4), blk5, 0, stream>>>(
        x_bf, DIN, Wt_in, DIN, nullptr, nullptr, P14, M, Hh, DIN / 4);
    reduce_split_bf<4, true><<<dim3((M * Hh) / 2048), blk, 0, stream>>>(
        P14, b_in, h_bf, M * Hh, Hh - 1);

    // 2) xz = h @ in_proj_w    [1600,1024]@[1024,4096], 224 blocks, no split
    gemm_deep<false, false, true><<<dim3(7, (2 * DI) / 128, 1), blk5, 0, stream>>>(
        h_bf, Hh, Wt_ip, Hh, nullptr, xz_bf, nullptr, M, 2 * DI, Hh);

    // 3) xc = silu(conv(xm) + conv_b)  -> fp32 + bf16
    conv_silu_kernel<<<dim3((Bb * Ll * DI) / 256), blk, 0, stream>>>(
        xz_bf, conv_w, conv_b, xc, xc_bf);

    // 4) proj = xc @ x_proj_w  [1600,2048]@[2048,96], split-K 8 -> 104 blocks
    gemm_mfma<true, false, false, 0, false, false><<<dim3(13, 1, 8), blk, 0, stream>>>(
        xc_bf, DI, xpw_t, DI, nullptr, nullptr, nullptr, P8, M, 96, DI / 8);
    reduce_split<8, false, 0, true, true><<<dim3((M * 96) / 1024), blk, 0, stream>>>(
        P8, nullptr, proj_f, proj_bf, M * 96, 0);

    // 5) delta = softplus(proj[:,:64] @ dt_proj_w + dt_proj_b)  [1600,64]@[64,2048]
    gemm_mfma<false, false, true, 1, true, false><<<dim3(13, DI / 128, 1), blk, 0, stream>>>(
        proj_bf, 96, dtw_t, DTR, dt_proj_b, delta, nullptr, nullptr, M, DI, DTR);

    // 6) chunked selective scan: pass1 (chunks 0..2) then pass2 (all 4)
    scan_part1<<<dim3(DI / 64, Bb, NCH - 1), blk, 0, stream>>>(
        delta, xc, proj_f, A_log, Pbuf, Sbuf);
    scan_part2<<<dim3(DI / 64, Bb, NCH), blk, 0, stream>>>(
        delta, xc, xz_bf, proj_f, A_log, Dv, Pbuf, Sbuf, y_bf);

    // 7) out = y @ out_proj_w  [1600,2048]@[2048,1024], split-K 4 -> 224 blocks
    gemm_deep<true, false, false><<<dim3(7, Hh / 128, 4), blk5, 0, stream>>>(
        y_bf, DI, Wt_op, DI, nullptr, nullptr, P14, M, Hh, DI / 4);
    reduce_split_bf<4, false><<<dim3((M * Hh) / 2048), blk, 0, stream>>>(
        P14, nullptr, out_bf, M * Hh, 0);

    // 8) logits = out @ W_out + b_out  [1600,1024]@[1024,16]
    gemm_n16<<<dim3(M), blk, 0, stream>>>(out_bf, W_out, b_out, logits, Hh);
}